// Round 11
// baseline (291.251 us; speedup 1.0000x reference)
//
#include <hip/hip_runtime.h>
#include <hip/hip_bf16.h>
#include <math.h>

// SelectiveSSM: D_MODEL=1024, D_STATE=16, D_CONV=4, EXPAND=2, B=2, L=2048
#define D_MODEL 1024
#define D_STATE 16
#define D_CONV  4
#define D_INNER 2048
#define BB      2
#define LL      2048
#define BLROWS  (BB*LL)       // 4096
#define NCHUNK  64
#define CHUNK   (LL/NCHUNK)   // 32
#define SSML    36            // padded ssm row stride (floats)
#define XSPLIT  16            // split-K factor for xproj

typedef __hip_bfloat16 bf16;
typedef __attribute__((ext_vector_type(8))) short short8;
typedef __attribute__((ext_vector_type(4))) float f32x4;

__device__ __forceinline__ float ldf(const void* p, long i, int isbf) {
    return isbf ? __bfloat162float(((const bf16*)p)[i]) : ((const float*)p)[i];
}
__device__ __forceinline__ short bfbits(float f) {
    bf16 h = __float2bfloat16(f);
    return *(short*)&h;
}
__device__ __forceinline__ float bits2f(short s) {
    bf16 h; *(short*)&h = s; return __bfloat162float(h);
}
__device__ __forceinline__ float bf2f(bf16 h) { return __bfloat162float(h); }
__device__ __forceinline__ float siluf(float x) {
    return __fdividef(x, 1.f + __expf(-x));
}
// fused stable softplus + exp-negation: delta = log(1+exp(x)), r = exp(-delta)
__device__ __forceinline__ void softplus_r(float x, float& delta, float& r) {
    float e = __expf(-fabsf(x));
    float t = 1.f + e;
    delta = fmaxf(x, 0.f) + __logf(t);
    r = __fdividef((x >= 0.f) ? e : 1.f, t);
}

// smallf float offsets
#define OFF_CW   0
#define OFF_CB   8192
#define OFF_WDT  10240
#define OFF_BDT  12288
#define OFF_AA   14336
#define OFF_D    47104
#define N_SMALL  49152
#define N_WXPB   (128*2048)
#define N_SSMZ   (BLROWS*SSML)

#define G_LDS16(gptr, lptr) __builtin_amdgcn_global_load_lds( \
    (const __attribute__((address_space(1))) void*)(gptr),    \
    (__attribute__((address_space(3))) void*)(lptr), 16, 0, 0)

// ---------------------------------------------------------------------------
// dtype probe + flag init. flag[0]=isbf, flag[1]=fastA.
// ---------------------------------------------------------------------------
__global__ void dtype_probe(const unsigned short* __restrict__ alog, int* __restrict__ flag) {
    if (threadIdx.x == 0) { flag[0] = (alog[1] != 0) ? 1 : 0; flag[1] = 1; }
}

// ---------------------------------------------------------------------------
// prep: padded bf16 W_xproj + fp32 smalls + zero ssm + A-structure check
// ---------------------------------------------------------------------------
__global__ __launch_bounds__(256) void cvt_prep(
    const void* __restrict__ Wxp, const void* __restrict__ cw,
    const void* __restrict__ cb, const void* __restrict__ wdt,
    const void* __restrict__ bdt, const void* __restrict__ alog,
    const void* __restrict__ Dp,
    bf16* __restrict__ wxpb, float* __restrict__ smallf,
    float* __restrict__ ssm, int* __restrict__ flag)
{
    const int isbf = flag[0];
    int idx = blockIdx.x * 256 + threadIdx.x;
    if (idx < N_WXPB) {
        int row = idx >> 11, col = idx & 2047;
        float v = (row < 33) ? ldf(Wxp, (long)row*2048 + col, isbf) : 0.f;
        wxpb[idx] = __float2bfloat16(v);
        return;
    }
    int j = idx - N_WXPB;
    if      (j < 8192)  smallf[OFF_CW  + j]         = ldf(cw,  j, isbf);
    else if (j < 10240) smallf[OFF_CB  + j - 8192]  = ldf(cb,  j - 8192, isbf);
    else if (j < 12288) smallf[OFF_WDT + j - 10240] = ldf(wdt, j - 10240, isbf);
    else if (j < 14336) smallf[OFF_BDT + j - 12288] = ldf(bdt, j - 12288, isbf);
    else if (j < 47104) {
        int jj = j - 14336;                 // = d*16 + s
        float aa = -__expf(ldf(alog, jj, isbf));
        smallf[OFF_AA + jj] = aa;
        int s = jj & 15;
        if (fabsf(aa + (float)(s+1)) > 1e-3f) flag[1] = 0;
    }
    else if (j < 49152) smallf[OFF_D   + j - 47104] = ldf(Dp,  j - 47104, isbf);
    else {
        int z = j - N_SMALL;
        if (z < N_SSMZ) ssm[z] = 0.f;
    }
}

// ---------------------------------------------------------------------------
// merged x/W_in/W_out -> bf16 conversion (8 elems/thread, one launch)
// ---------------------------------------------------------------------------
__global__ __launch_bounds__(256) void cvt_all(
    const void* __restrict__ x, const void* __restrict__ win,
    const void* __restrict__ wout,
    bf16* __restrict__ xb, bf16* __restrict__ winb, bf16* __restrict__ woutb,
    const int* __restrict__ flagp)
{
    const int isbf = *flagp;
    int i = blockIdx.x * 256 + threadIdx.x;
    const void* src; bf16* dst; long o;
    if (i < 524288)       { src = x;    dst = xb;    o = (long)i * 8; }
    else if (i < 1048576) { src = win;  dst = winb;  o = (long)(i - 524288) * 8; }
    else if (i < 1310720) { src = wout; dst = woutb; o = (long)(i - 1048576) * 8; }
    else return;
    short8 v;
    if (isbf) {
        v = *(const short8*)((const bf16*)src + o);
    } else {
        const float* s = (const float*)src + o;
        f32x4 u = *(const f32x4*)s, w = *(const f32x4*)(s + 4);
        v[0]=bfbits(u[0]); v[1]=bfbits(u[1]); v[2]=bfbits(u[2]); v[3]=bfbits(u[3]);
        v[4]=bfbits(w[0]); v[5]=bfbits(w[1]); v[6]=bfbits(w[2]); v[7]=bfbits(w[3]);
    }
    *(short8*)(dst + o) = v;
}

// ---------------------------------------------------------------------------
// gemm8x (r11): TRUE 8-phase 256x256 GEMM (T3+T4 template, §5).
// 512 thr / 8 waves; wave sub-tile per phase = 64x32 of the 128x128 block
// C-quadrant. LDS = [2 buf][2 half][128x64] for A and B (128 KiB).
// Per phase: 12 ds_read_b128 + 1 half-tile stage (2 G_LDS16) + barrier +
// lgkmcnt(0) + 16 MFMA + barrier. Quadrant order (qm,qn) = (0,0),(0,1),
// (1,0),(1,1); stages per quartet kt: A1(kt+1)@p0, B1(kt+1)@p1,
// A0(kt+2)@p2, B0(kt+2)@p3 — each target slot's last read is strictly
// before the staging phase (guarded by the p-1 post-MFMA barrier).
// Boundary vmcnt(4) at each p3 retires exactly the next K-tile's 4
// half-tiles (2 remain in flight); vmcnt(0) at the kt=NT-2 boundary.
// Replaces r6's coarse split (all-reads-then-all-MFMA = 672 TF, m196).
// ---------------------------------------------------------------------------
__global__ __launch_bounds__(512) void gemm8x(
    const bf16* __restrict__ A,    // [4096][1024] row-major
    const bf16* __restrict__ Bm,   // [4096][1024] row-major
    bf16* __restrict__ Cp)         // [4096][4096]
{
    __shared__ bf16 As[2][2][128*64];
    __shared__ bf16 Bs[2][2][128*64];
    const int t    = threadIdx.x;          // 0..511
    const int lane = t & 63;
    const int w    = t >> 6;               // 0..7
    const int rm   = w >> 2;               // 0..1 row-sub within quadrant
    const int cn   = w & 3;                // 0..3 col-sub within quadrant
    const int bm   = blockIdx.y, bn = blockIdx.x;
    const int quad = lane >> 4, l16 = lane & 15;
    const int NT   = 16;                   // K=1024 / BK=64

    f32x4 acc[4][4][2];
    #pragma unroll
    for (int p = 0; p < 4; p++)
        #pragma unroll
        for (int i = 0; i < 4; i++)
            #pragma unroll
            for (int j = 0; j < 2; j++)
                acc[p][i][j] = f32x4{0.f, 0.f, 0.f, 0.f};

    auto stageA = [&](int bufi, int half, int kt) {
        #pragma unroll
        for (int seg = 0; seg < 2; seg++) {
            int s = seg*512 + t, row = s >> 3, sg = s & 7;
            int col = (sg ^ (row & 7)) * 8;
            G_LDS16(A + ((long)bm*256 + half*128 + row)*1024 + kt*64 + col,
                    &As[bufi][half][s*8]);
        }
    };
    auto stageB = [&](int bufi, int half, int kt) {
        #pragma unroll
        for (int seg = 0; seg < 2; seg++) {
            int s = seg*512 + t, row = s >> 3, sg = s & 7;
            int col = (sg ^ (row & 7)) * 8;
            G_LDS16(Bm + ((long)bn*256 + half*128 + row)*1024 + kt*64 + col,
                    &Bs[bufi][half][s*8]);
        }
    };

    // prologue: tile0 (4 half-tiles) + A0/B0 of tile1; wait tile0 landed.
    stageA(0, 0, 0); stageB(0, 0, 0); stageA(0, 1, 0); stageB(0, 1, 0);
    stageA(1, 0, 1); stageB(1, 0, 1);
    asm volatile("s_waitcnt vmcnt(4)" ::: "memory");
    __builtin_amdgcn_s_barrier();

    for (int kt = 0; kt < NT; ++kt) {
        const int buf = kt & 1;
        #pragma unroll
        for (int p = 0; p < 4; ++p) {
            const int qm = p >> 1, qn = p & 1;
            short8 af[4][2], bfv[2][2];
            #pragma unroll
            for (int fi = 0; fi < 4; fi++)
                #pragma unroll
                for (int kk = 0; kk < 2; kk++) {
                    int ar = rm*64 + fi*16 + l16;
                    int c = kk*4 + quad;
                    af[fi][kk] = *(const short8*)&As[buf][qm][ar*64 + ((c ^ (ar & 7))*8)];
                }
            #pragma unroll
            for (int fj = 0; fj < 2; fj++)
                #pragma unroll
                for (int kk = 0; kk < 2; kk++) {
                    int br = cn*32 + fj*16 + l16;
                    int c = kk*4 + quad;
                    bfv[fj][kk] = *(const short8*)&Bs[buf][qn][br*64 + ((c ^ (br & 7))*8)];
                }
            if      (p == 0) { if (kt + 1 < NT) stageA(buf ^ 1, 1, kt + 1); }
            else if (p == 1) { if (kt + 1 < NT) stageB(buf ^ 1, 1, kt + 1); }
            else if (p == 2) { if (kt + 2 < NT) stageA(buf, 0, kt + 2); }
            else             { if (kt + 2 < NT) stageB(buf, 0, kt + 2); }
            __builtin_amdgcn_s_barrier();
            asm volatile("s_waitcnt lgkmcnt(0)" ::: "memory");
            __builtin_amdgcn_sched_barrier(0);
            __builtin_amdgcn_s_setprio(1);
            #pragma unroll
            for (int kk = 0; kk < 2; kk++)
                #pragma unroll
                for (int fi = 0; fi < 4; fi++)
                    #pragma unroll
                    for (int fj = 0; fj < 2; fj++)
                        acc[p][fi][fj] = __builtin_amdgcn_mfma_f32_16x16x32_bf16(
                            af[fi][kk], bfv[fj][kk], acc[p][fi][fj], 0, 0, 0);
            __builtin_amdgcn_s_setprio(0);
            __builtin_amdgcn_sched_barrier(0);
            if (p == 3) {
                if (kt == NT - 2)     { asm volatile("s_waitcnt vmcnt(0)" ::: "memory"); }
                else if (kt < NT - 2) { asm volatile("s_waitcnt vmcnt(4)" ::: "memory"); }
            }
            __builtin_amdgcn_sched_barrier(0);
            __builtin_amdgcn_s_barrier();
        }
    }

    #pragma unroll
    for (int p = 0; p < 4; p++) {
        const int qm = p >> 1, qn = p & 1;
        #pragma unroll
        for (int fi = 0; fi < 4; fi++)
            #pragma unroll
            for (int fj = 0; fj < 2; fj++)
                #pragma unroll
                for (int r = 0; r < 4; r++) {
                    int row = bm*256 + qm*128 + rm*64 + fi*16 + quad*4 + r;
                    int col = bn*256 + qn*128 + cn*32 + fj*16 + l16;
                    Cp[(long)row * 4096 + col] = __float2bfloat16(acc[p][fi][fj][r]);
                }
    }
}

// ---------------------------------------------------------------------------
// GEMM fallback (small-ws path): 128x128 tile, BK=64, XOR-swizzled LDS
// ---------------------------------------------------------------------------
__global__ __launch_bounds__(256) void gemm_dual(
    const void* __restrict__ A, int lda,
    const void* __restrict__ Bm, int ldb,
    void* __restrict__ Cp, int ldc, int K,
    const int* __restrict__ flagp, int amode, int bmode, int cmode)
{
    const int isbf = *flagp;
    const int a_bf = amode ? isbf : 1;
    const int b_bf = bmode ? isbf : 1;
    const int c_bf = cmode ? isbf : 1;

    __shared__ bf16 As[128*64];
    __shared__ bf16 Bs[128*64];
    const int t    = threadIdx.x;
    const int lane = t & 63;
    const int w    = t >> 6;
    const int wm   = w >> 1, wn = w & 1;
    const int bm   = blockIdx.y, bn = blockIdx.x;
    const int quad = lane >> 4, l16 = lane & 15;

    f32x4 acc[4][4];
    #pragma unroll
    for (int i = 0; i < 4; i++)
        #pragma unroll
        for (int j = 0; j < 4; j++)
            acc[i][j] = f32x4{0.f, 0.f, 0.f, 0.f};

    for (int k0 = 0; k0 < K; k0 += 64) {
        __syncthreads();
        if (a_bf) {
            #pragma unroll
            for (int seg = 0; seg < 4; seg++) {
                int s = seg*256 + t, row = s >> 3, sg = s & 7;
                int col = (sg ^ (row & 7)) * 8;
                const bf16* ga = (const bf16*)A + ((long)bm*128 + row)*(long)lda + k0 + col;
                G_LDS16(ga, &As[row*64 + sg*8]);
            }
        } else {
            #pragma unroll
            for (int seg = 0; seg < 4; seg++) {
                int s = seg*256 + t, row = s >> 3, sg = s & 7;
                int col = (sg ^ (row & 7)) * 8;
                const float* ap = (const float*)A + ((long)bm*128 + row)*(long)lda + k0 + col;
                f32x4 u = *(const f32x4*)ap, v = *(const f32x4*)(ap + 4);
                short8 va;
                va[0]=bfbits(u[0]); va[1]=bfbits(u[1]); va[2]=bfbits(u[2]); va[3]=bfbits(u[3]);
                va[4]=bfbits(v[0]); va[5]=bfbits(v[1]); va[6]=bfbits(v[2]); va[7]=bfbits(v[3]);
                *(short8*)&As[row*64 + sg*8] = va;
            }
        }
        if (b_bf) {
            #pragma unroll
            for (int seg = 0; seg < 4; seg++) {
                int s = seg*256 + t, row = s >> 3, sg = s & 7;
                int col = (sg ^ (row & 7)) * 8;
                const bf16* gb = (const bf16*)Bm + ((long)bn*128 + row)*(long)ldb + k0 + col;
                G_LDS16(gb, &Bs[row*64 + sg*8]);
            }
        } else {
            #pragma unroll
            for (int seg = 0; seg < 4; seg++) {
                int s = seg*256 + t, row = s >> 3, sg = s & 7;
                int col = (sg ^ (row & 7)) * 8;
                const float* bp = (const float*)Bm + ((long)bn*128 + row)*(long)ldb + k0 + col;
                f32x4 u = *(const f32x4*)bp, v = *(const f32x4*)(bp + 4);
                short8 vb;
                vb[0]=bfbits(u[0]); vb[1]=bfbits(u[1]); vb[2]=bfbits(u[2]); vb[3]=bfbits(u[3]);
                vb[4]=bfbits(v[0]); vb[5]=bfbits(v[1]); vb[6]=bfbits(v[2]); vb[7]=bfbits(v[3]);
                *(short8*)&Bs[row*64 + sg*8] = vb;
            }
        }
        __syncthreads();

        #pragma unroll
        for (int kk = 0; kk < 64; kk += 32) {
            const int cbase = kk >> 3;
            short8 af[4], bfr[4];
            #pragma unroll
            for (int mi = 0; mi < 4; mi++) {
                int row = wm*64 + mi*16 + l16;
                int c = cbase + quad;
                af[mi] = *(const short8*)&As[row*64 + ((c ^ (row & 7))*8)];
            }
            #pragma unroll
            for (int ni = 0; ni < 4; ni++) {
                int row = wn*64 + ni*16 + l16;
                int c = cbase + quad;
                bfr[ni] = *(const short8*)&Bs[row*64 + ((c ^ (row & 7))*8)];
            }
            #pragma unroll
            for (int mi = 0; mi < 4; mi++)
                #pragma unroll
                for (int ni = 0; ni < 4; ni++)
                    acc[mi][ni] = __builtin_amdgcn_mfma_f32_16x16x32_bf16(
                        af[mi], bfr[ni], acc[mi][ni], 0, 0, 0);
        }
    }

    #pragma unroll
    for (int mi = 0; mi < 4; mi++)
        #pragma unroll
        for (int ni = 0; ni < 4; ni++)
            #pragma unroll
            for (int r = 0; r < 4; r++) {
                int row = bm*128 + wm*64 + mi*16 + quad*4 + r;
                int col = bn*128 + wn*64 + ni*16 + l16;
                float val = acc[mi][ni][r];
                if (c_bf) ((bf16*)Cp)[(long)row * ldc + col] = __float2bfloat16(val);
                else      ((float*)Cp)[(long)row * ldc + col] = val;
            }
}

// ---------------------------------------------------------------------------
// GEMM2 (r6-verified): 128x64 tile, BK=64, XOR swizzle. Grid (16,32).
// ---------------------------------------------------------------------------
__global__ __launch_bounds__(256) void gemm_n64(
    const bf16* __restrict__ A, int lda,
    const void* __restrict__ Bm, int ldb,
    void* __restrict__ Cp, int ldc, int K,
    const int* __restrict__ flagp, int bmode, int cmode)
{
    const int isbf = *flagp;
    const int b_bf = bmode ? isbf : 1;
    const int c_bf = cmode ? isbf : 1;

    __shared__ bf16 As[128*64];
    __shared__ bf16 Bs[64*64];
    const int t    = threadIdx.x;
    const int lane = t & 63;
    const int w    = t >> 6;
    const int wm   = w >> 1, wn = w & 1;
    const int bm   = blockIdx.y, bn = blockIdx.x;
    const int quad = lane >> 4, l16 = lane & 15;

    f32x4 acc[4][2];
    #pragma unroll
    for (int i = 0; i < 4; i++)
        #pragma unroll
        for (int j = 0; j < 2; j++)
            acc[i][j] = f32x4{0.f, 0.f, 0.f, 0.f};

    for (int k0 = 0; k0 < K; k0 += 64) {
        __syncthreads();
        #pragma unroll
        for (int seg = 0; seg < 4; seg++) {
            int s = seg*256 + t, row = s >> 3, sg = s & 7;
            int col = (sg ^ (row & 7)) * 8;
            const bf16* ga = A + ((long)bm*128 + row)*(long)lda + k0 + col;
            G_LDS16(ga, &As[row*64 + sg*8]);
        }
        if (b_bf) {
            #pragma unroll
            for (int seg = 0; seg < 2; seg++) {
                int s = seg*256 + t, row = s >> 3, sg = s & 7;
                int col = (sg ^ (row & 7)) * 8;
                const bf16* gb = (const bf16*)Bm + ((long)bn*64 + row)*(long)ldb + k0 + col;
                G_LDS16(gb, &Bs[row*64 + sg*8]);
            }
        } else {
            #pragma unroll
            for (int seg = 0; seg < 2; seg++) {
                int s = seg*256 + t, row = s >> 3, sg = s & 7;
                int col = (sg ^ (row & 7)) * 8;
                const float* bp = (const float*)Bm + ((long)bn*64 + row)*(long)ldb + k0 + col;
                f32x4 u = *(const f32x4*)bp, v = *(const f32x4*)(bp + 4);
                short8 vb;
                vb[0]=bfbits(u[0]); vb[1]=bfbits(u[1]); vb[2]=bfbits(u[2]); vb[3]=bfbits(u[3]);
                vb[4]=bfbits(v[0]); vb[5]=bfbits(v[1]); vb[6]=bfbits(v[2]); vb[7]=bfbits(v[3]);
                *(short8*)&Bs[row*64 + sg*8] = vb;
            }
        }
        __syncthreads();

        #pragma unroll
        for (int kk = 0; kk < 64; kk += 32) {
            const int cbase = kk >> 3;
            short8 af[4], bfr[2];
            #pragma unroll
            for (int mi = 0; mi < 4; mi++) {
                int row = wm*64 + mi*16 + l16;
                int c = cbase + quad;
                af[mi] = *(const short8*)&As[row*64 + ((c ^ (row & 7))*8)];
            }
            #pragma unroll
            for (int ni = 0; ni < 2; ni++) {
                int row = wn*32 + ni*16 + l16;
                int c = cbase + quad;
                bfr[ni] = *(const short8*)&Bs[row*64 + ((c ^ (row & 7))*8)];
            }
            #pragma unroll
            for (int mi = 0; mi < 4; mi++)
                #pragma unroll
                for (int ni = 0; ni < 2; ni++)
                    acc[mi][ni] = __builtin_amdgcn_mfma_f32_16x16x32_bf16(
                        af[mi], bfr[ni], acc[mi][ni], 0, 0, 0);
        }
    }

    #pragma unroll
    for (int mi = 0; mi < 4; mi++)
        #pragma unroll
        for (int ni = 0; ni < 2; ni++)
            #pragma unroll
            for (int r = 0; r < 4; r++) {
                int row = bm*128 + wm*64 + mi*16 + quad*4 + r;
                int col = bn*64 + wn*32 + ni*16 + l16;
                float val = acc[mi][ni][r];
                if (c_bf) ((bf16*)Cp)[(long)row * ldc + col] = __float2bfloat16(val);
                else      ((float*)Cp)[(long)row * ldc + col] = val;
            }
}

// ---------------------------------------------------------------------------
// xproj fused, split-K: ssm[bl, :] += partial(conv+silu(x_in) @ Wxp.T).
// r10: optionally spill the staged xc tile (silu(conv)) to global xcb.
// ---------------------------------------------------------------------------
__global__ __launch_bounds__(256) void xproj_fused(
    const bf16* __restrict__ xz, const bf16* __restrict__ wxpb,
    const float* __restrict__ smallf, float* __restrict__ ssm,
    bf16* __restrict__ xcb)
{
    const float* cwf = smallf + OFF_CW;
    const float* cbf = smallf + OFF_CB;
    __shared__ bf16 As[128*32];
    __shared__ bf16 Bs[128*32];
    const int t    = threadIdx.x;
    const int lane = t & 63;
    const int w    = t >> 6;
    const int wm   = w >> 1, wn = w & 1;
    const int bm   = blockIdx.y;
    const int ks   = blockIdx.x * (D_INNER / XSPLIT);
    const int quad = lane >> 4, l16 = lane & 15;

    f32x4 acc[4][4];
    #pragma unroll
    for (int i = 0; i < 4; i++)
        #pragma unroll
        for (int j = 0; j < 4; j++)
            acc[i][j] = f32x4{0.f, 0.f, 0.f, 0.f};

    for (int k0 = ks; k0 < ks + D_INNER/XSPLIT; k0 += 32) {
        __syncthreads();
        #pragma unroll
        for (int seg = 0; seg < 2; seg++) {
            int s = seg*256 + t, row = s >> 2, dcol = (s & 3) * 8;
            int blg = bm*128 + row;
            int b = blg >> 11, l = blg & (LL - 1);
            int d0 = k0 + dcol;
            float a[8];
            {
                f32x4 c0 = *(const f32x4*)&cbf[d0], c1 = *(const f32x4*)&cbf[d0+4];
                a[0]=c0[0]; a[1]=c0[1]; a[2]=c0[2]; a[3]=c0[3];
                a[4]=c1[0]; a[5]=c1[1]; a[6]=c1[2]; a[7]=c1[3];
            }
            f32x4 cw4[8];
            #pragma unroll
            for (int j = 0; j < 8; j++) cw4[j] = *(const f32x4*)&cwf[(d0+j)*4];
            #pragma unroll
            for (int kk = 0; kk < D_CONV; kk++) {
                int ls = l - 3 + kk;
                if (ls >= 0) {
                    short8 xv = *(const short8*)&xz[((long)(b*LL + ls))*4096 + d0];
                    #pragma unroll
                    for (int j = 0; j < 8; j++) a[j] += bits2f(xv[j]) * cw4[j][kk];
                }
            }
            short8 va;
            #pragma unroll
            for (int j = 0; j < 8; j++) va[j] = bfbits(siluf(a[j]));
            *(short8*)&As[row*32 + dcol] = va;
            if (xcb) *(short8*)&xcb[(long)blg*D_INNER + d0] = va;
        }
        #pragma unroll
        for (int seg = 0; seg < 2; seg++) {
            int s = seg*256 + t, row = s >> 2, col = (s & 3) * 8;
            const bf16* gb = wxpb + (long)row*D_INNER + k0 + col;
            G_LDS16(gb, &Bs[row*32 + col]);
        }
        __syncthreads();

        short8 af[4], bfr[4];
        #pragma unroll
        for (int mi = 0; mi < 4; mi++)
            af[mi] = *(const short8*)&As[(wm*64 + mi*16 + l16)*32 + quad*8];
        #pragma unroll
        for (int ni = 0; ni < 4; ni++)
            bfr[ni] = *(const short8*)&Bs[(wn*64 + ni*16 + l16)*32 + quad*8];
        #pragma unroll
        for (int mi = 0; mi < 4; mi++)
            #pragma unroll
            for (int ni = 0; ni < 4; ni++)
                acc[mi][ni] = __builtin_amdgcn_mfma_f32_16x16x32_bf16(
                    af[mi], bfr[ni], acc[mi][ni], 0, 0, 0);
    }

    #pragma unroll
    for (int mi = 0; mi < 4; mi++)
        #pragma unroll
        for (int ni = 0; ni < 4; ni++) {
            int col = wn*64 + ni*16 + l16;
            if (col < 33) {
                int newcol = (col == 0) ? 32 : (col - 1);
                #pragma unroll
                for (int r = 0; r < 4; r++) {
                    int row = bm*128 + wm*64 + mi*16 + quad*4 + r;
                    atomicAdd(&ssm[(long)row * SSML + newcol], acc[mi][ni][r]);
                }
            }
        }
}

// ---------------------------------------------------------------------------
// Scan phase A (r6-verified fallback): packed-f32 h, LDS x-prefetch + conv.
// ---------------------------------------------------------------------------
template<int CHUNK_T>
__global__ __launch_bounds__(256) void scan_partA(
    const float* __restrict__ ssm, const bf16* __restrict__ xz,
    const float* __restrict__ smallf,
    float* __restrict__ sumdq, float* __restrict__ Q,
    const int* __restrict__ flag)
{
    __shared__ float sL[CHUNK_T*SSML];
    __shared__ bf16  sX[CHUNK_T*256];
    const int fastA = flag[1];
    int d = blockIdx.x * 256 + threadIdx.x;
    int c = blockIdx.y, b = blockIdx.z;
    const int NC = gridDim.y;
    int l0 = c * CHUNK_T;
    {
        const float* src = ssm + (long)(b*LL + l0) * SSML;
        for (int idx = threadIdx.x; idx < CHUNK_T*SSML; idx += 256) sL[idx] = src[idx];
        const bf16* xsrc = xz + (long)(b*LL + l0)*4096 + blockIdx.x*256;
        for (int j = threadIdx.x; j < CHUNK_T*32; j += 256) {
            int li = j >> 5, ln = j & 31;
            *(short8*)&sX[li*256 + ln*8] = *(const short8*)&xsrc[(long)li*4096 + ln*8];
        }
    }
    f32x4 h4[4];
    #pragma unroll
    for (int g = 0; g < 4; g++) h4[g] = f32x4{0.f, 0.f, 0.f, 0.f};
    float Aa[D_STATE];
    if (!fastA) {
        #pragma unroll
        for (int s = 0; s < D_STATE; s++) Aa[s] = smallf[OFF_AA + d*D_STATE + s];
    }
    f32x4 cw4 = *(const f32x4*)&smallf[OFF_CW + d*4];
    float cbv  = smallf[OFF_CB + d];
    float wdt  = smallf[OFF_WDT + d];
    float bdtv = smallf[OFF_BDT + d];
    float win[3];
    #pragma unroll
    for (int k = 0; k < 3; k++) {
        int ls = l0 - 3 + k;
        win[k] = (ls >= 0) ? bf2f(xz[((long)(b*LL + ls))*4096 + d]) : 0.f;
    }
    __syncthreads();
    float sumd = 0.f;
    #pragma unroll 4
    for (int li = 0; li < CHUNK_T; li++) {
        float xnew = bf2f(sX[li*256 + threadIdx.x]);
        float convv = cbv + win[0]*cw4[0] + win[1]*cw4[1] + win[2]*cw4[2] + xnew*cw4[3];
        win[0] = win[1]; win[1] = win[2]; win[2] = xnew;
        float xc = siluf(convv);
        const float* row = &sL[li*SSML];
        f32x4 Bv[4];
        #pragma unroll
        for (int g = 0; g < 4; g++) Bv[g] = *(const f32x4*)(row + g*4);
        float delta, r;
        softplus_r(row[32]*wdt + bdtv, delta, r);
        sumd += delta;
        float du = delta * xc;
        if (fastA) {
            float r2 = r*r, r3 = r2*r, r4 = r2*r2;
            f32x4 p0; p0[0]=r; p0[1]=r2; p0[2]=r3; p0[3]=r4;
            float s8 = r4*r4, s12 = s8*r4;
            h4[0] = p0*h4[0]       + du*Bv[0];
            h4[1] = (p0*r4)*h4[1]  + du*Bv[1];
            h4[2] = (p0*s8)*h4[2]  + du*Bv[2];
            h4[3] = (p0*s12)*h4[3] + du*Bv[3];
        } else {
            #pragma unroll
            for (int g = 0; g < 4; g++)
                #pragma unroll
                for (int j = 0; j < 4; j++) {
                    int s = g*4 + j;
                    h4[g][j] = __expf(delta*Aa[s])*h4[g][j] + du*Bv[g][j];
                }
        }
    }
    sumdq[(long)(b*NC + c)*D_INNER + d] = sumd;
    long o = ((long)(b*NC + c)*D_STATE)*D_INNER + d;
    #pragma unroll
    for (int s = 0; s < D_STATE; s++)
        Q[o + (long)s*D_INNER] = h4[s >> 2][s & 3];
}

// ---------------------------------------------------------------------------
// Scan phase A, xc path (r10-verified): xc pre-computed by xproj (xcb).
// ---------------------------------------------------------------------------
template<int CHUNK_T>
__global__ __launch_bounds__(256) void scan_partA_xc(
    const float* __restrict__ ssm, const bf16* __restrict__ xcb,
    const float* __restrict__ smallf,
    float* __restrict__ sumdq, float* __restrict__ Q,
    const int* __restrict__ flag)
{
    __shared__ float sL[CHUNK_T*SSML];
    __shared__ bf16  sX[CHUNK_T*256];
    const int fastA = flag[1];
    int d = blockIdx.x * 256 + threadIdx.x;
    int c = blockIdx.y, b = blockIdx.z;
    const int NC = gridDim.y;
    int l0 = c * CHUNK_T;
    {
        const float* src = ssm + (long)(b*LL + l0) * SSML;
        for (int idx = threadIdx.x; idx < CHUNK_T*SSML; idx += 256) sL[idx] = src[idx];
        const bf16* xsrc = xcb + (long)(b*LL + l0)*D_INNER + blockIdx.x*256;
        for (int j = threadIdx.x; j < CHUNK_T*32; j += 256) {
            int li = j >> 5, ln = j & 31;
            *(short8*)&sX[li*256 + ln*8] = *(const short8*)&xsrc[(long)li*D_INNER + ln*8];
        }
    }
    f32x4 h4[4];
    #pragma unroll
    for (int g = 0; g < 4; g++) h4[g] = f32x4{0.f, 0.f, 0.f, 0.f};
    float Aa[D_STATE];
    if (!fastA) {
        #pragma unroll
        for (int s = 0; s < D_STATE; s++) Aa[s] = smallf[OFF_AA + d*D_STATE + s];
    }
    float wdt  = smallf[OFF_WDT + d];
    float bdtv = smallf[OFF_BDT + d];
    __syncthreads();
    float sumd = 0.f;
    #pragma unroll 4
    for (int li = 0; li < CHUNK_T; li++) {
        float xc = bf2f(sX[li*256 + threadIdx.x]);
        const float* row = &sL[li*SSML];
        f32x4 Bv[4];
        #pragma unroll
        for (int g = 0; g < 4; g++) Bv[g] = *(const f32x4*)(row + g*4);
        float delta, r;
        softplus_r(row[32]*wdt + bdtv, delta, r);
        sumd += delta;
        float du = delta * xc;
        if (fastA) {
            float r2 = r*r, r3 = r2*r, r4 = r2*r2;
            f32x4 p0; p0[0]=r; p0[1]=r2; p0[2]=r3; p0[3]=r4;
            float s8 = r4*r4, s12 = s8*r4;
            h4[0] = p0*h4[0]       + du*Bv[0];
            h4[1] = (p0*r4)*h4[1]  + du*Bv[1];
            h4[2] = (p0*s8)*h4[2]  + du*Bv[2];
            h4[3] = (p0*s12)*h4[3] + du*Bv[3];
        } else {
            #pragma unroll
            for (int g = 0; g < 4; g++)
                #pragma unroll
                for (int j = 0; j < 4; j++) {
                    int s = g*4 + j;
                    h4[g][j] = __expf(delta*Aa[s])*h4[g][j] + du*Bv[g][j];
                }
        }
    }
    sumdq[(long)(b*NC + c)*D_INNER + d] = sumd;
    long o = ((long)(b*NC + c)*D_STATE)*D_INNER + d;
    #pragma unroll
    for (int s = 0; s < D_STATE; s++)
        Q[o + (long)s*D_INNER] = h4[s >> 2][s & 3];
}

// ---------------------------------------------------------------------------
// Scan phase B: combine chunks per (b,d,s); P recomputed from sumd.
// ---------------------------------------------------------------------------
__global__ __launch_bounds__(256) void scan_combine(
    const float* __restrict__ sumdq, float* __restrict__ Q_hst,
    const float* __restrict__ smallf, int NC)
{
    int t = blockIdx.x * 256 + threadIdx.x;   // (b,s,d): d fastest
    int d = t & (D_INNER - 1);
    int s = (t >> 11) & (D_STATE - 1);
    int b = t >> 15;
    float Aa = smallf[OFF_AA + d*D_STATE + s];
    float h = 0.f;
    #pragma unroll 4
    for (int c = 0; c < NC; c++) {
        float sd = sumdq[(long)(b*NC + c)*D_INNER + d];
        long idx = ((long)(b*NC + c)*D_STATE + s)*D_INNER + d;
        float q = Q_hst[idx];
        Q_hst[idx] = h;
        h = __expf(Aa*sd)*h + q;
    }
}

// ---------------------------------------------------------------------------
// Scan phase C (r6-verified fallback): packed-f32; x AND z prefetched.
// ---------------------------------------------------------------------------
template<int CHUNK_T>
__global__ __launch_bounds__(256) void scan_partC(
    const float* __restrict__ ssm, bf16* __restrict__ xz,
    const float* __restrict__ smallf, const float* __restrict__ hst,
    const int* __restrict__ flag)
{
    __shared__ float sL[CHUNK_T*SSML];
    __shared__ bf16  sX[CHUNK_T*256];
    __shared__ bf16  sZ[CHUNK_T*256];
    const int fastA = flag[1];
    int d = blockIdx.x * 256 + threadIdx.x;
    int c = blockIdx.y, b = blockIdx.z;
    const int NC = gridDim.y;
    int l0 = c * CHUNK_T;
    {
        const float* src = ssm + (long)(b*LL + l0) * SSML;
        for (int idx = threadIdx.x; idx < CHUNK_T*SSML; idx += 256) sL[idx] = src[idx];
        const bf16* xsrc = xz + (long)(b*LL + l0)*4096 + blockIdx.x*256;
        for (int j = threadIdx.x; j < CHUNK_T*32; j += 256) {
            int li = j >> 5, ln = j & 31;
            *(short8*)&sX[li*256 + ln*8] = *(const short8*)&xsrc[(long)li*4096 + ln*8];
            *(short8*)&sZ[li*256 + ln*8] = *(const short8*)&xsrc[(long)li*4096 + D_INNER + ln*8];
        }
    }
    f32x4 h4[4];
    long o = ((long)(b*NC + c)*D_STATE)*D_INNER + d;
    #pragma unroll
    for (int s = 0; s < D_STATE; s++) h4[s >> 2][s & 3] = hst[o + (long)s*D_INNER];
    float Aa[D_STATE];
    if (!fastA) {
        #pragma unroll
        for (int s = 0; s < D_STATE; s++) Aa[s] = smallf[OFF_AA + d*D_STATE + s];
    }
    f32x4 cw4 = *(const f32x4*)&smallf[OFF_CW + d*4];
    float cbv  = smallf[OFF_CB + d];
    float wdt  = smallf[OFF_WDT + d];
    float bdtv = smallf[OFF_BDT + d];
    float Dv   = smallf[OFF_D + d];
    float win[3];
    #pragma unroll
    for (int k = 0; k < 3; k++) {
        int ls = l0 - 3 + k;
        win[k] = (ls >= 0) ? bf2f(xz[((long)(b*LL + ls))*4096 + d]) : 0.f;
    }
    __syncthreads();
    #pragma unroll 2
    for (int li = 0; li < CHUNK_T; li++) {
        long bl = (long)(b*LL + l0 + li);
        float xnew = bf2f(sX[li*256 + threadIdx.x]);
        float convv = cbv + win[0]*cw4[0] + win[1]*cw4[1] + win[2]*cw4[2] + xnew*cw4[3];
        win[0] = win[1]; win[1] = win[2]; win[2] = xnew;
        float xc = siluf(convv);
        const float* row = &sL[li*SSML];
        f32x4 Bv[4], Cv[4];
        #pragma unroll
        for (int g = 0; g < 4; g++) {
            Bv[g] = *(const f32x4*)(row + g*4);
            Cv[g] = *(const f32x4*)(row + 16 + g*4);
        }
        float delta, r;
        softplus_r(row[32]*wdt + bdtv, delta, r);
        float du = delta * xc;
        f32x4 yacc = f32x4{0.f, 0.f, 0.f, 0.f};
        if (fastA) {
            float r2 = r*r, r3 = r2*r, r4 = r2*r2;
            f32x4 p0; p0[0]=r; p0[1]=r2; p0[2]=r3; p0[3]=r4;
            float s8 = r4*r4, s12 = s8*r4;
            h4[0] = p0*h4[0]       + du*Bv[0];
            h4[1] = (p0*r4)*h4[1]  + du*Bv[1];
            h4[2] = (p0*s8)*h4[2]  + du*Bv[2];
            h4[3] = (p0*s12)*h4[3] + du*Bv[3];
            yacc = yacc + h4[0]*Cv[0];
            yacc = yacc + h4[1]*Cv[1];
            yacc = yacc + h4[2]*Cv[2];
            yacc = yacc + h4[3]*Cv[3];
        } else {
            #pragma unroll
            for (int g = 0; g < 4; g++)
                #pragma unroll
                for (int j = 0; j < 4; j++) {
                    int s = g*4 + j;
                    h4[g][j] = __expf(delta*Aa[s])*h4[g][j] + du*Bv[g][j];
                    yacc[j] += h4[g][j]*Cv[g][j];
                }
        }
        float yv = (yacc[0] + yacc[1]) + (yacc[2] + yacc[3]);
        yv += xc * Dv;
        float z = bf2f(sZ[li*256 + threadIdx.x]);
        yv *= siluf(z);
        xz[bl*4096 + D_INNER + d] = __float2bfloat16(yv);
    }
}

// ---------------------------------------------------------------------------
// Scan phase C, xc path (r10-verified): xc from xcb — no conv window.
// ---------------------------------------------------------------------------
template<int CHUNK_T>
__global__ __launch_bounds__(256) void scan_partC_xc(
    const float* __restrict__ ssm, bf16* __restrict__ xz,
    const bf16* __restrict__ xcb,
    const float* __restrict__ smallf, const float* __restrict__ hst,
    const int* __restrict__ flag)
{
    __shared__ float sL[CHUNK_T*SSML];
    __shared__ bf16  sX[CHUNK_T*256];
    __shared__ bf16  sZ[CHUNK_T*256];
    const int fastA = flag[1];
    int d = blockIdx.x * 256 + threadIdx.x;
    int c = blockIdx.y, b = blockIdx.z;
    const int NC = gridDim.y;
    int l0 = c * CHUNK_T;
    {
        const float* src = ssm + (long)(b*LL + l0) * SSML;
        for (int idx = threadIdx.x; idx < CHUNK_T*SSML; idx += 256) sL[idx] = src[idx];
        const bf16* xcs = xcb + (long)(b*LL + l0)*D_INNER + blockIdx.x*256;
        const bf16* zs  = xz  + (long)(b*LL + l0)*4096 + D_INNER + blockIdx.x*256;
        for (int j = threadIdx.x; j < CHUNK_T*32; j += 256) {
            int li = j >> 5, ln = j & 31;
            *(short8*)&sX[li*256 + ln*8] = *(const short8*)&xcs[(long)li*D_INNER + ln*8];
            *(short8*)&sZ[li*256 + ln*8] = *(const short8*)&zs[(long)li*4096 + ln*8];
        }
    }
    f32x4 h4[4];
    long o = ((long)(b*NC + c)*D_STATE)*D_INNER + d;
    #pragma unroll
    for (int s = 0; s < D_STATE; s++) h4[s >> 2][s & 3] = hst[o + (long)s*D_INNER];
    float Aa[D_STATE];
    if (!fastA) {
        #pragma unroll
        for (int s = 0; s < D_STATE; s++) Aa[s] = smallf[OFF_AA + d*D_STATE + s];
    }
    float wdt  = smallf[OFF_WDT + d];
    float bdtv = smallf[OFF_BDT + d];
    float Dv   = smallf[OFF_D + d];
    __syncthreads();
    #pragma unroll 2
    for (int li = 0; li < CHUNK_T; li++) {
        long bl = (long)(b*LL + l0 + li);
        float xc = bf2f(sX[li*256 + threadIdx.x]);
        const float* row = &sL[li*SSML];
        f32x4 Bv[4], Cv[4];
        #pragma unroll
        for (int g = 0; g < 4; g++) {
            Bv[g] = *(const f32x4*)(row + g*4);
            Cv[g] = *(const f32x4*)(row + 16 + g*4);
        }
        float delta, r;
        softplus_r(row[32]*wdt + bdtv, delta, r);
        float du = delta * xc;
        f32x4 yacc = f32x4{0.f, 0.f, 0.f, 0.f};
        if (fastA) {
            float r2 = r*r, r3 = r2*r, r4 = r2*r2;
            f32x4 p0; p0[0]=r; p0[1]=r2; p0[2]=r3; p0[3]=r4;
            float s8 = r4*r4, s12 = s8*r4;
            h4[0] = p0*h4[0]       + du*Bv[0];
            h4[1] = (p0*r4)*h4[1]  + du*Bv[1];
            h4[2] = (p0*s8)*h4[2]  + du*Bv[2];
            h4[3] = (p0*s12)*h4[3] + du*Bv[3];
            yacc = yacc + h4[0]*Cv[0];
            yacc = yacc + h4[1]*Cv[1];
            yacc = yacc + h4[2]*Cv[2];
            yacc = yacc + h4[3]*Cv[3];
        } else {
            #pragma unroll
            for (int g = 0; g < 4; g++)
                #pragma unroll
                for (int j = 0; j < 4; j++) {
                    int s = g*4 + j;
                    h4[g][j] = __expf(delta*Aa[s])*h4[g][j] + du*Bv[g][j];
                    yacc[j] += h4[g][j]*Cv[g][j];
                }
        }
        float yv = (yacc[0] + yacc[1]) + (yacc[2] + yacc[3]);
        yv += xc * Dv;
        float z = bf2f(sZ[li*256 + threadIdx.x]);
        yv *= siluf(z);
        xz[bl*4096 + D_INNER + d] = __float2bfloat16(yv);
    }
}

// ---------------------------------------------------------------------------
extern "C" void kernel_launch(void* const* d_in, const int* in_sizes, int n_in,
                              void* d_out, int out_size, void* d_ws, size_t ws_size,
                              hipStream_t stream)
{
    char* ws = (char*)d_ws;
    bf16*  xz     = (bf16*) (ws);               // 33,554,432
    bf16*  wxpb   = (bf16*) (ws + 33554432);    //    524,288
    float* ssm    = (float*)(ws + 34078720);    //    589,824
    float* sumdq  = (float*)(ws + 34668544);    //  1,048,576
    float* Q      = (float*)(ws + 35717120);    // 16,777,216
    float* smallf = (float*)(ws + 52494336);    //    196,608
    int*   flag   = (int*)  (ws + 52690944);    //         64
    bf16*  woutb  = (bf16*) (ws + 52691008);    //  4,194,304  end: 56,885,312
    bf16*  xcb    = (bf16*) (ws + 56885312);    // 16,777,216  end: 73,662,528
    // xb and winb ALIAS Q (dead before scan writes Q)
    bf16*  xb     = (bf16*) (ws + 35717120);
    bf16*  winb   = (bf16*) (ws + 35717120 + 8388608);
    const bool big  = ws_size >= 56885312;
    const bool big2 = ws_size >= 73662528;   // xc-fusion path (r10)

    // 0) dtype probe + flag init
    dtype_probe<<<1, 64, 0, stream>>>((const unsigned short*)d_in[7], flag);

    // 1) weight prep (+ zero ssm, + A-structure check -> flag[1])
    cvt_prep<<<(N_WXPB + N_SMALL + N_SSMZ)/256, 256, 0, stream>>>(
        d_in[4], d_in[2], d_in[3], d_in[5], d_in[6], d_in[7], d_in[8],
        wxpb, smallf, ssm, flag);

    // 2) xz = x @ W_in.T  (M=4096, N=4096, K=1024) — 8-phase gemm8x (r11)
    if (big) {
        cvt_all<<<1310720/256, 256, 0, stream>>>(
            d_in[0], d_in[1], d_in[9], xb, winb, woutb, flag);
        gemm8x<<<dim3(16, 16), 512, 0, stream>>>(xb, winb, xz);
    } else {
        gemm_dual<<<dim3(32, 32), 256, 0, stream>>>(
            d_in[0], D_MODEL, d_in[1], D_MODEL, xz, 2*D_INNER, D_MODEL, flag, 1, 1, 0);
    }

    // 3) ssm += conv+silu(x_in) @ Wxp.T  (+ spill xc to xcb when big2)
    xproj_fused<<<dim3(XSPLIT, 32), 256, 0, stream>>>(
        xz, wxpb, smallf, ssm, big2 ? xcb : (bf16*)nullptr);

    // 4) chunked selective scan (xc path when big2)
    {
        dim3 g(D_INNER/256, NCHUNK, BB);
        if (big2) {
            scan_partA_xc<CHUNK><<<g, 256, 0, stream>>>(ssm, xcb, smallf, sumdq, Q, flag);
            scan_combine<<<(BB*D_STATE*D_INNER)/256, 256, 0, stream>>>(sumdq, Q, smallf, NCHUNK);
            scan_partC_xc<CHUNK><<<g, 256, 0, stream>>>(ssm, xz, xcb, smallf, Q, flag);
        } else {
            scan_partA<CHUNK><<<g, 256, 0, stream>>>(ssm, xz, smallf, sumdq, Q, flag);
            scan_combine<<<(BB*D_STATE*D_INNER)/256, 256, 0, stream>>>(sumdq, Q, smallf, NCHUNK);
            scan_partC<CHUNK><<<g, 256, 0, stream>>>(ssm, xz, smallf, Q, flag);
        }
    }

    // 5) out = y @ W_out.T  (M=4096, N=1024, K=2048) — r6-verified gemm_n64
    if (big) {
        gemm_n64<<<dim3(D_MODEL/64, 32), 256, 0, stream>>>(
            xz + D_INNER, 2*D_INNER, woutb, D_INNER, d_out, D_MODEL, D_INNER, flag, 0, 1);
    } else {
        gemm_n64<<<dim3(D_MODEL/64, 32), 256, 0, stream>>>(
            xz + D_INNER, 2*D_INNER, d_in[9], D_INNER, d_out, D_MODEL, D_INNER, flag, 1, 1);
    }
}

// Round 12
// 282.744 us; speedup vs baseline: 1.0301x; 1.0301x over previous
//
#include <hip/hip_runtime.h>
#include <hip/hip_bf16.h>
#include <math.h>

// SelectiveSSM: D_MODEL=1024, D_STATE=16, D_CONV=4, EXPAND=2, B=2, L=2048
#define D_MODEL 1024
#define D_STATE 16
#define D_CONV  4
#define D_INNER 2048
#define BB      2
#define LL      2048
#define BLROWS  (BB*LL)       // 4096
#define NCHUNK  64
#define CHUNK   (LL/NCHUNK)   // 32
#define SSML    36            // padded ssm row stride (floats)
#define XSPLIT  16            // split-K factor for xproj

typedef __hip_bfloat16 bf16;
typedef __attribute__((ext_vector_type(8))) short short8;
typedef __attribute__((ext_vector_type(4))) float f32x4;

__device__ __forceinline__ float ldf(const void* p, long i, int isbf) {
    return isbf ? __bfloat162float(((const bf16*)p)[i]) : ((const float*)p)[i];
}
__device__ __forceinline__ short bfbits(float f) {
    bf16 h = __float2bfloat16(f);
    return *(short*)&h;
}
__device__ __forceinline__ float bits2f(short s) {
    bf16 h; *(short*)&h = s; return __bfloat162float(h);
}
__device__ __forceinline__ float bf2f(bf16 h) { return __bfloat162float(h); }
__device__ __forceinline__ float siluf(float x) {
    return __fdividef(x, 1.f + __expf(-x));
}
// fused stable softplus + exp-negation: delta = log(1+exp(x)), r = exp(-delta)
__device__ __forceinline__ void softplus_r(float x, float& delta, float& r) {
    float e = __expf(-fabsf(x));
    float t = 1.f + e;
    delta = fmaxf(x, 0.f) + __logf(t);
    r = __fdividef((x >= 0.f) ? e : 1.f, t);
}

// smallf float offsets
#define OFF_CW   0
#define OFF_CB   8192
#define OFF_WDT  10240
#define OFF_BDT  12288
#define OFF_AA   14336
#define OFF_D    47104
#define N_SMALL  49152
#define N_WXPB   (128*2048)
#define N_SSMZ   (BLROWS*SSML)

#define G_LDS16(gptr, lptr) __builtin_amdgcn_global_load_lds( \
    (const __attribute__((address_space(1))) void*)(gptr),    \
    (__attribute__((address_space(3))) void*)(lptr), 16, 0, 0)

// ---------------------------------------------------------------------------
// dtype probe + flag init. flag[0]=isbf, flag[1]=fastA.
// ---------------------------------------------------------------------------
__global__ void dtype_probe(const unsigned short* __restrict__ alog, int* __restrict__ flag) {
    if (threadIdx.x == 0) { flag[0] = (alog[1] != 0) ? 1 : 0; flag[1] = 1; }
}

// ---------------------------------------------------------------------------
// prep: padded bf16 W_xproj + fp32 smalls + zero ssm + A-structure check
// ---------------------------------------------------------------------------
__global__ __launch_bounds__(256) void cvt_prep(
    const void* __restrict__ Wxp, const void* __restrict__ cw,
    const void* __restrict__ cb, const void* __restrict__ wdt,
    const void* __restrict__ bdt, const void* __restrict__ alog,
    const void* __restrict__ Dp,
    bf16* __restrict__ wxpb, float* __restrict__ smallf,
    float* __restrict__ ssm, int* __restrict__ flag)
{
    const int isbf = flag[0];
    int idx = blockIdx.x * 256 + threadIdx.x;
    if (idx < N_WXPB) {
        int row = idx >> 11, col = idx & 2047;
        float v = (row < 33) ? ldf(Wxp, (long)row*2048 + col, isbf) : 0.f;
        wxpb[idx] = __float2bfloat16(v);
        return;
    }
    int j = idx - N_WXPB;
    if      (j < 8192)  smallf[OFF_CW  + j]         = ldf(cw,  j, isbf);
    else if (j < 10240) smallf[OFF_CB  + j - 8192]  = ldf(cb,  j - 8192, isbf);
    else if (j < 12288) smallf[OFF_WDT + j - 10240] = ldf(wdt, j - 10240, isbf);
    else if (j < 14336) smallf[OFF_BDT + j - 12288] = ldf(bdt, j - 12288, isbf);
    else if (j < 47104) {
        int jj = j - 14336;                 // = d*16 + s
        float aa = -__expf(ldf(alog, jj, isbf));
        smallf[OFF_AA + jj] = aa;
        int s = jj & 15;
        if (fabsf(aa + (float)(s+1)) > 1e-3f) flag[1] = 0;
    }
    else if (j < 49152) smallf[OFF_D   + j - 47104] = ldf(Dp,  j - 47104, isbf);
    else {
        int z = j - N_SMALL;
        if (z < N_SSMZ) ssm[z] = 0.f;
    }
}

// ---------------------------------------------------------------------------
// merged x/W_in/W_out -> bf16 conversion (8 elems/thread, one launch)
// ---------------------------------------------------------------------------
__global__ __launch_bounds__(256) void cvt_all(
    const void* __restrict__ x, const void* __restrict__ win,
    const void* __restrict__ wout,
    bf16* __restrict__ xb, bf16* __restrict__ winb, bf16* __restrict__ woutb,
    const int* __restrict__ flagp)
{
    const int isbf = *flagp;
    int i = blockIdx.x * 256 + threadIdx.x;
    const void* src; bf16* dst; long o;
    if (i < 524288)       { src = x;    dst = xb;    o = (long)i * 8; }
    else if (i < 1048576) { src = win;  dst = winb;  o = (long)(i - 524288) * 8; }
    else if (i < 1310720) { src = wout; dst = woutb; o = (long)(i - 1048576) * 8; }
    else return;
    short8 v;
    if (isbf) {
        v = *(const short8*)((const bf16*)src + o);
    } else {
        const float* s = (const float*)src + o;
        f32x4 u = *(const f32x4*)s, w = *(const f32x4*)(s + 4);
        v[0]=bfbits(u[0]); v[1]=bfbits(u[1]); v[2]=bfbits(u[2]); v[3]=bfbits(u[3]);
        v[4]=bfbits(w[0]); v[5]=bfbits(w[1]); v[6]=bfbits(w[2]); v[7]=bfbits(w[3]);
    }
    *(short8*)(dst + o) = v;
}

// ---------------------------------------------------------------------------
// gemm8s (r12): 8-phase 256x256 GEMM with SNAKE quadrant order + fragment
// reuse. r11's gemm8x re-read af/bfv every phase (48 ds_read/kt/wave, 2x
// gemm8p) — LDS-read traffic ate the interleave gain (both 51us/25% Mfma).
// Snake order (qm,qn) = (0,1),(0,0),(1,0),(1,1): af re-read only on qm
// change (p0,p2), bfv only on qn change (p0,p1,p3; p2 reuses p1's) ->
// 28 reads/kt/wave. Staging (re-race-checked for this order):
//   p0: A1(kt+1)->As[buf^1][1]  (last read kt-1 p2)
//   p1: B1(kt+1)->Bs[buf^1][1]  (last read kt-1 p3, 2+ barriers ago)
//   p2: A0(kt+2)->As[buf][0]    (read this kt at p0 only)
//   p3: B0(kt+2)->Bs[buf][0]    (read this kt at p1 only)
// vmcnt identical to the r11-verified schedule (same stage count/order).
// ---------------------------------------------------------------------------
__global__ __launch_bounds__(512) void gemm8s(
    const bf16* __restrict__ A,    // [4096][1024] row-major
    const bf16* __restrict__ Bm,   // [4096][1024] row-major
    bf16* __restrict__ Cp)         // [4096][4096]
{
    __shared__ bf16 As[2][2][128*64];
    __shared__ bf16 Bs[2][2][128*64];
    const int t    = threadIdx.x;          // 0..511
    const int lane = t & 63;
    const int w    = t >> 6;               // 0..7
    const int rm   = w >> 2;               // 0..1 row-sub within quadrant
    const int cn   = w & 3;                // 0..3 col-sub within quadrant
    const int bm   = blockIdx.y, bn = blockIdx.x;
    const int quad = lane >> 4, l16 = lane & 15;
    const int NT   = 16;                   // K=1024 / BK=64

    f32x4 acc[2][2][4][2];
    #pragma unroll
    for (int a = 0; a < 2; a++)
        #pragma unroll
        for (int b = 0; b < 2; b++)
            #pragma unroll
            for (int i = 0; i < 4; i++)
                #pragma unroll
                for (int j = 0; j < 2; j++)
                    acc[a][b][i][j] = f32x4{0.f, 0.f, 0.f, 0.f};

    auto stageA = [&](int bufi, int half, int kt) {
        #pragma unroll
        for (int seg = 0; seg < 2; seg++) {
            int s = seg*512 + t, row = s >> 3, sg = s & 7;
            int col = (sg ^ (row & 7)) * 8;
            G_LDS16(A + ((long)bm*256 + half*128 + row)*1024 + kt*64 + col,
                    &As[bufi][half][s*8]);
        }
    };
    auto stageB = [&](int bufi, int half, int kt) {
        #pragma unroll
        for (int seg = 0; seg < 2; seg++) {
            int s = seg*512 + t, row = s >> 3, sg = s & 7;
            int col = (sg ^ (row & 7)) * 8;
            G_LDS16(Bm + ((long)bn*256 + half*128 + row)*1024 + kt*64 + col,
                    &Bs[bufi][half][s*8]);
        }
    };

    // prologue: tile0 (4 half-tiles) + A0/B0 of tile1; wait tile0 landed.
    stageA(0, 0, 0); stageB(0, 0, 0); stageA(0, 1, 0); stageB(0, 1, 0);
    stageA(1, 0, 1); stageB(1, 0, 1);
    asm volatile("s_waitcnt vmcnt(4)" ::: "memory");
    __builtin_amdgcn_s_barrier();

    short8 af[4][2], bfv[2][2];
    for (int kt = 0; kt < NT; ++kt) {
        const int buf = kt & 1;
        #pragma unroll
        for (int p = 0; p < 4; ++p) {
            // snake: (qm,qn) = (0,1),(0,0),(1,0),(1,1)
            const int qm = p >> 1;
            const int qn = (p == 0 || p == 3) ? 1 : 0;
            if (p == 0 || p == 2) {
                #pragma unroll
                for (int fi = 0; fi < 4; fi++)
                    #pragma unroll
                    for (int kk = 0; kk < 2; kk++) {
                        int ar = rm*64 + fi*16 + l16;
                        int c = kk*4 + quad;
                        af[fi][kk] = *(const short8*)&As[buf][qm][ar*64 + ((c ^ (ar & 7))*8)];
                    }
            }
            if (p != 2) {
                #pragma unroll
                for (int fj = 0; fj < 2; fj++)
                    #pragma unroll
                    for (int kk = 0; kk < 2; kk++) {
                        int br = cn*32 + fj*16 + l16;
                        int c = kk*4 + quad;
                        bfv[fj][kk] = *(const short8*)&Bs[buf][qn][br*64 + ((c ^ (br & 7))*8)];
                    }
            }
            if      (p == 0) { if (kt + 1 < NT) stageA(buf ^ 1, 1, kt + 1); }
            else if (p == 1) { if (kt + 1 < NT) stageB(buf ^ 1, 1, kt + 1); }
            else if (p == 2) { if (kt + 2 < NT) stageA(buf, 0, kt + 2); }
            else             { if (kt + 2 < NT) stageB(buf, 0, kt + 2); }
            __builtin_amdgcn_s_barrier();
            asm volatile("s_waitcnt lgkmcnt(0)" ::: "memory");
            __builtin_amdgcn_sched_barrier(0);
            __builtin_amdgcn_s_setprio(1);
            #pragma unroll
            for (int kk = 0; kk < 2; kk++)
                #pragma unroll
                for (int fi = 0; fi < 4; fi++)
                    #pragma unroll
                    for (int fj = 0; fj < 2; fj++)
                        acc[qm][qn][fi][fj] = __builtin_amdgcn_mfma_f32_16x16x32_bf16(
                            af[fi][kk], bfv[fj][kk], acc[qm][qn][fi][fj], 0, 0, 0);
            __builtin_amdgcn_s_setprio(0);
            __builtin_amdgcn_sched_barrier(0);
            if (p == 3) {
                if (kt == NT - 2)     { asm volatile("s_waitcnt vmcnt(0)" ::: "memory"); }
                else if (kt < NT - 2) { asm volatile("s_waitcnt vmcnt(4)" ::: "memory"); }
            }
            __builtin_amdgcn_sched_barrier(0);
            __builtin_amdgcn_s_barrier();
        }
    }

    #pragma unroll
    for (int qm = 0; qm < 2; qm++)
        #pragma unroll
        for (int qn = 0; qn < 2; qn++)
            #pragma unroll
            for (int fi = 0; fi < 4; fi++)
                #pragma unroll
                for (int fj = 0; fj < 2; fj++)
                    #pragma unroll
                    for (int r = 0; r < 4; r++) {
                        int row = bm*256 + qm*128 + rm*64 + fi*16 + quad*4 + r;
                        int col = bn*256 + qn*128 + cn*32 + fj*16 + l16;
                        Cp[(long)row * 4096 + col] = __float2bfloat16(acc[qm][qn][fi][fj][r]);
                    }
}

// ---------------------------------------------------------------------------
// GEMM fallback (small-ws path): 128x128 tile, BK=64, XOR-swizzled LDS
// ---------------------------------------------------------------------------
__global__ __launch_bounds__(256) void gemm_dual(
    const void* __restrict__ A, int lda,
    const void* __restrict__ Bm, int ldb,
    void* __restrict__ Cp, int ldc, int K,
    const int* __restrict__ flagp, int amode, int bmode, int cmode)
{
    const int isbf = *flagp;
    const int a_bf = amode ? isbf : 1;
    const int b_bf = bmode ? isbf : 1;
    const int c_bf = cmode ? isbf : 1;

    __shared__ bf16 As[128*64];
    __shared__ bf16 Bs[128*64];
    const int t    = threadIdx.x;
    const int lane = t & 63;
    const int w    = t >> 6;
    const int wm   = w >> 1, wn = w & 1;
    const int bm   = blockIdx.y, bn = blockIdx.x;
    const int quad = lane >> 4, l16 = lane & 15;

    f32x4 acc[4][4];
    #pragma unroll
    for (int i = 0; i < 4; i++)
        #pragma unroll
        for (int j = 0; j < 4; j++)
            acc[i][j] = f32x4{0.f, 0.f, 0.f, 0.f};

    for (int k0 = 0; k0 < K; k0 += 64) {
        __syncthreads();
        if (a_bf) {
            #pragma unroll
            for (int seg = 0; seg < 4; seg++) {
                int s = seg*256 + t, row = s >> 3, sg = s & 7;
                int col = (sg ^ (row & 7)) * 8;
                const bf16* ga = (const bf16*)A + ((long)bm*128 + row)*(long)lda + k0 + col;
                G_LDS16(ga, &As[row*64 + sg*8]);
            }
        } else {
            #pragma unroll
            for (int seg = 0; seg < 4; seg++) {
                int s = seg*256 + t, row = s >> 3, sg = s & 7;
                int col = (sg ^ (row & 7)) * 8;
                const float* ap = (const float*)A + ((long)bm*128 + row)*(long)lda + k0 + col;
                f32x4 u = *(const f32x4*)ap, v = *(const f32x4*)(ap + 4);
                short8 va;
                va[0]=bfbits(u[0]); va[1]=bfbits(u[1]); va[2]=bfbits(u[2]); va[3]=bfbits(u[3]);
                va[4]=bfbits(v[0]); va[5]=bfbits(v[1]); va[6]=bfbits(v[2]); va[7]=bfbits(v[3]);
                *(short8*)&As[row*64 + sg*8] = va;
            }
        }
        if (b_bf) {
            #pragma unroll
            for (int seg = 0; seg < 4; seg++) {
                int s = seg*256 + t, row = s >> 3, sg = s & 7;
                int col = (sg ^ (row & 7)) * 8;
                const bf16* gb = (const bf16*)Bm + ((long)bn*128 + row)*(long)ldb + k0 + col;
                G_LDS16(gb, &Bs[row*64 + sg*8]);
            }
        } else {
            #pragma unroll
            for (int seg = 0; seg < 4; seg++) {
                int s = seg*256 + t, row = s >> 3, sg = s & 7;
                int col = (sg ^ (row & 7)) * 8;
                const float* bp = (const float*)Bm + ((long)bn*128 + row)*(long)ldb + k0 + col;
                f32x4 u = *(const f32x4*)bp, v = *(const f32x4*)(bp + 4);
                short8 vb;
                vb[0]=bfbits(u[0]); vb[1]=bfbits(u[1]); vb[2]=bfbits(u[2]); vb[3]=bfbits(u[3]);
                vb[4]=bfbits(v[0]); vb[5]=bfbits(v[1]); vb[6]=bfbits(v[2]); vb[7]=bfbits(v[3]);
                *(short8*)&Bs[row*64 + sg*8] = vb;
            }
        }
        __syncthreads();

        #pragma unroll
        for (int kk = 0; kk < 64; kk += 32) {
            const int cbase = kk >> 3;
            short8 af[4], bfr[4];
            #pragma unroll
            for (int mi = 0; mi < 4; mi++) {
                int row = wm*64 + mi*16 + l16;
                int c = cbase + quad;
                af[mi] = *(const short8*)&As[row*64 + ((c ^ (row & 7))*8)];
            }
            #pragma unroll
            for (int ni = 0; ni < 4; ni++) {
                int row = wn*64 + ni*16 + l16;
                int c = cbase + quad;
                bfr[ni] = *(const short8*)&Bs[row*64 + ((c ^ (row & 7))*8)];
            }
            #pragma unroll
            for (int mi = 0; mi < 4; mi++)
                #pragma unroll
                for (int ni = 0; ni < 4; ni++)
                    acc[mi][ni] = __builtin_amdgcn_mfma_f32_16x16x32_bf16(
                        af[mi], bfr[ni], acc[mi][ni], 0, 0, 0);
        }
    }

    #pragma unroll
    for (int mi = 0; mi < 4; mi++)
        #pragma unroll
        for (int ni = 0; ni < 4; ni++)
            #pragma unroll
            for (int r = 0; r < 4; r++) {
                int row = bm*128 + wm*64 + mi*16 + quad*4 + r;
                int col = bn*128 + wn*64 + ni*16 + l16;
                float val = acc[mi][ni][r];
                if (c_bf) ((bf16*)Cp)[(long)row * ldc + col] = __float2bfloat16(val);
                else      ((float*)Cp)[(long)row * ldc + col] = val;
            }
}

// ---------------------------------------------------------------------------
// GEMM2 (r6-verified): 128x64 tile, BK=64, XOR swizzle. Grid (16,32).
// ---------------------------------------------------------------------------
__global__ __launch_bounds__(256) void gemm_n64(
    const bf16* __restrict__ A, int lda,
    const void* __restrict__ Bm, int ldb,
    void* __restrict__ Cp, int ldc, int K,
    const int* __restrict__ flagp, int bmode, int cmode)
{
    const int isbf = *flagp;
    const int b_bf = bmode ? isbf : 1;
    const int c_bf = cmode ? isbf : 1;

    __shared__ bf16 As[128*64];
    __shared__ bf16 Bs[64*64];
    const int t    = threadIdx.x;
    const int lane = t & 63;
    const int w    = t >> 6;
    const int wm   = w >> 1, wn = w & 1;
    const int bm   = blockIdx.y, bn = blockIdx.x;
    const int quad = lane >> 4, l16 = lane & 15;

    f32x4 acc[4][2];
    #pragma unroll
    for (int i = 0; i < 4; i++)
        #pragma unroll
        for (int j = 0; j < 2; j++)
            acc[i][j] = f32x4{0.f, 0.f, 0.f, 0.f};

    for (int k0 = 0; k0 < K; k0 += 64) {
        __syncthreads();
        #pragma unroll
        for (int seg = 0; seg < 4; seg++) {
            int s = seg*256 + t, row = s >> 3, sg = s & 7;
            int col = (sg ^ (row & 7)) * 8;
            const bf16* ga = A + ((long)bm*128 + row)*(long)lda + k0 + col;
            G_LDS16(ga, &As[row*64 + sg*8]);
        }
        if (b_bf) {
            #pragma unroll
            for (int seg = 0; seg < 2; seg++) {
                int s = seg*256 + t, row = s >> 3, sg = s & 7;
                int col = (sg ^ (row & 7)) * 8;
                const bf16* gb = (const bf16*)Bm + ((long)bn*64 + row)*(long)ldb + k0 + col;
                G_LDS16(gb, &Bs[row*64 + sg*8]);
            }
        } else {
            #pragma unroll
            for (int seg = 0; seg < 2; seg++) {
                int s = seg*256 + t, row = s >> 3, sg = s & 7;
                int col = (sg ^ (row & 7)) * 8;
                const float* bp = (const float*)Bm + ((long)bn*64 + row)*(long)ldb + k0 + col;
                f32x4 u = *(const f32x4*)bp, v = *(const f32x4*)(bp + 4);
                short8 vb;
                vb[0]=bfbits(u[0]); vb[1]=bfbits(u[1]); vb[2]=bfbits(u[2]); vb[3]=bfbits(u[3]);
                vb[4]=bfbits(v[0]); vb[5]=bfbits(v[1]); vb[6]=bfbits(v[2]); vb[7]=bfbits(v[3]);
                *(short8*)&Bs[row*64 + sg*8] = vb;
            }
        }
        __syncthreads();

        #pragma unroll
        for (int kk = 0; kk < 64; kk += 32) {
            const int cbase = kk >> 3;
            short8 af[4], bfr[2];
            #pragma unroll
            for (int mi = 0; mi < 4; mi++) {
                int row = wm*64 + mi*16 + l16;
                int c = cbase + quad;
                af[mi] = *(const short8*)&As[row*64 + ((c ^ (row & 7))*8)];
            }
            #pragma unroll
            for (int ni = 0; ni < 2; ni++) {
                int row = wn*32 + ni*16 + l16;
                int c = cbase + quad;
                bfr[ni] = *(const short8*)&Bs[row*64 + ((c ^ (row & 7))*8)];
            }
            #pragma unroll
            for (int mi = 0; mi < 4; mi++)
                #pragma unroll
                for (int ni = 0; ni < 2; ni++)
                    acc[mi][ni] = __builtin_amdgcn_mfma_f32_16x16x32_bf16(
                        af[mi], bfr[ni], acc[mi][ni], 0, 0, 0);
        }
    }

    #pragma unroll
    for (int mi = 0; mi < 4; mi++)
        #pragma unroll
        for (int ni = 0; ni < 2; ni++)
            #pragma unroll
            for (int r = 0; r < 4; r++) {
                int row = bm*128 + wm*64 + mi*16 + quad*4 + r;
                int col = bn*64 + wn*32 + ni*16 + l16;
                float val = acc[mi][ni][r];
                if (c_bf) ((bf16*)Cp)[(long)row * ldc + col] = __float2bfloat16(val);
                else      ((float*)Cp)[(long)row * ldc + col] = val;
            }
}

// ---------------------------------------------------------------------------
// xproj fused, split-K: ssm[bl, :] += partial(conv+silu(x_in) @ Wxp.T).
// r10: optionally spill the staged xc tile (silu(conv)) to global xcb.
// ---------------------------------------------------------------------------
__global__ __launch_bounds__(256) void xproj_fused(
    const bf16* __restrict__ xz, const bf16* __restrict__ wxpb,
    const float* __restrict__ smallf, float* __restrict__ ssm,
    bf16* __restrict__ xcb)
{
    const float* cwf = smallf + OFF_CW;
    const float* cbf = smallf + OFF_CB;
    __shared__ bf16 As[128*32];
    __shared__ bf16 Bs[128*32];
    const int t    = threadIdx.x;
    const int lane = t & 63;
    const int w    = t >> 6;
    const int wm   = w >> 1, wn = w & 1;
    const int bm   = blockIdx.y;
    const int ks   = blockIdx.x * (D_INNER / XSPLIT);
    const int quad = lane >> 4, l16 = lane & 15;

    f32x4 acc[4][4];
    #pragma unroll
    for (int i = 0; i < 4; i++)
        #pragma unroll
        for (int j = 0; j < 4; j++)
            acc[i][j] = f32x4{0.f, 0.f, 0.f, 0.f};

    for (int k0 = ks; k0 < ks + D_INNER/XSPLIT; k0 += 32) {
        __syncthreads();
        #pragma unroll
        for (int seg = 0; seg < 2; seg++) {
            int s = seg*256 + t, row = s >> 2, dcol = (s & 3) * 8;
            int blg = bm*128 + row;
            int b = blg >> 11, l = blg & (LL - 1);
            int d0 = k0 + dcol;
            float a[8];
            {
                f32x4 c0 = *(const f32x4*)&cbf[d0], c1 = *(const f32x4*)&cbf[d0+4];
                a[0]=c0[0]; a[1]=c0[1]; a[2]=c0[2]; a[3]=c0[3];
                a[4]=c1[0]; a[5]=c1[1]; a[6]=c1[2]; a[7]=c1[3];
            }
            f32x4 cw4[8];
            #pragma unroll
            for (int j = 0; j < 8; j++) cw4[j] = *(const f32x4*)&cwf[(d0+j)*4];
            #pragma unroll
            for (int kk = 0; kk < D_CONV; kk++) {
                int ls = l - 3 + kk;
                if (ls >= 0) {
                    short8 xv = *(const short8*)&xz[((long)(b*LL + ls))*4096 + d0];
                    #pragma unroll
                    for (int j = 0; j < 8; j++) a[j] += bits2f(xv[j]) * cw4[j][kk];
                }
            }
            short8 va;
            #pragma unroll
            for (int j = 0; j < 8; j++) va[j] = bfbits(siluf(a[j]));
            *(short8*)&As[row*32 + dcol] = va;
            if (xcb) *(short8*)&xcb[(long)blg*D_INNER + d0] = va;
        }
        #pragma unroll
        for (int seg = 0; seg < 2; seg++) {
            int s = seg*256 + t, row = s >> 2, col = (s & 3) * 8;
            const bf16* gb = wxpb + (long)row*D_INNER + k0 + col;
            G_LDS16(gb, &Bs[row*32 + col]);
        }
        __syncthreads();

        short8 af[4], bfr[4];
        #pragma unroll
        for (int mi = 0; mi < 4; mi++)
            af[mi] = *(const short8*)&As[(wm*64 + mi*16 + l16)*32 + quad*8];
        #pragma unroll
        for (int ni = 0; ni < 4; ni++)
            bfr[ni] = *(const short8*)&Bs[(wn*64 + ni*16 + l16)*32 + quad*8];
        #pragma unroll
        for (int mi = 0; mi < 4; mi++)
            #pragma unroll
            for (int ni = 0; ni < 4; ni++)
                acc[mi][ni] = __builtin_amdgcn_mfma_f32_16x16x32_bf16(
                    af[mi], bfr[ni], acc[mi][ni], 0, 0, 0);
    }

    #pragma unroll
    for (int mi = 0; mi < 4; mi++)
        #pragma unroll
        for (int ni = 0; ni < 4; ni++) {
            int col = wn*64 + ni*16 + l16;
            if (col < 33) {
                int newcol = (col == 0) ? 32 : (col - 1);
                #pragma unroll
                for (int r = 0; r < 4; r++) {
                    int row = bm*128 + wm*64 + mi*16 + quad*4 + r;
                    atomicAdd(&ssm[(long)row * SSML + newcol], acc[mi][ni][r]);
                }
            }
        }
}

// ---------------------------------------------------------------------------
// Scan phase A (fallback): packed-f32 h, LDS x-prefetch + conv.
// ---------------------------------------------------------------------------
template<int CHUNK_T>
__global__ __launch_bounds__(256) void scan_partA(
    const float* __restrict__ ssm, const bf16* __restrict__ xz,
    const float* __restrict__ smallf,
    float* __restrict__ sumdq, float* __restrict__ Q,
    const int* __restrict__ flag)
{
    __shared__ float sL[CHUNK_T*SSML];
    __shared__ bf16  sX[CHUNK_T*256];
    const int fastA = flag[1];
    int d = blockIdx.x * 256 + threadIdx.x;
    int c = blockIdx.y, b = blockIdx.z;
    const int NC = gridDim.y;
    int l0 = c * CHUNK_T;
    {
        const float* src = ssm + (long)(b*LL + l0) * SSML;
        for (int idx = threadIdx.x; idx < CHUNK_T*SSML; idx += 256) sL[idx] = src[idx];
        const bf16* xsrc = xz + (long)(b*LL + l0)*4096 + blockIdx.x*256;
        for (int j = threadIdx.x; j < CHUNK_T*32; j += 256) {
            int li = j >> 5, ln = j & 31;
            *(short8*)&sX[li*256 + ln*8] = *(const short8*)&xsrc[(long)li*4096 + ln*8];
        }
    }
    f32x4 h4[4];
    #pragma unroll
    for (int g = 0; g < 4; g++) h4[g] = f32x4{0.f, 0.f, 0.f, 0.f};
    float Aa[D_STATE];
    if (!fastA) {
        #pragma unroll
        for (int s = 0; s < D_STATE; s++) Aa[s] = smallf[OFF_AA + d*D_STATE + s];
    }
    f32x4 cw4 = *(const f32x4*)&smallf[OFF_CW + d*4];
    float cbv  = smallf[OFF_CB + d];
    float wdt  = smallf[OFF_WDT + d];
    float bdtv = smallf[OFF_BDT + d];
    float win[3];
    #pragma unroll
    for (int k = 0; k < 3; k++) {
        int ls = l0 - 3 + k;
        win[k] = (ls >= 0) ? bf2f(xz[((long)(b*LL + ls))*4096 + d]) : 0.f;
    }
    __syncthreads();
    float sumd = 0.f;
    #pragma unroll 4
    for (int li = 0; li < CHUNK_T; li++) {
        float xnew = bf2f(sX[li*256 + threadIdx.x]);
        float convv = cbv + win[0]*cw4[0] + win[1]*cw4[1] + win[2]*cw4[2] + xnew*cw4[3];
        win[0] = win[1]; win[1] = win[2]; win[2] = xnew;
        float xc = siluf(convv);
        const float* row = &sL[li*SSML];
        f32x4 Bv[4];
        #pragma unroll
        for (int g = 0; g < 4; g++) Bv[g] = *(const f32x4*)(row + g*4);
        float delta, r;
        softplus_r(row[32]*wdt + bdtv, delta, r);
        sumd += delta;
        float du = delta * xc;
        if (fastA) {
            float r2 = r*r, r3 = r2*r, r4 = r2*r2;
            f32x4 p0; p0[0]=r; p0[1]=r2; p0[2]=r3; p0[3]=r4;
            float s8 = r4*r4, s12 = s8*r4;
            h4[0] = p0*h4[0]       + du*Bv[0];
            h4[1] = (p0*r4)*h4[1]  + du*Bv[1];
            h4[2] = (p0*s8)*h4[2]  + du*Bv[2];
            h4[3] = (p0*s12)*h4[3] + du*Bv[3];
        } else {
            #pragma unroll
            for (int g = 0; g < 4; g++)
                #pragma unroll
                for (int j = 0; j < 4; j++) {
                    int s = g*4 + j;
                    h4[g][j] = __expf(delta*Aa[s])*h4[g][j] + du*Bv[g][j];
                }
        }
    }
    sumdq[(long)(b*NC + c)*D_INNER + d] = sumd;
    long o = ((long)(b*NC + c)*D_STATE)*D_INNER + d;
    #pragma unroll
    for (int s = 0; s < D_STATE; s++)
        Q[o + (long)s*D_INNER] = h4[s >> 2][s & 3];
}

// ---------------------------------------------------------------------------
// Scan phase A, xc path (r10-verified): xc pre-computed by xproj (xcb).
// ---------------------------------------------------------------------------
template<int CHUNK_T>
__global__ __launch_bounds__(256) void scan_partA_xc(
    const float* __restrict__ ssm, const bf16* __restrict__ xcb,
    const float* __restrict__ smallf,
    float* __restrict__ sumdq, float* __restrict__ Q,
    const int* __restrict__ flag)
{
    __shared__ float sL[CHUNK_T*SSML];
    __shared__ bf16  sX[CHUNK_T*256];
    const int fastA = flag[1];
    int d = blockIdx.x * 256 + threadIdx.x;
    int c = blockIdx.y, b = blockIdx.z;
    const int NC = gridDim.y;
    int l0 = c * CHUNK_T;
    {
        const float* src = ssm + (long)(b*LL + l0) * SSML;
        for (int idx = threadIdx.x; idx < CHUNK_T*SSML; idx += 256) sL[idx] = src[idx];
        const bf16* xsrc = xcb + (long)(b*LL + l0)*D_INNER + blockIdx.x*256;
        for (int j = threadIdx.x; j < CHUNK_T*32; j += 256) {
            int li = j >> 5, ln = j & 31;
            *(short8*)&sX[li*256 + ln*8] = *(const short8*)&xsrc[(long)li*D_INNER + ln*8];
        }
    }
    f32x4 h4[4];
    #pragma unroll
    for (int g = 0; g < 4; g++) h4[g] = f32x4{0.f, 0.f, 0.f, 0.f};
    float Aa[D_STATE];
    if (!fastA) {
        #pragma unroll
        for (int s = 0; s < D_STATE; s++) Aa[s] = smallf[OFF_AA + d*D_STATE + s];
    }
    float wdt  = smallf[OFF_WDT + d];
    float bdtv = smallf[OFF_BDT + d];
    __syncthreads();
    float sumd = 0.f;
    #pragma unroll 4
    for (int li = 0; li < CHUNK_T; li++) {
        float xc = bf2f(sX[li*256 + threadIdx.x]);
        const float* row = &sL[li*SSML];
        f32x4 Bv[4];
        #pragma unroll
        for (int g = 0; g < 4; g++) Bv[g] = *(const f32x4*)(row + g*4);
        float delta, r;
        softplus_r(row[32]*wdt + bdtv, delta, r);
        sumd += delta;
        float du = delta * xc;
        if (fastA) {
            float r2 = r*r, r3 = r2*r, r4 = r2*r2;
            f32x4 p0; p0[0]=r; p0[1]=r2; p0[2]=r3; p0[3]=r4;
            float s8 = r4*r4, s12 = s8*r4;
            h4[0] = p0*h4[0]       + du*Bv[0];
            h4[1] = (p0*r4)*h4[1]  + du*Bv[1];
            h4[2] = (p0*s8)*h4[2]  + du*Bv[2];
            h4[3] = (p0*s12)*h4[3] + du*Bv[3];
        } else {
            #pragma unroll
            for (int g = 0; g < 4; g++)
                #pragma unroll
                for (int j = 0; j < 4; j++) {
                    int s = g*4 + j;
                    h4[g][j] = __expf(delta*Aa[s])*h4[g][j] + du*Bv[g][j];
                }
        }
    }
    sumdq[(long)(b*NC + c)*D_INNER + d] = sumd;
    long o = ((long)(b*NC + c)*D_STATE)*D_INNER + d;
    #pragma unroll
    for (int s = 0; s < D_STATE; s++)
        Q[o + (long)s*D_INNER] = h4[s >> 2][s & 3];
}

// ---------------------------------------------------------------------------
// Scan phase B: combine chunks per (b,d,s); P recomputed from sumd.
// ---------------------------------------------------------------------------
__global__ __launch_bounds__(256) void scan_combine(
    const float* __restrict__ sumdq, float* __restrict__ Q_hst,
    const float* __restrict__ smallf, int NC)
{
    int t = blockIdx.x * 256 + threadIdx.x;   // (b,s,d): d fastest
    int d = t & (D_INNER - 1);
    int s = (t >> 11) & (D_STATE - 1);
    int b = t >> 15;
    float Aa = smallf[OFF_AA + d*D_STATE + s];
    float h = 0.f;
    #pragma unroll 4
    for (int c = 0; c < NC; c++) {
        float sd = sumdq[(long)(b*NC + c)*D_INNER + d];
        long idx = ((long)(b*NC + c)*D_STATE + s)*D_INNER + d;
        float q = Q_hst[idx];
        Q_hst[idx] = h;
        h = __expf(Aa*sd)*h + q;
    }
}

// ---------------------------------------------------------------------------
// Scan phase C (fallback): packed-f32; x AND z prefetched.
// ---------------------------------------------------------------------------
template<int CHUNK_T>
__global__ __launch_bounds__(256) void scan_partC(
    const float* __restrict__ ssm, bf16* __restrict__ xz,
    const float* __restrict__ smallf, const float* __restrict__ hst,
    const int* __restrict__ flag)
{
    __shared__ float sL[CHUNK_T*SSML];
    __shared__ bf16  sX[CHUNK_T*256];
    __shared__ bf16  sZ[CHUNK_T*256];
    const int fastA = flag[1];
    int d = blockIdx.x * 256 + threadIdx.x;
    int c = blockIdx.y, b = blockIdx.z;
    const int NC = gridDim.y;
    int l0 = c * CHUNK_T;
    {
        const float* src = ssm + (long)(b*LL + l0) * SSML;
        for (int idx = threadIdx.x; idx < CHUNK_T*SSML; idx += 256) sL[idx] = src[idx];
        const bf16* xsrc = xz + (long)(b*LL + l0)*4096 + blockIdx.x*256;
        for (int j = threadIdx.x; j < CHUNK_T*32; j += 256) {
            int li = j >> 5, ln = j & 31;
            *(short8*)&sX[li*256 + ln*8] = *(const short8*)&xsrc[(long)li*4096 + ln*8];
            *(short8*)&sZ[li*256 + ln*8] = *(const short8*)&xsrc[(long)li*4096 + D_INNER + ln*8];
        }
    }
    f32x4 h4[4];
    long o = ((long)(b*NC + c)*D_STATE)*D_INNER + d;
    #pragma unroll
    for (int s = 0; s < D_STATE; s++) h4[s >> 2][s & 3] = hst[o + (long)s*D_INNER];
    float Aa[D_STATE];
    if (!fastA) {
        #pragma unroll
        for (int s = 0; s < D_STATE; s++) Aa[s] = smallf[OFF_AA + d*D_STATE + s];
    }
    f32x4 cw4 = *(const f32x4*)&smallf[OFF_CW + d*4];
    float cbv  = smallf[OFF_CB + d];
    float wdt  = smallf[OFF_WDT + d];
    float bdtv = smallf[OFF_BDT + d];
    float Dv   = smallf[OFF_D + d];
    float win[3];
    #pragma unroll
    for (int k = 0; k < 3; k++) {
        int ls = l0 - 3 + k;
        win[k] = (ls >= 0) ? bf2f(xz[((long)(b*LL + ls))*4096 + d]) : 0.f;
    }
    __syncthreads();
    #pragma unroll 2
    for (int li = 0; li < CHUNK_T; li++) {
        long bl = (long)(b*LL + l0 + li);
        float xnew = bf2f(sX[li*256 + threadIdx.x]);
        float convv = cbv + win[0]*cw4[0] + win[1]*cw4[1] + win[2]*cw4[2] + xnew*cw4[3];
        win[0] = win[1]; win[1] = win[2]; win[2] = xnew;
        float xc = siluf(convv);
        const float* row = &sL[li*SSML];
        f32x4 Bv[4], Cv[4];
        #pragma unroll
        for (int g = 0; g < 4; g++) {
            Bv[g] = *(const f32x4*)(row + g*4);
            Cv[g] = *(const f32x4*)(row + 16 + g*4);
        }
        float delta, r;
        softplus_r(row[32]*wdt + bdtv, delta, r);
        float du = delta * xc;
        f32x4 yacc = f32x4{0.f, 0.f, 0.f, 0.f};
        if (fastA) {
            float r2 = r*r, r3 = r2*r, r4 = r2*r2;
            f32x4 p0; p0[0]=r; p0[1]=r2; p0[2]=r3; p0[3]=r4;
            float s8 = r4*r4, s12 = s8*r4;
            h4[0] = p0*h4[0]       + du*Bv[0];
            h4[1] = (p0*r4)*h4[1]  + du*Bv[1];
            h4[2] = (p0*s8)*h4[2]  + du*Bv[2];
            h4[3] = (p0*s12)*h4[3] + du*Bv[3];
            yacc = yacc + h4[0]*Cv[0];
            yacc = yacc + h4[1]*Cv[1];
            yacc = yacc + h4[2]*Cv[2];
            yacc = yacc + h4[3]*Cv[3];
        } else {
            #pragma unroll
            for (int g = 0; g < 4; g++)
                #pragma unroll
                for (int j = 0; j < 4; j++) {
                    int s = g*4 + j;
                    h4[g][j] = __expf(delta*Aa[s])*h4[g][j] + du*Bv[g][j];
                    yacc[j] += h4[g][j]*Cv[g][j];
                }
        }
        float yv = (yacc[0] + yacc[1]) + (yacc[2] + yacc[3]);
        yv += xc * Dv;
        float z = bf2f(sZ[li*256 + threadIdx.x]);
        yv *= siluf(z);
        xz[bl*4096 + D_INNER + d] = __float2bfloat16(yv);
    }
}

// ---------------------------------------------------------------------------
// Scan phase C, xc path (r10-verified): xc from xcb — no conv window.
// ---------------------------------------------------------------------------
template<int CHUNK_T>
__global__ __launch_bounds__(256) void scan_partC_xc(
    const float* __restrict__ ssm, bf16* __restrict__ xz,
    const bf16* __restrict__ xcb,
    const float* __restrict__ smallf, const float* __restrict__ hst,
    const int* __restrict__ flag)
{
    __shared__ float sL[CHUNK_T*SSML];
    __shared__ bf16  sX[CHUNK_T*256];
    __shared__ bf16  sZ[CHUNK_T*256];
    const int fastA = flag[1];
    int d = blockIdx.x * 256 + threadIdx.x;
    int c = blockIdx.y, b = blockIdx.z;
    const int NC = gridDim.y;
    int l0 = c * CHUNK_T;
    {
        const float* src = ssm + (long)(b*LL + l0) * SSML;
        for (int idx = threadIdx.x; idx < CHUNK_T*SSML; idx += 256) sL[idx] = src[idx];
        const bf16* xcs = xcb + (long)(b*LL + l0)*D_INNER + blockIdx.x*256;
        const bf16* zs  = xz  + (long)(b*LL + l0)*4096 + D_INNER + blockIdx.x*256;
        for (int j = threadIdx.x; j < CHUNK_T*32; j += 256) {
            int li = j >> 5, ln = j & 31;
            *(short8*)&sX[li*256 + ln*8] = *(const short8*)&xcs[(long)li*D_INNER + ln*8];
            *(short8*)&sZ[li*256 + ln*8] = *(const short8*)&zs[(long)li*4096 + ln*8];
        }
    }
    f32x4 h4[4];
    long o = ((long)(b*NC + c)*D_STATE)*D_INNER + d;
    #pragma unroll
    for (int s = 0; s < D_STATE; s++) h4[s >> 2][s & 3] = hst[o + (long)s*D_INNER];
    float Aa[D_STATE];
    if (!fastA) {
        #pragma unroll
        for (int s = 0; s < D_STATE; s++) Aa[s] = smallf[OFF_AA + d*D_STATE + s];
    }
    float wdt  = smallf[OFF_WDT + d];
    float bdtv = smallf[OFF_BDT + d];
    float Dv   = smallf[OFF_D + d];
    __syncthreads();
    #pragma unroll 2
    for (int li = 0; li < CHUNK_T; li++) {
        long bl = (long)(b*LL + l0 + li);
        float xc = bf2f(sX[li*256 + threadIdx.x]);
        const float* row = &sL[li*SSML];
        f32x4 Bv[4], Cv[4];
        #pragma unroll
        for (int g = 0; g < 4; g++) {
            Bv[g] = *(const f32x4*)(row + g*4);
            Cv[g] = *(const f32x4*)(row + 16 + g*4);
        }
        float delta, r;
        softplus_r(row[32]*wdt + bdtv, delta, r);
        float du = delta * xc;
        f32x4 yacc = f32x4{0.f, 0.f, 0.f, 0.f};
        if (fastA) {
            float r2 = r*r, r3 = r2*r, r4 = r2*r2;
            f32x4 p0; p0[0]=r; p0[1]=r2; p0[2]=r3; p0[3]=r4;
            float s8 = r4*r4, s12 = s8*r4;
            h4[0] = p0*h4[0]       + du*Bv[0];
            h4[1] = (p0*r4)*h4[1]  + du*Bv[1];
            h4[2] = (p0*s8)*h4[2]  + du*Bv[2];
            h4[3] = (p0*s12)*h4[3] + du*Bv[3];
            yacc = yacc + h4[0]*Cv[0];
            yacc = yacc + h4[1]*Cv[1];
            yacc = yacc + h4[2]*Cv[2];
            yacc = yacc + h4[3]*Cv[3];
        } else {
            #pragma unroll
            for (int g = 0; g < 4; g++)
                #pragma unroll
                for (int j = 0; j < 4; j++) {
                    int s = g*4 + j;
                    h4[g][j] = __expf(delta*Aa[s])*h4[g][j] + du*Bv[g][j];
                    yacc[j] += h4[g][j]*Cv[g][j];
                }
        }
        float yv = (yacc[0] + yacc[1]) + (yacc[2] + yacc[3]);
        yv += xc * Dv;
        float z = bf2f(sZ[li*256 + threadIdx.x]);
        yv *= siluf(z);
        xz[bl*4096 + D_INNER + d] = __float2bfloat16(yv);
    }
}

// ---------------------------------------------------------------------------
extern "C" void kernel_launch(void* const* d_in, const int* in_sizes, int n_in,
                              void* d_out, int out_size, void* d_ws, size_t ws_size,
                              hipStream_t stream)
{
    char* ws = (char*)d_ws;
    bf16*  xz     = (bf16*) (ws);               // 33,554,432
    bf16*  wxpb   = (bf16*) (ws + 33554432);    //    524,288
    float* ssm    = (float*)(ws + 34078720);    //    589,824
    float* sumdq  = (float*)(ws + 34668544);    //  1,048,576
    float* Q      = (float*)(ws + 35717120);    // 16,777,216
    float* smallf = (float*)(ws + 52494336);    //    196,608
    int*   flag   = (int*)  (ws + 52690944);    //         64
    bf16*  woutb  = (bf16*) (ws + 52691008);    //  4,194,304  end: 56,885,312
    bf16*  xcb    = (bf16*) (ws + 56885312);    // 16,777,216  end: 73,662,528
    // xb and winb ALIAS Q (dead before scan writes Q)
    bf16*  xb     = (bf16*) (ws + 35717120);
    bf16*  winb   = (bf16*) (ws + 35717120 + 8388608);
    const bool big  = ws_size >= 56885312;
    const bool big2 = ws_size >= 73662528;   // xc-fusion path (r10)

    // 0) dtype probe + flag init
    dtype_probe<<<1, 64, 0, stream>>>((const unsigned short*)d_in[7], flag);

    // 1) weight prep (+ zero ssm, + A-structure check -> flag[1])
    cvt_prep<<<(N_WXPB + N_SMALL + N_SSMZ)/256, 256, 0, stream>>>(
        d_in[4], d_in[2], d_in[3], d_in[5], d_in[6], d_in[7], d_in[8],
        wxpb, smallf, ssm, flag);

    // 2) xz = x @ W_in.T  (M=4096, N=4096, K=1024) — snake 8-phase (r12)
    if (big) {
        cvt_all<<<1310720/256, 256, 0, stream>>>(
            d_in[0], d_in[1], d_in[9], xb, winb, woutb, flag);
        gemm8s<<<dim3(16, 16), 512, 0, stream>>>(xb, winb, xz);
    } else {
        gemm_dual<<<dim3(32, 32), 256, 0, stream>>>(
            d_in[0], D_MODEL, d_in[1], D_MODEL, xz, 2*D_INNER, D_MODEL, flag, 1, 1, 0);
    }

    // 3) ssm += conv+silu(x_in) @ Wxp.T  (+ spill xc to xcb when big2)
    xproj_fused<<<dim3(XSPLIT, 32), 256, 0, stream>>>(
        xz, wxpb, smallf, ssm, big2 ? xcb : (bf16*)nullptr);

    // 4) chunked selective scan (xc path when big2)
    {
        dim3 g(D_INNER/256, NCHUNK, BB);
        if (big2) {
            scan_partA_xc<CHUNK><<<g, 256, 0, stream>>>(ssm, xcb, smallf, sumdq, Q, flag);
            scan_combine<<<(BB*D_STATE*D_INNER)/256, 256, 0, stream>>>(sumdq, Q, smallf, NCHUNK);
            scan_partC_xc<CHUNK><<<g, 256, 0, stream>>>(ssm, xz, xcb, smallf, Q, flag);
        } else {
            scan_partA<CHUNK><<<g, 256, 0, stream>>>(ssm, xz, smallf, sumdq, Q, flag);
            scan_combine<<<(BB*D_STATE*D_INNER)/256, 256, 0, stream>>>(sumdq, Q, smallf, NCHUNK);
            scan_partC<CHUNK><<<g, 256, 0, stream>>>(ssm, xz, smallf, Q, flag);
        }
    }

    // 5) out = y @ W_out.T  (M=4096, N=1024, K=2048) — r6-verified gemm_n64
    if (big) {
        gemm_n64<<<dim3(D_MODEL/64, 32), 256, 0, stream>>>(
            xz + D_INNER, 2*D_INNER, woutb, D_INNER, d_out, D_MODEL, D_INNER, flag, 0, 1);
    } else {
        gemm_n64<<<dim3(D_MODEL/64, 32), 256, 0, stream>>>(
            xz + D_INNER, 2*D_INNER, d_in[9], D_INNER, d_out, D_MODEL, D_INNER, flag, 1, 1);
    }
}

// Round 13
// 277.491 us; speedup vs baseline: 1.0496x; 1.0189x over previous
//
#include <hip/hip_runtime.h>
#include <hip/hip_bf16.h>
#include <math.h>

// SelectiveSSM: D_MODEL=1024, D_STATE=16, D_CONV=4, EXPAND=2, B=2, L=2048
#define D_MODEL 1024
#define D_STATE 16
#define D_CONV  4
#define D_INNER 2048
#define BB      2
#define LL      2048
#define BLROWS  (BB*LL)       // 4096
#define NCHUNK  64
#define CHUNK   (LL/NCHUNK)   // 32
#define SSML    36            // padded ssm row stride (floats)
#define XSPLIT  16            // split-K factor for xproj

typedef __hip_bfloat16 bf16;
typedef __attribute__((ext_vector_type(8))) short short8;
typedef __attribute__((ext_vector_type(4))) float f32x4;

__device__ __forceinline__ float ldf(const void* p, long i, int isbf) {
    return isbf ? __bfloat162float(((const bf16*)p)[i]) : ((const float*)p)[i];
}
__device__ __forceinline__ short bfbits(float f) {
    bf16 h = __float2bfloat16(f);
    return *(short*)&h;
}
__device__ __forceinline__ float bits2f(short s) {
    bf16 h; *(short*)&h = s; return __bfloat162float(h);
}
__device__ __forceinline__ float bf2f(bf16 h) { return __bfloat162float(h); }
__device__ __forceinline__ float siluf(float x) {
    return __fdividef(x, 1.f + __expf(-x));
}
// fused stable softplus + exp-negation: delta = log(1+exp(x)), r = exp(-delta)
__device__ __forceinline__ void softplus_r(float x, float& delta, float& r) {
    float e = __expf(-fabsf(x));
    float t = 1.f + e;
    delta = fmaxf(x, 0.f) + __logf(t);
    r = __fdividef((x >= 0.f) ? e : 1.f, t);
}

// smallf float offsets
#define OFF_CW   0
#define OFF_CB   8192
#define OFF_WDT  10240
#define OFF_BDT  12288
#define OFF_AA   14336
#define OFF_D    47104
#define N_SMALL  49152
#define N_WXPB   (128*2048)
#define N_SSMZ   (BLROWS*SSML)

#define G_LDS16(gptr, lptr) __builtin_amdgcn_global_load_lds( \
    (const __attribute__((address_space(1))) void*)(gptr),    \
    (__attribute__((address_space(3))) void*)(lptr), 16, 0, 0)

// ---------------------------------------------------------------------------
// dtype probe + flag init. flag[0]=isbf, flag[1]=fastA.
// ---------------------------------------------------------------------------
__global__ void dtype_probe(const unsigned short* __restrict__ alog, int* __restrict__ flag) {
    if (threadIdx.x == 0) { flag[0] = (alog[1] != 0) ? 1 : 0; flag[1] = 1; }
}

// ---------------------------------------------------------------------------
// prep: padded bf16 W_xproj + fp32 smalls + zero ssm + A-structure check
// ---------------------------------------------------------------------------
__global__ __launch_bounds__(256) void cvt_prep(
    const void* __restrict__ Wxp, const void* __restrict__ cw,
    const void* __restrict__ cb, const void* __restrict__ wdt,
    const void* __restrict__ bdt, const void* __restrict__ alog,
    const void* __restrict__ Dp,
    bf16* __restrict__ wxpb, float* __restrict__ smallf,
    float* __restrict__ ssm, int* __restrict__ flag)
{
    const int isbf = flag[0];
    int idx = blockIdx.x * 256 + threadIdx.x;
    if (idx < N_WXPB) {
        int row = idx >> 11, col = idx & 2047;
        float v = (row < 33) ? ldf(Wxp, (long)row*2048 + col, isbf) : 0.f;
        wxpb[idx] = __float2bfloat16(v);
        return;
    }
    int j = idx - N_WXPB;
    if      (j < 8192)  smallf[OFF_CW  + j]         = ldf(cw,  j, isbf);
    else if (j < 10240) smallf[OFF_CB  + j - 8192]  = ldf(cb,  j - 8192, isbf);
    else if (j < 12288) smallf[OFF_WDT + j - 10240] = ldf(wdt, j - 10240, isbf);
    else if (j < 14336) smallf[OFF_BDT + j - 12288] = ldf(bdt, j - 12288, isbf);
    else if (j < 47104) {
        int jj = j - 14336;                 // = d*16 + s
        float aa = -__expf(ldf(alog, jj, isbf));
        smallf[OFF_AA + jj] = aa;
        int s = jj & 15;
        if (fabsf(aa + (float)(s+1)) > 1e-3f) flag[1] = 0;
    }
    else if (j < 49152) smallf[OFF_D   + j - 47104] = ldf(Dp,  j - 47104, isbf);
    else {
        int z = j - N_SMALL;
        if (z < N_SSMZ) ssm[z] = 0.f;
    }
}

// ---------------------------------------------------------------------------
// merged x/W_in/W_out -> bf16 conversion (8 elems/thread, one launch)
// ---------------------------------------------------------------------------
__global__ __launch_bounds__(256) void cvt_all(
    const void* __restrict__ x, const void* __restrict__ win,
    const void* __restrict__ wout,
    bf16* __restrict__ xb, bf16* __restrict__ winb, bf16* __restrict__ woutb,
    const int* __restrict__ flagp)
{
    const int isbf = *flagp;
    int i = blockIdx.x * 256 + threadIdx.x;
    const void* src; bf16* dst; long o;
    if (i < 524288)       { src = x;    dst = xb;    o = (long)i * 8; }
    else if (i < 1048576) { src = win;  dst = winb;  o = (long)(i - 524288) * 8; }
    else if (i < 1310720) { src = wout; dst = woutb; o = (long)(i - 1048576) * 8; }
    else return;
    short8 v;
    if (isbf) {
        v = *(const short8*)((const bf16*)src + o);
    } else {
        const float* s = (const float*)src + o;
        f32x4 u = *(const f32x4*)s, w = *(const f32x4*)(s + 4);
        v[0]=bfbits(u[0]); v[1]=bfbits(u[1]); v[2]=bfbits(u[2]); v[3]=bfbits(u[3]);
        v[4]=bfbits(w[0]); v[5]=bfbits(w[1]); v[6]=bfbits(w[2]); v[7]=bfbits(w[3]);
    }
    *(short8*)(dst + o) = v;
}

// ---------------------------------------------------------------------------
// gemm8r (r13): snake 8-phase GEMM with RELAXED scheduling. r11/r12's
// explicit lgkmcnt(0)+sched_barrier pins before the MFMA cluster forced a
// full LDS drain per phase (m141 anti-pattern) — all three schedule
// variants landed at identical 674 TF. Here the compiler inserts
// fine-grained lgkmcnt per MFMA operand (m97 behavior); only raw closing
// barriers (1/phase, slot-reuse safety re-verified) + counted vmcnt remain.
// Phase: reads(cond) -> stage(cond) -> MFMA -> [p3: vmcnt(4)] -> barrier.
// Staging targets vs last-reader (closing-barrier-guarded):
//   p0: As[b^1][1] (last read kt-1 p2/p3) | p1: Bs[b^1][1] (kt-1 p0/p3)
//   p2: As[b][0] (this kt p0/p1)          | p3: Bs[b][0] (this kt p1/p2)
// vmcnt(4)@p3: 12 outstanding -> retires tile kt+1's 8 loads; kt+2's 4 fly.
// ---------------------------------------------------------------------------
__global__ __launch_bounds__(512) void gemm8r(
    const bf16* __restrict__ A,    // [4096][1024] row-major
    const bf16* __restrict__ Bm,   // [4096][1024] row-major
    bf16* __restrict__ Cp)         // [4096][4096]
{
    __shared__ bf16 As[2][2][128*64];
    __shared__ bf16 Bs[2][2][128*64];
    const int t    = threadIdx.x;          // 0..511
    const int lane = t & 63;
    const int w    = t >> 6;               // 0..7
    const int rm   = w >> 2;               // 0..1 row-sub within quadrant
    const int cn   = w & 3;                // 0..3 col-sub within quadrant
    const int bm   = blockIdx.y, bn = blockIdx.x;
    const int quad = lane >> 4, l16 = lane & 15;
    const int NT   = 16;                   // K=1024 / BK=64

    f32x4 acc[2][2][4][2];
    #pragma unroll
    for (int a = 0; a < 2; a++)
        #pragma unroll
        for (int b = 0; b < 2; b++)
            #pragma unroll
            for (int i = 0; i < 4; i++)
                #pragma unroll
                for (int j = 0; j < 2; j++)
                    acc[a][b][i][j] = f32x4{0.f, 0.f, 0.f, 0.f};

    auto stageA = [&](int bufi, int half, int kt) {
        #pragma unroll
        for (int seg = 0; seg < 2; seg++) {
            int s = seg*512 + t, row = s >> 3, sg = s & 7;
            int col = (sg ^ (row & 7)) * 8;
            G_LDS16(A + ((long)bm*256 + half*128 + row)*1024 + kt*64 + col,
                    &As[bufi][half][s*8]);
        }
    };
    auto stageB = [&](int bufi, int half, int kt) {
        #pragma unroll
        for (int seg = 0; seg < 2; seg++) {
            int s = seg*512 + t, row = s >> 3, sg = s & 7;
            int col = (sg ^ (row & 7)) * 8;
            G_LDS16(Bm + ((long)bn*256 + half*128 + row)*1024 + kt*64 + col,
                    &Bs[bufi][half][s*8]);
        }
    };

    // prologue: tile0 (4 half-tiles) + A0/B0 of tile1; wait tile0 landed.
    stageA(0, 0, 0); stageB(0, 0, 0); stageA(0, 1, 0); stageB(0, 1, 0);
    stageA(1, 0, 1); stageB(1, 0, 1);
    asm volatile("s_waitcnt vmcnt(4)" ::: "memory");
    __builtin_amdgcn_s_barrier();

    short8 af[4][2], bfv[2][2];
    for (int kt = 0; kt < NT; ++kt) {
        const int buf = kt & 1;
        #pragma unroll
        for (int p = 0; p < 4; ++p) {
            // snake: (qm,qn) = (0,1),(0,0),(1,0),(1,1)
            const int qm = p >> 1;
            const int qn = (p == 0 || p == 3) ? 1 : 0;
            if (p == 0 || p == 2) {
                #pragma unroll
                for (int fi = 0; fi < 4; fi++)
                    #pragma unroll
                    for (int kk = 0; kk < 2; kk++) {
                        int ar = rm*64 + fi*16 + l16;
                        int c = kk*4 + quad;
                        af[fi][kk] = *(const short8*)&As[buf][qm][ar*64 + ((c ^ (ar & 7))*8)];
                    }
            }
            if (p != 2) {
                #pragma unroll
                for (int fj = 0; fj < 2; fj++)
                    #pragma unroll
                    for (int kk = 0; kk < 2; kk++) {
                        int br = cn*32 + fj*16 + l16;
                        int c = kk*4 + quad;
                        bfv[fj][kk] = *(const short8*)&Bs[buf][qn][br*64 + ((c ^ (br & 7))*8)];
                    }
            }
            if      (p == 0) { if (kt + 1 < NT) stageA(buf ^ 1, 1, kt + 1); }
            else if (p == 1) { if (kt + 1 < NT) stageB(buf ^ 1, 1, kt + 1); }
            else if (p == 2) { if (kt + 2 < NT) stageA(buf, 0, kt + 2); }
            else             { if (kt + 2 < NT) stageB(buf, 0, kt + 2); }
            __builtin_amdgcn_s_setprio(1);
            #pragma unroll
            for (int kk = 0; kk < 2; kk++)
                #pragma unroll
                for (int fi = 0; fi < 4; fi++)
                    #pragma unroll
                    for (int fj = 0; fj < 2; fj++)
                        acc[qm][qn][fi][fj] = __builtin_amdgcn_mfma_f32_16x16x32_bf16(
                            af[fi][kk], bfv[fj][kk], acc[qm][qn][fi][fj], 0, 0, 0);
            __builtin_amdgcn_s_setprio(0);
            if (p == 3) {
                if (kt == NT - 2)     { asm volatile("s_waitcnt vmcnt(0)" ::: "memory"); }
                else if (kt < NT - 2) { asm volatile("s_waitcnt vmcnt(4)" ::: "memory"); }
            }
            __builtin_amdgcn_s_barrier();
        }
    }

    #pragma unroll
    for (int qm = 0; qm < 2; qm++)
        #pragma unroll
        for (int qn = 0; qn < 2; qn++)
            #pragma unroll
            for (int fi = 0; fi < 4; fi++)
                #pragma unroll
                for (int fj = 0; fj < 2; fj++)
                    #pragma unroll
                    for (int r = 0; r < 4; r++) {
                        int row = bm*256 + qm*128 + rm*64 + fi*16 + quad*4 + r;
                        int col = bn*256 + qn*128 + cn*32 + fj*16 + l16;
                        Cp[(long)row * 4096 + col] = __float2bfloat16(acc[qm][qn][fi][fj][r]);
                    }
}

// ---------------------------------------------------------------------------
// GEMM fallback (small-ws path): 128x128 tile, BK=64, XOR-swizzled LDS
// ---------------------------------------------------------------------------
__global__ __launch_bounds__(256) void gemm_dual(
    const void* __restrict__ A, int lda,
    const void* __restrict__ Bm, int ldb,
    void* __restrict__ Cp, int ldc, int K,
    const int* __restrict__ flagp, int amode, int bmode, int cmode)
{
    const int isbf = *flagp;
    const int a_bf = amode ? isbf : 1;
    const int b_bf = bmode ? isbf : 1;
    const int c_bf = cmode ? isbf : 1;

    __shared__ bf16 As[128*64];
    __shared__ bf16 Bs[128*64];
    const int t    = threadIdx.x;
    const int lane = t & 63;
    const int w    = t >> 6;
    const int wm   = w >> 1, wn = w & 1;
    const int bm   = blockIdx.y, bn = blockIdx.x;
    const int quad = lane >> 4, l16 = lane & 15;

    f32x4 acc[4][4];
    #pragma unroll
    for (int i = 0; i < 4; i++)
        #pragma unroll
        for (int j = 0; j < 4; j++)
            acc[i][j] = f32x4{0.f, 0.f, 0.f, 0.f};

    for (int k0 = 0; k0 < K; k0 += 64) {
        __syncthreads();
        if (a_bf) {
            #pragma unroll
            for (int seg = 0; seg < 4; seg++) {
                int s = seg*256 + t, row = s >> 3, sg = s & 7;
                int col = (sg ^ (row & 7)) * 8;
                const bf16* ga = (const bf16*)A + ((long)bm*128 + row)*(long)lda + k0 + col;
                G_LDS16(ga, &As[row*64 + sg*8]);
            }
        } else {
            #pragma unroll
            for (int seg = 0; seg < 4; seg++) {
                int s = seg*256 + t, row = s >> 3, sg = s & 7;
                int col = (sg ^ (row & 7)) * 8;
                const float* ap = (const float*)A + ((long)bm*128 + row)*(long)lda + k0 + col;
                f32x4 u = *(const f32x4*)ap, v = *(const f32x4*)(ap + 4);
                short8 va;
                va[0]=bfbits(u[0]); va[1]=bfbits(u[1]); va[2]=bfbits(u[2]); va[3]=bfbits(u[3]);
                va[4]=bfbits(v[0]); va[5]=bfbits(v[1]); va[6]=bfbits(v[2]); va[7]=bfbits(v[3]);
                *(short8*)&As[row*64 + sg*8] = va;
            }
        }
        if (b_bf) {
            #pragma unroll
            for (int seg = 0; seg < 4; seg++) {
                int s = seg*256 + t, row = s >> 3, sg = s & 7;
                int col = (sg ^ (row & 7)) * 8;
                const bf16* gb = (const bf16*)Bm + ((long)bn*128 + row)*(long)ldb + k0 + col;
                G_LDS16(gb, &Bs[row*64 + sg*8]);
            }
        } else {
            #pragma unroll
            for (int seg = 0; seg < 4; seg++) {
                int s = seg*256 + t, row = s >> 3, sg = s & 7;
                int col = (sg ^ (row & 7)) * 8;
                const float* bp = (const float*)Bm + ((long)bn*128 + row)*(long)ldb + k0 + col;
                f32x4 u = *(const f32x4*)bp, v = *(const f32x4*)(bp + 4);
                short8 vb;
                vb[0]=bfbits(u[0]); vb[1]=bfbits(u[1]); vb[2]=bfbits(u[2]); vb[3]=bfbits(u[3]);
                vb[4]=bfbits(v[0]); vb[5]=bfbits(v[1]); vb[6]=bfbits(v[2]); vb[7]=bfbits(v[3]);
                *(short8*)&Bs[row*64 + sg*8] = vb;
            }
        }
        __syncthreads();

        #pragma unroll
        for (int kk = 0; kk < 64; kk += 32) {
            const int cbase = kk >> 3;
            short8 af[4], bfr[4];
            #pragma unroll
            for (int mi = 0; mi < 4; mi++) {
                int row = wm*64 + mi*16 + l16;
                int c = cbase + quad;
                af[mi] = *(const short8*)&As[row*64 + ((c ^ (row & 7))*8)];
            }
            #pragma unroll
            for (int ni = 0; ni < 4; ni++) {
                int row = wn*64 + ni*16 + l16;
                int c = cbase + quad;
                bfr[ni] = *(const short8*)&Bs[row*64 + ((c ^ (row & 7))*8)];
            }
            #pragma unroll
            for (int mi = 0; mi < 4; mi++)
                #pragma unroll
                for (int ni = 0; ni < 4; ni++)
                    acc[mi][ni] = __builtin_amdgcn_mfma_f32_16x16x32_bf16(
                        af[mi], bfr[ni], acc[mi][ni], 0, 0, 0);
        }
    }

    #pragma unroll
    for (int mi = 0; mi < 4; mi++)
        #pragma unroll
        for (int ni = 0; ni < 4; ni++)
            #pragma unroll
            for (int r = 0; r < 4; r++) {
                int row = bm*128 + wm*64 + mi*16 + quad*4 + r;
                int col = bn*128 + wn*64 + ni*16 + l16;
                float val = acc[mi][ni][r];
                if (c_bf) ((bf16*)Cp)[(long)row * ldc + col] = __float2bfloat16(val);
                else      ((float*)Cp)[(long)row * ldc + col] = val;
            }
}

// ---------------------------------------------------------------------------
// GEMM2 (r6-verified): 128x64 tile, BK=64, XOR swizzle. Grid (16,32).
// ---------------------------------------------------------------------------
__global__ __launch_bounds__(256) void gemm_n64(
    const bf16* __restrict__ A, int lda,
    const void* __restrict__ Bm, int ldb,
    void* __restrict__ Cp, int ldc, int K,
    const int* __restrict__ flagp, int bmode, int cmode)
{
    const int isbf = *flagp;
    const int b_bf = bmode ? isbf : 1;
    const int c_bf = cmode ? isbf : 1;

    __shared__ bf16 As[128*64];
    __shared__ bf16 Bs[64*64];
    const int t    = threadIdx.x;
    const int lane = t & 63;
    const int w    = t >> 6;
    const int wm   = w >> 1, wn = w & 1;
    const int bm   = blockIdx.y, bn = blockIdx.x;
    const int quad = lane >> 4, l16 = lane & 15;

    f32x4 acc[4][2];
    #pragma unroll
    for (int i = 0; i < 4; i++)
        #pragma unroll
        for (int j = 0; j < 2; j++)
            acc[i][j] = f32x4{0.f, 0.f, 0.f, 0.f};

    for (int k0 = 0; k0 < K; k0 += 64) {
        __syncthreads();
        #pragma unroll
        for (int seg = 0; seg < 4; seg++) {
            int s = seg*256 + t, row = s >> 3, sg = s & 7;
            int col = (sg ^ (row & 7)) * 8;
            const bf16* ga = A + ((long)bm*128 + row)*(long)lda + k0 + col;
            G_LDS16(ga, &As[row*64 + sg*8]);
        }
        if (b_bf) {
            #pragma unroll
            for (int seg = 0; seg < 2; seg++) {
                int s = seg*256 + t, row = s >> 3, sg = s & 7;
                int col = (sg ^ (row & 7)) * 8;
                const bf16* gb = (const bf16*)Bm + ((long)bn*64 + row)*(long)ldb + k0 + col;
                G_LDS16(gb, &Bs[row*64 + sg*8]);
            }
        } else {
            #pragma unroll
            for (int seg = 0; seg < 2; seg++) {
                int s = seg*256 + t, row = s >> 3, sg = s & 7;
                int col = (sg ^ (row & 7)) * 8;
                const float* bp = (const float*)Bm + ((long)bn*64 + row)*(long)ldb + k0 + col;
                f32x4 u = *(const f32x4*)bp, v = *(const f32x4*)(bp + 4);
                short8 vb;
                vb[0]=bfbits(u[0]); vb[1]=bfbits(u[1]); vb[2]=bfbits(u[2]); vb[3]=bfbits(u[3]);
                vb[4]=bfbits(v[0]); vb[5]=bfbits(v[1]); vb[6]=bfbits(v[2]); vb[7]=bfbits(v[3]);
                *(short8*)&Bs[row*64 + sg*8] = vb;
            }
        }
        __syncthreads();

        #pragma unroll
        for (int kk = 0; kk < 64; kk += 32) {
            const int cbase = kk >> 3;
            short8 af[4], bfr[2];
            #pragma unroll
            for (int mi = 0; mi < 4; mi++) {
                int row = wm*64 + mi*16 + l16;
                int c = cbase + quad;
                af[mi] = *(const short8*)&As[row*64 + ((c ^ (row & 7))*8)];
            }
            #pragma unroll
            for (int ni = 0; ni < 2; ni++) {
                int row = wn*32 + ni*16 + l16;
                int c = cbase + quad;
                bfr[ni] = *(const short8*)&Bs[row*64 + ((c ^ (row & 7))*8)];
            }
            #pragma unroll
            for (int mi = 0; mi < 4; mi++)
                #pragma unroll
                for (int ni = 0; ni < 2; ni++)
                    acc[mi][ni] = __builtin_amdgcn_mfma_f32_16x16x32_bf16(
                        af[mi], bfr[ni], acc[mi][ni], 0, 0, 0);
        }
    }

    #pragma unroll
    for (int mi = 0; mi < 4; mi++)
        #pragma unroll
        for (int ni = 0; ni < 2; ni++)
            #pragma unroll
            for (int r = 0; r < 4; r++) {
                int row = bm*128 + wm*64 + mi*16 + quad*4 + r;
                int col = bn*64 + wn*32 + ni*16 + l16;
                float val = acc[mi][ni][r];
                if (c_bf) ((bf16*)Cp)[(long)row * ldc + col] = __float2bfloat16(val);
                else      ((float*)Cp)[(long)row * ldc + col] = val;
            }
}

// ---------------------------------------------------------------------------
// xproj fused, split-K: ssm[bl, :] += partial(conv+silu(x_in) @ Wxp.T).
// r10: optionally spill the staged xc tile (silu(conv)) to global xcb.
// ---------------------------------------------------------------------------
__global__ __launch_bounds__(256) void xproj_fused(
    const bf16* __restrict__ xz, const bf16* __restrict__ wxpb,
    const float* __restrict__ smallf, float* __restrict__ ssm,
    bf16* __restrict__ xcb)
{
    const float* cwf = smallf + OFF_CW;
    const float* cbf = smallf + OFF_CB;
    __shared__ bf16 As[128*32];
    __shared__ bf16 Bs[128*32];
    const int t    = threadIdx.x;
    const int lane = t & 63;
    const int w    = t >> 6;
    const int wm   = w >> 1, wn = w & 1;
    const int bm   = blockIdx.y;
    const int ks   = blockIdx.x * (D_INNER / XSPLIT);
    const int quad = lane >> 4, l16 = lane & 15;

    f32x4 acc[4][4];
    #pragma unroll
    for (int i = 0; i < 4; i++)
        #pragma unroll
        for (int j = 0; j < 4; j++)
            acc[i][j] = f32x4{0.f, 0.f, 0.f, 0.f};

    for (int k0 = ks; k0 < ks + D_INNER/XSPLIT; k0 += 32) {
        __syncthreads();
        #pragma unroll
        for (int seg = 0; seg < 2; seg++) {
            int s = seg*256 + t, row = s >> 2, dcol = (s & 3) * 8;
            int blg = bm*128 + row;
            int b = blg >> 11, l = blg & (LL - 1);
            int d0 = k0 + dcol;
            float a[8];
            {
                f32x4 c0 = *(const f32x4*)&cbf[d0], c1 = *(const f32x4*)&cbf[d0+4];
                a[0]=c0[0]; a[1]=c0[1]; a[2]=c0[2]; a[3]=c0[3];
                a[4]=c1[0]; a[5]=c1[1]; a[6]=c1[2]; a[7]=c1[3];
            }
            f32x4 cw4[8];
            #pragma unroll
            for (int j = 0; j < 8; j++) cw4[j] = *(const f32x4*)&cwf[(d0+j)*4];
            #pragma unroll
            for (int kk = 0; kk < D_CONV; kk++) {
                int ls = l - 3 + kk;
                if (ls >= 0) {
                    short8 xv = *(const short8*)&xz[((long)(b*LL + ls))*4096 + d0];
                    #pragma unroll
                    for (int j = 0; j < 8; j++) a[j] += bits2f(xv[j]) * cw4[j][kk];
                }
            }
            short8 va;
            #pragma unroll
            for (int j = 0; j < 8; j++) va[j] = bfbits(siluf(a[j]));
            *(short8*)&As[row*32 + dcol] = va;
            if (xcb) *(short8*)&xcb[(long)blg*D_INNER + d0] = va;
        }
        #pragma unroll
        for (int seg = 0; seg < 2; seg++) {
            int s = seg*256 + t, row = s >> 2, col = (s & 3) * 8;
            const bf16* gb = wxpb + (long)row*D_INNER + k0 + col;
            G_LDS16(gb, &Bs[row*32 + col]);
        }
        __syncthreads();

        short8 af[4], bfr[4];
        #pragma unroll
        for (int mi = 0; mi < 4; mi++)
            af[mi] = *(const short8*)&As[(wm*64 + mi*16 + l16)*32 + quad*8];
        #pragma unroll
        for (int ni = 0; ni < 4; ni++)
            bfr[ni] = *(const short8*)&Bs[(wn*64 + ni*16 + l16)*32 + quad*8];
        #pragma unroll
        for (int mi = 0; mi < 4; mi++)
            #pragma unroll
            for (int ni = 0; ni < 4; ni++)
                acc[mi][ni] = __builtin_amdgcn_mfma_f32_16x16x32_bf16(
                    af[mi], bfr[ni], acc[mi][ni], 0, 0, 0);
    }

    #pragma unroll
    for (int mi = 0; mi < 4; mi++)
        #pragma unroll
        for (int ni = 0; ni < 4; ni++) {
            int col = wn*64 + ni*16 + l16;
            if (col < 33) {
                int newcol = (col == 0) ? 32 : (col - 1);
                #pragma unroll
                for (int r = 0; r < 4; r++) {
                    int row = bm*128 + wm*64 + mi*16 + quad*4 + r;
                    atomicAdd(&ssm[(long)row * SSML + newcol], acc[mi][ni][r]);
                }
            }
        }
}

// ---------------------------------------------------------------------------
// Scan phase A (fallback): packed-f32 h, LDS x-prefetch + conv.
// ---------------------------------------------------------------------------
template<int CHUNK_T>
__global__ __launch_bounds__(256) void scan_partA(
    const float* __restrict__ ssm, const bf16* __restrict__ xz,
    const float* __restrict__ smallf,
    float* __restrict__ sumdq, float* __restrict__ Q,
    const int* __restrict__ flag)
{
    __shared__ float sL[CHUNK_T*SSML];
    __shared__ bf16  sX[CHUNK_T*256];
    const int fastA = flag[1];
    int d = blockIdx.x * 256 + threadIdx.x;
    int c = blockIdx.y, b = blockIdx.z;
    const int NC = gridDim.y;
    int l0 = c * CHUNK_T;
    {
        const float* src = ssm + (long)(b*LL + l0) * SSML;
        for (int idx = threadIdx.x; idx < CHUNK_T*SSML; idx += 256) sL[idx] = src[idx];
        const bf16* xsrc = xz + (long)(b*LL + l0)*4096 + blockIdx.x*256;
        for (int j = threadIdx.x; j < CHUNK_T*32; j += 256) {
            int li = j >> 5, ln = j & 31;
            *(short8*)&sX[li*256 + ln*8] = *(const short8*)&xsrc[(long)li*4096 + ln*8];
        }
    }
    f32x4 h4[4];
    #pragma unroll
    for (int g = 0; g < 4; g++) h4[g] = f32x4{0.f, 0.f, 0.f, 0.f};
    float Aa[D_STATE];
    if (!fastA) {
        #pragma unroll
        for (int s = 0; s < D_STATE; s++) Aa[s] = smallf[OFF_AA + d*D_STATE + s];
    }
    f32x4 cw4 = *(const f32x4*)&smallf[OFF_CW + d*4];
    float cbv  = smallf[OFF_CB + d];
    float wdt  = smallf[OFF_WDT + d];
    float bdtv = smallf[OFF_BDT + d];
    float win[3];
    #pragma unroll
    for (int k = 0; k < 3; k++) {
        int ls = l0 - 3 + k;
        win[k] = (ls >= 0) ? bf2f(xz[((long)(b*LL + ls))*4096 + d]) : 0.f;
    }
    __syncthreads();
    float sumd = 0.f;
    #pragma unroll 4
    for (int li = 0; li < CHUNK_T; li++) {
        float xnew = bf2f(sX[li*256 + threadIdx.x]);
        float convv = cbv + win[0]*cw4[0] + win[1]*cw4[1] + win[2]*cw4[2] + xnew*cw4[3];
        win[0] = win[1]; win[1] = win[2]; win[2] = xnew;
        float xc = siluf(convv);
        const float* row = &sL[li*SSML];
        f32x4 Bv[4];
        #pragma unroll
        for (int g = 0; g < 4; g++) Bv[g] = *(const f32x4*)(row + g*4);
        float delta, r;
        softplus_r(row[32]*wdt + bdtv, delta, r);
        sumd += delta;
        float du = delta * xc;
        if (fastA) {
            float r2 = r*r, r3 = r2*r, r4 = r2*r2;
            f32x4 p0; p0[0]=r; p0[1]=r2; p0[2]=r3; p0[3]=r4;
            float s8 = r4*r4, s12 = s8*r4;
            h4[0] = p0*h4[0]       + du*Bv[0];
            h4[1] = (p0*r4)*h4[1]  + du*Bv[1];
            h4[2] = (p0*s8)*h4[2]  + du*Bv[2];
            h4[3] = (p0*s12)*h4[3] + du*Bv[3];
        } else {
            #pragma unroll
            for (int g = 0; g < 4; g++)
                #pragma unroll
                for (int j = 0; j < 4; j++) {
                    int s = g*4 + j;
                    h4[g][j] = __expf(delta*Aa[s])*h4[g][j] + du*Bv[g][j];
                }
        }
    }
    sumdq[(long)(b*NC + c)*D_INNER + d] = sumd;
    long o = ((long)(b*NC + c)*D_STATE)*D_INNER + d;
    #pragma unroll
    for (int s = 0; s < D_STATE; s++)
        Q[o + (long)s*D_INNER] = h4[s >> 2][s & 3];
}

// ---------------------------------------------------------------------------
// Scan phase A, xc path (r10-verified): xc pre-computed by xproj (xcb).
// ---------------------------------------------------------------------------
template<int CHUNK_T>
__global__ __launch_bounds__(256) void scan_partA_xc(
    const float* __restrict__ ssm, const bf16* __restrict__ xcb,
    const float* __restrict__ smallf,
    float* __restrict__ sumdq, float* __restrict__ Q,
    const int* __restrict__ flag)
{
    __shared__ float sL[CHUNK_T*SSML];
    __shared__ bf16  sX[CHUNK_T*256];
    const int fastA = flag[1];
    int d = blockIdx.x * 256 + threadIdx.x;
    int c = blockIdx.y, b = blockIdx.z;
    const int NC = gridDim.y;
    int l0 = c * CHUNK_T;
    {
        const float* src = ssm + (long)(b*LL + l0) * SSML;
        for (int idx = threadIdx.x; idx < CHUNK_T*SSML; idx += 256) sL[idx] = src[idx];
        const bf16* xsrc = xcb + (long)(b*LL + l0)*D_INNER + blockIdx.x*256;
        for (int j = threadIdx.x; j < CHUNK_T*32; j += 256) {
            int li = j >> 5, ln = j & 31;
            *(short8*)&sX[li*256 + ln*8] = *(const short8*)&xsrc[(long)li*D_INNER + ln*8];
        }
    }
    f32x4 h4[4];
    #pragma unroll
    for (int g = 0; g < 4; g++) h4[g] = f32x4{0.f, 0.f, 0.f, 0.f};
    float Aa[D_STATE];
    if (!fastA) {
        #pragma unroll
        for (int s = 0; s < D_STATE; s++) Aa[s] = smallf[OFF_AA + d*D_STATE + s];
    }
    float wdt  = smallf[OFF_WDT + d];
    float bdtv = smallf[OFF_BDT + d];
    __syncthreads();
    float sumd = 0.f;
    #pragma unroll 4
    for (int li = 0; li < CHUNK_T; li++) {
        float xc = bf2f(sX[li*256 + threadIdx.x]);
        const float* row = &sL[li*SSML];
        f32x4 Bv[4];
        #pragma unroll
        for (int g = 0; g < 4; g++) Bv[g] = *(const f32x4*)(row + g*4);
        float delta, r;
        softplus_r(row[32]*wdt + bdtv, delta, r);
        sumd += delta;
        float du = delta * xc;
        if (fastA) {
            float r2 = r*r, r3 = r2*r, r4 = r2*r2;
            f32x4 p0; p0[0]=r; p0[1]=r2; p0[2]=r3; p0[3]=r4;
            float s8 = r4*r4, s12 = s8*r4;
            h4[0] = p0*h4[0]       + du*Bv[0];
            h4[1] = (p0*r4)*h4[1]  + du*Bv[1];
            h4[2] = (p0*s8)*h4[2]  + du*Bv[2];
            h4[3] = (p0*s12)*h4[3] + du*Bv[3];
        } else {
            #pragma unroll
            for (int g = 0; g < 4; g++)
                #pragma unroll
                for (int j = 0; j < 4; j++) {
                    int s = g*4 + j;
                    h4[g][j] = __expf(delta*Aa[s])*h4[g][j] + du*Bv[g][j];
                }
        }
    }
    sumdq[(long)(b*NC + c)*D_INNER + d] = sumd;
    long o = ((long)(b*NC + c)*D_STATE)*D_INNER + d;
    #pragma unroll
    for (int s = 0; s < D_STATE; s++)
        Q[o + (long)s*D_INNER] = h4[s >> 2][s & 3];
}

// ---------------------------------------------------------------------------
// Scan phase B: combine chunks per (b,d,s); P recomputed from sumd.
// ---------------------------------------------------------------------------
__global__ __launch_bounds__(256) void scan_combine(
    const float* __restrict__ sumdq, float* __restrict__ Q_hst,
    const float* __restrict__ smallf, int NC)
{
    int t = blockIdx.x * 256 + threadIdx.x;   // (b,s,d): d fastest
    int d = t & (D_INNER - 1);
    int s = (t >> 11) & (D_STATE - 1);
    int b = t >> 15;
    float Aa = smallf[OFF_AA + d*D_STATE + s];
    float h = 0.f;
    #pragma unroll 4
    for (int c = 0; c < NC; c++) {
        float sd = sumdq[(long)(b*NC + c)*D_INNER + d];
        long idx = ((long)(b*NC + c)*D_STATE + s)*D_INNER + d;
        float q = Q_hst[idx];
        Q_hst[idx] = h;
        h = __expf(Aa*sd)*h + q;
    }
}

// ---------------------------------------------------------------------------
// Scan phase C (fallback): packed-f32; x AND z prefetched.
// ---------------------------------------------------------------------------
template<int CHUNK_T>
__global__ __launch_bounds__(256) void scan_partC(
    const float* __restrict__ ssm, bf16* __restrict__ xz,
    const float* __restrict__ smallf, const float* __restrict__ hst,
    const int* __restrict__ flag)
{
    __shared__ float sL[CHUNK_T*SSML];
    __shared__ bf16  sX[CHUNK_T*256];
    __shared__ bf16  sZ[CHUNK_T*256];
    const int fastA = flag[1];
    int d = blockIdx.x * 256 + threadIdx.x;
    int c = blockIdx.y, b = blockIdx.z;
    const int NC = gridDim.y;
    int l0 = c * CHUNK_T;
    {
        const float* src = ssm + (long)(b*LL + l0) * SSML;
        for (int idx = threadIdx.x; idx < CHUNK_T*SSML; idx += 256) sL[idx] = src[idx];
        const bf16* xsrc = xz + (long)(b*LL + l0)*4096 + blockIdx.x*256;
        for (int j = threadIdx.x; j < CHUNK_T*32; j += 256) {
            int li = j >> 5, ln = j & 31;
            *(short8*)&sX[li*256 + ln*8] = *(const short8*)&xsrc[(long)li*4096 + ln*8];
            *(short8*)&sZ[li*256 + ln*8] = *(const short8*)&xsrc[(long)li*4096 + D_INNER + ln*8];
        }
    }
    f32x4 h4[4];
    long o = ((long)(b*NC + c)*D_STATE)*D_INNER + d;
    #pragma unroll
    for (int s = 0; s < D_STATE; s++) h4[s >> 2][s & 3] = hst[o + (long)s*D_INNER];
    float Aa[D_STATE];
    if (!fastA) {
        #pragma unroll
        for (int s = 0; s < D_STATE; s++) Aa[s] = smallf[OFF_AA + d*D_STATE + s];
    }
    f32x4 cw4 = *(const f32x4*)&smallf[OFF_CW + d*4];
    float cbv  = smallf[OFF_CB + d];
    float wdt  = smallf[OFF_WDT + d];
    float bdtv = smallf[OFF_BDT + d];
    float Dv   = smallf[OFF_D + d];
    float win[3];
    #pragma unroll
    for (int k = 0; k < 3; k++) {
        int ls = l0 - 3 + k;
        win[k] = (ls >= 0) ? bf2f(xz[((long)(b*LL + ls))*4096 + d]) : 0.f;
    }
    __syncthreads();
    #pragma unroll 2
    for (int li = 0; li < CHUNK_T; li++) {
        long bl = (long)(b*LL + l0 + li);
        float xnew = bf2f(sX[li*256 + threadIdx.x]);
        float convv = cbv + win[0]*cw4[0] + win[1]*cw4[1] + win[2]*cw4[2] + xnew*cw4[3];
        win[0] = win[1]; win[1] = win[2]; win[2] = xnew;
        float xc = siluf(convv);
        const float* row = &sL[li*SSML];
        f32x4 Bv[4], Cv[4];
        #pragma unroll
        for (int g = 0; g < 4; g++) {
            Bv[g] = *(const f32x4*)(row + g*4);
            Cv[g] = *(const f32x4*)(row + 16 + g*4);
        }
        float delta, r;
        softplus_r(row[32]*wdt + bdtv, delta, r);
        float du = delta * xc;
        f32x4 yacc = f32x4{0.f, 0.f, 0.f, 0.f};
        if (fastA) {
            float r2 = r*r, r3 = r2*r, r4 = r2*r2;
            f32x4 p0; p0[0]=r; p0[1]=r2; p0[2]=r3; p0[3]=r4;
            float s8 = r4*r4, s12 = s8*r4;
            h4[0] = p0*h4[0]       + du*Bv[0];
            h4[1] = (p0*r4)*h4[1]  + du*Bv[1];
            h4[2] = (p0*s8)*h4[2]  + du*Bv[2];
            h4[3] = (p0*s12)*h4[3] + du*Bv[3];
            yacc = yacc + h4[0]*Cv[0];
            yacc = yacc + h4[1]*Cv[1];
            yacc = yacc + h4[2]*Cv[2];
            yacc = yacc + h4[3]*Cv[3];
        } else {
            #pragma unroll
            for (int g = 0; g < 4; g++)
                #pragma unroll
                for (int j = 0; j < 4; j++) {
                    int s = g*4 + j;
                    h4[g][j] = __expf(delta*Aa[s])*h4[g][j] + du*Bv[g][j];
                    yacc[j] += h4[g][j]*Cv[g][j];
                }
        }
        float yv = (yacc[0] + yacc[1]) + (yacc[2] + yacc[3]);
        yv += xc * Dv;
        float z = bf2f(sZ[li*256 + threadIdx.x]);
        yv *= siluf(z);
        xz[bl*4096 + D_INNER + d] = __float2bfloat16(yv);
    }
}

// ---------------------------------------------------------------------------
// Scan phase C, xc path (r10-verified): xc from xcb — no conv window.
// ---------------------------------------------------------------------------
template<int CHUNK_T>
__global__ __launch_bounds__(256) void scan_partC_xc(
    const float* __restrict__ ssm, bf16* __restrict__ xz,
    const bf16* __restrict__ xcb,
    const float* __restrict__ smallf, const float* __restrict__ hst,
    const int* __restrict__ flag)
{
    __shared__ float sL[CHUNK_T*SSML];
    __shared__ bf16  sX[CHUNK_T*256];
    __shared__ bf16  sZ[CHUNK_T*256];
    const int fastA = flag[1];
    int d = blockIdx.x * 256 + threadIdx.x;
    int c = blockIdx.y, b = blockIdx.z;
    const int NC = gridDim.y;
    int l0 = c * CHUNK_T;
    {
        const float* src = ssm + (long)(b*LL + l0) * SSML;
        for (int idx = threadIdx.x; idx < CHUNK_T*SSML; idx += 256) sL[idx] = src[idx];
        const bf16* xcs = xcb + (long)(b*LL + l0)*D_INNER + blockIdx.x*256;
        const bf16* zs  = xz  + (long)(b*LL + l0)*4096 + D_INNER + blockIdx.x*256;
        for (int j = threadIdx.x; j < CHUNK_T*32; j += 256) {
            int li = j >> 5, ln = j & 31;
            *(short8*)&sX[li*256 + ln*8] = *(const short8*)&xcs[(long)li*D_INNER + ln*8];
            *(short8*)&sZ[li*256 + ln*8] = *(const short8*)&zs[(long)li*4096 + ln*8];
        }
    }
    f32x4 h4[4];
    long o = ((long)(b*NC + c)*D_STATE)*D_INNER + d;
    #pragma unroll
    for (int s = 0; s < D_STATE; s++) h4[s >> 2][s & 3] = hst[o + (long)s*D_INNER];
    float Aa[D_STATE];
    if (!fastA) {
        #pragma unroll
        for (int s = 0; s < D_STATE; s++) Aa[s] = smallf[OFF_AA + d*D_STATE + s];
    }
    float wdt  = smallf[OFF_WDT + d];
    float bdtv = smallf[OFF_BDT + d];
    float Dv   = smallf[OFF_D + d];
    __syncthreads();
    #pragma unroll 2
    for (int li = 0; li < CHUNK_T; li++) {
        long bl = (long)(b*LL + l0 + li);
        float xc = bf2f(sX[li*256 + threadIdx.x]);
        const float* row = &sL[li*SSML];
        f32x4 Bv[4], Cv[4];
        #pragma unroll
        for (int g = 0; g < 4; g++) {
            Bv[g] = *(const f32x4*)(row + g*4);
            Cv[g] = *(const f32x4*)(row + 16 + g*4);
        }
        float delta, r;
        softplus_r(row[32]*wdt + bdtv, delta, r);
        float du = delta * xc;
        f32x4 yacc = f32x4{0.f, 0.f, 0.f, 0.f};
        if (fastA) {
            float r2 = r*r, r3 = r2*r, r4 = r2*r2;
            f32x4 p0; p0[0]=r; p0[1]=r2; p0[2]=r3; p0[3]=r4;
            float s8 = r4*r4, s12 = s8*r4;
            h4[0] = p0*h4[0]       + du*Bv[0];
            h4[1] = (p0*r4)*h4[1]  + du*Bv[1];
            h4[2] = (p0*s8)*h4[2]  + du*Bv[2];
            h4[3] = (p0*s12)*h4[3] + du*Bv[3];
            yacc = yacc + h4[0]*Cv[0];
            yacc = yacc + h4[1]*Cv[1];
            yacc = yacc + h4[2]*Cv[2];
            yacc = yacc + h4[3]*Cv[3];
        } else {
            #pragma unroll
            for (int g = 0; g < 4; g++)
                #pragma unroll
                for (int j = 0; j < 4; j++) {
                    int s = g*4 + j;
                    h4[g][j] = __expf(delta*Aa[s])*h4[g][j] + du*Bv[g][j];
                    yacc[j] += h4[g][j]*Cv[g][j];
                }
        }
        float yv = (yacc[0] + yacc[1]) + (yacc[2] + yacc[3]);
        yv += xc * Dv;
        float z = bf2f(sZ[li*256 + threadIdx.x]);
        yv *= siluf(z);
        xz[bl*4096 + D_INNER + d] = __float2bfloat16(yv);
    }
}

// ---------------------------------------------------------------------------
extern "C" void kernel_launch(void* const* d_in, const int* in_sizes, int n_in,
                              void* d_out, int out_size, void* d_ws, size_t ws_size,
                              hipStream_t stream)
{
    char* ws = (char*)d_ws;
    bf16*  xz     = (bf16*) (ws);               // 33,554,432
    bf16*  wxpb   = (bf16*) (ws + 33554432);    //    524,288
    float* ssm    = (float*)(ws + 34078720);    //    589,824
    float* sumdq  = (float*)(ws + 34668544);    //  1,048,576
    float* Q      = (float*)(ws + 35717120);    // 16,777,216
    float* smallf = (float*)(ws + 52494336);    //    196,608
    int*   flag   = (int*)  (ws + 52690944);    //         64
    bf16*  woutb  = (bf16*) (ws + 52691008);    //  4,194,304  end: 56,885,312
    bf16*  xcb    = (bf16*) (ws + 56885312);    // 16,777,216  end: 73,662,528
    // xb and winb ALIAS Q (dead before scan writes Q)
    bf16*  xb     = (bf16*) (ws + 35717120);
    bf16*  winb   = (bf16*) (ws + 35717120 + 8388608);
    const bool big  = ws_size >= 56885312;
    const bool big2 = ws_size >= 73662528;   // xc-fusion path (r10)

    // 0) dtype probe + flag init
    dtype_probe<<<1, 64, 0, stream>>>((const unsigned short*)d_in[7], flag);

    // 1) weight prep (+ zero ssm, + A-structure check -> flag[1])
    cvt_prep<<<(N_WXPB + N_SMALL + N_SSMZ)/256, 256, 0, stream>>>(
        d_in[4], d_in[2], d_in[3], d_in[5], d_in[6], d_in[7], d_in[8],
        wxpb, smallf, ssm, flag);

    // 2) xz = x @ W_in.T  (M=4096, N=4096, K=1024) — relaxed 8-phase (r13)
    if (big) {
        cvt_all<<<1310720/256, 256, 0, stream>>>(
            d_in[0], d_in[1], d_in[9], xb, winb, woutb, flag);
        gemm8r<<<dim3(16, 16), 512, 0, stream>>>(xb, winb, xz);
    } else {
        gemm_dual<<<dim3(32, 32), 256, 0, stream>>>(
            d_in[0], D_MODEL, d_in[1], D_MODEL, xz, 2*D_INNER, D_MODEL, flag, 1, 1, 0);
    }

    // 3) ssm += conv+silu(x_in) @ Wxp.T  (+ spill xc to xcb when big2)
    xproj_fused<<<dim3(XSPLIT, 32), 256, 0, stream>>>(
        xz, wxpb, smallf, ssm, big2 ? xcb : (bf16*)nullptr);

    // 4) chunked selective scan (xc path when big2)
    {
        dim3 g(D_INNER/256, NCHUNK, BB);
        if (big2) {
            scan_partA_xc<CHUNK><<<g, 256, 0, stream>>>(ssm, xcb, smallf, sumdq, Q, flag);
            scan_combine<<<(BB*D_STATE*D_INNER)/256, 256, 0, stream>>>(sumdq, Q, smallf, NCHUNK);
            scan_partC_xc<CHUNK><<<g, 256, 0, stream>>>(ssm, xz, xcb, smallf, Q, flag);
        } else {
            scan_partA<CHUNK><<<g, 256, 0, stream>>>(ssm, xz, smallf, sumdq, Q, flag);
            scan_combine<<<(BB*D_STATE*D_INNER)/256, 256, 0, stream>>>(sumdq, Q, smallf, NCHUNK);
            scan_partC<CHUNK><<<g, 256, 0, stream>>>(ssm, xz, smallf, Q, flag);
        }
    }

    // 5) out = y @ W_out.T  (M=4096, N=1024, K=2048) — r6-verified gemm_n64
    if (big) {
        gemm_n64<<<dim3(D_MODEL/64, 32), 256, 0, stream>>>(
            xz + D_INNER, 2*D_INNER, woutb, D_INNER, d_out, D_MODEL, D_INNER, flag, 0, 1);
    } else {
        gemm_n64<<<dim3(D_MODEL/64, 32), 256, 0, stream>>>(
            xz + D_INNER, 2*D_INNER, d_in[9], D_INNER, d_out, D_MODEL, D_INNER, flag, 1, 1);
    }
}

// Round 14
// 268.003 us; speedup vs baseline: 1.0867x; 1.0354x over previous
//
#include <hip/hip_runtime.h>
#include <hip/hip_bf16.h>
#include <math.h>

// SelectiveSSM: D_MODEL=1024, D_STATE=16, D_CONV=4, EXPAND=2, B=2, L=2048
#define D_MODEL 1024
#define D_STATE 16
#define D_CONV  4
#define D_INNER 2048
#define BB      2
#define LL      2048
#define BLROWS  (BB*LL)       // 4096
#define NCHUNK  64
#define CHUNK   (LL/NCHUNK)   // 32
#define SSML    36            // padded ssm row stride (floats)
#define XSPLIT  16            // split-K factor for xproj

typedef __hip_bfloat16 bf16;
typedef __attribute__((ext_vector_type(8))) short short8;
typedef __attribute__((ext_vector_type(4))) float f32x4;

__device__ __forceinline__ float ldf(const void* p, long i, int isbf) {
    return isbf ? __bfloat162float(((const bf16*)p)[i]) : ((const float*)p)[i];
}
__device__ __forceinline__ short bfbits(float f) {
    bf16 h = __float2bfloat16(f);
    return *(short*)&h;
}
__device__ __forceinline__ float bits2f(short s) {
    bf16 h; *(short*)&h = s; return __bfloat162float(h);
}
__device__ __forceinline__ float bf2f(bf16 h) { return __bfloat162float(h); }
__device__ __forceinline__ float siluf(float x) {
    return __fdividef(x, 1.f + __expf(-x));
}
// fused stable softplus + exp-negation: delta = log(1+exp(x)), r = exp(-delta)
__device__ __forceinline__ void softplus_r(float x, float& delta, float& r) {
    float e = __expf(-fabsf(x));
    float t = 1.f + e;
    delta = fmaxf(x, 0.f) + __logf(t);
    r = __fdividef((x >= 0.f) ? e : 1.f, t);
}

// smallf float offsets
#define OFF_CW   0
#define OFF_CB   8192
#define OFF_WDT  10240
#define OFF_BDT  12288
#define OFF_AA   14336
#define OFF_D    47104
#define N_SMALL  49152
#define N_WXPB   (128*2048)
#define N_SSMZ   (BLROWS*SSML)

#define G_LDS16(gptr, lptr) __builtin_amdgcn_global_load_lds( \
    (const __attribute__((address_space(1))) void*)(gptr),    \
    (__attribute__((address_space(3))) void*)(lptr), 16, 0, 0)

// ---------------------------------------------------------------------------
// dtype probe + flag init. flag[0]=isbf, flag[1]=fastA.
// ---------------------------------------------------------------------------
__global__ void dtype_probe(const unsigned short* __restrict__ alog, int* __restrict__ flag) {
    if (threadIdx.x == 0) { flag[0] = (alog[1] != 0) ? 1 : 0; flag[1] = 1; }
}

// ---------------------------------------------------------------------------
// prep: padded bf16 W_xproj + fp32 smalls + zero ssm + A-structure check
// ---------------------------------------------------------------------------
__global__ __launch_bounds__(256) void cvt_prep(
    const void* __restrict__ Wxp, const void* __restrict__ cw,
    const void* __restrict__ cb, const void* __restrict__ wdt,
    const void* __restrict__ bdt, const void* __restrict__ alog,
    const void* __restrict__ Dp,
    bf16* __restrict__ wxpb, float* __restrict__ smallf,
    float* __restrict__ ssm, int* __restrict__ flag)
{
    const int isbf = flag[0];
    int idx = blockIdx.x * 256 + threadIdx.x;
    if (idx < N_WXPB) {
        int row = idx >> 11, col = idx & 2047;
        float v = (row < 33) ? ldf(Wxp, (long)row*2048 + col, isbf) : 0.f;
        wxpb[idx] = __float2bfloat16(v);
        return;
    }
    int j = idx - N_WXPB;
    if      (j < 8192)  smallf[OFF_CW  + j]         = ldf(cw,  j, isbf);
    else if (j < 10240) smallf[OFF_CB  + j - 8192]  = ldf(cb,  j - 8192, isbf);
    else if (j < 12288) smallf[OFF_WDT + j - 10240] = ldf(wdt, j - 10240, isbf);
    else if (j < 14336) smallf[OFF_BDT + j - 12288] = ldf(bdt, j - 12288, isbf);
    else if (j < 47104) {
        int jj = j - 14336;                 // = d*16 + s
        float aa = -__expf(ldf(alog, jj, isbf));
        smallf[OFF_AA + jj] = aa;
        int s = jj & 15;
        if (fabsf(aa + (float)(s+1)) > 1e-3f) flag[1] = 0;
    }
    else if (j < 49152) smallf[OFF_D   + j - 47104] = ldf(Dp,  j - 47104, isbf);
    else {
        int z = j - N_SMALL;
        if (z < N_SSMZ) ssm[z] = 0.f;
    }
}

// ---------------------------------------------------------------------------
// merged x/W_in/W_out -> bf16 conversion (8 elems/thread, one launch)
// ---------------------------------------------------------------------------
__global__ __launch_bounds__(256) void cvt_all(
    const void* __restrict__ x, const void* __restrict__ win,
    const void* __restrict__ wout,
    bf16* __restrict__ xb, bf16* __restrict__ winb, bf16* __restrict__ woutb,
    const int* __restrict__ flagp)
{
    const int isbf = *flagp;
    int i = blockIdx.x * 256 + threadIdx.x;
    const void* src; bf16* dst; long o;
    if (i < 524288)       { src = x;    dst = xb;    o = (long)i * 8; }
    else if (i < 1048576) { src = win;  dst = winb;  o = (long)(i - 524288) * 8; }
    else if (i < 1310720) { src = wout; dst = woutb; o = (long)(i - 1048576) * 8; }
    else return;
    short8 v;
    if (isbf) {
        v = *(const short8*)((const bf16*)src + o);
    } else {
        const float* s = (const float*)src + o;
        f32x4 u = *(const f32x4*)s, w = *(const f32x4*)(s + 4);
        v[0]=bfbits(u[0]); v[1]=bfbits(u[1]); v[2]=bfbits(u[2]); v[3]=bfbits(u[3]);
        v[4]=bfbits(w[0]); v[5]=bfbits(w[1]); v[6]=bfbits(w[2]); v[7]=bfbits(w[3]);
    }
    *(short8*)(dst + o) = v;
}

// ---------------------------------------------------------------------------
// gemm8r (r13-verified): snake 8-phase GEMM with relaxed scheduling.
// Compiler inserts fine-grained lgkmcnt per MFMA operand; only raw closing
// barriers (1/phase) + counted vmcnt. 51 -> <=42us vs pinned variants.
// ---------------------------------------------------------------------------
__global__ __launch_bounds__(512) void gemm8r(
    const bf16* __restrict__ A,    // [4096][1024] row-major
    const bf16* __restrict__ Bm,   // [4096][1024] row-major
    bf16* __restrict__ Cp)         // [4096][4096]
{
    __shared__ bf16 As[2][2][128*64];
    __shared__ bf16 Bs[2][2][128*64];
    const int t    = threadIdx.x;          // 0..511
    const int lane = t & 63;
    const int w    = t >> 6;               // 0..7
    const int rm   = w >> 2;               // 0..1 row-sub within quadrant
    const int cn   = w & 3;                // 0..3 col-sub within quadrant
    const int bm   = blockIdx.y, bn = blockIdx.x;
    const int quad = lane >> 4, l16 = lane & 15;
    const int NT   = 16;                   // K=1024 / BK=64

    f32x4 acc[2][2][4][2];
    #pragma unroll
    for (int a = 0; a < 2; a++)
        #pragma unroll
        for (int b = 0; b < 2; b++)
            #pragma unroll
            for (int i = 0; i < 4; i++)
                #pragma unroll
                for (int j = 0; j < 2; j++)
                    acc[a][b][i][j] = f32x4{0.f, 0.f, 0.f, 0.f};

    auto stageA = [&](int bufi, int half, int kt) {
        #pragma unroll
        for (int seg = 0; seg < 2; seg++) {
            int s = seg*512 + t, row = s >> 3, sg = s & 7;
            int col = (sg ^ (row & 7)) * 8;
            G_LDS16(A + ((long)bm*256 + half*128 + row)*1024 + kt*64 + col,
                    &As[bufi][half][s*8]);
        }
    };
    auto stageB = [&](int bufi, int half, int kt) {
        #pragma unroll
        for (int seg = 0; seg < 2; seg++) {
            int s = seg*512 + t, row = s >> 3, sg = s & 7;
            int col = (sg ^ (row & 7)) * 8;
            G_LDS16(Bm + ((long)bn*256 + half*128 + row)*1024 + kt*64 + col,
                    &Bs[bufi][half][s*8]);
        }
    };

    stageA(0, 0, 0); stageB(0, 0, 0); stageA(0, 1, 0); stageB(0, 1, 0);
    stageA(1, 0, 1); stageB(1, 0, 1);
    asm volatile("s_waitcnt vmcnt(4)" ::: "memory");
    __builtin_amdgcn_s_barrier();

    short8 af[4][2], bfv[2][2];
    for (int kt = 0; kt < NT; ++kt) {
        const int buf = kt & 1;
        #pragma unroll
        for (int p = 0; p < 4; ++p) {
            // snake: (qm,qn) = (0,1),(0,0),(1,0),(1,1)
            const int qm = p >> 1;
            const int qn = (p == 0 || p == 3) ? 1 : 0;
            if (p == 0 || p == 2) {
                #pragma unroll
                for (int fi = 0; fi < 4; fi++)
                    #pragma unroll
                    for (int kk = 0; kk < 2; kk++) {
                        int ar = rm*64 + fi*16 + l16;
                        int c = kk*4 + quad;
                        af[fi][kk] = *(const short8*)&As[buf][qm][ar*64 + ((c ^ (ar & 7))*8)];
                    }
            }
            if (p != 2) {
                #pragma unroll
                for (int fj = 0; fj < 2; fj++)
                    #pragma unroll
                    for (int kk = 0; kk < 2; kk++) {
                        int br = cn*32 + fj*16 + l16;
                        int c = kk*4 + quad;
                        bfv[fj][kk] = *(const short8*)&Bs[buf][qn][br*64 + ((c ^ (br & 7))*8)];
                    }
            }
            if      (p == 0) { if (kt + 1 < NT) stageA(buf ^ 1, 1, kt + 1); }
            else if (p == 1) { if (kt + 1 < NT) stageB(buf ^ 1, 1, kt + 1); }
            else if (p == 2) { if (kt + 2 < NT) stageA(buf, 0, kt + 2); }
            else             { if (kt + 2 < NT) stageB(buf, 0, kt + 2); }
            __builtin_amdgcn_s_setprio(1);
            #pragma unroll
            for (int kk = 0; kk < 2; kk++)
                #pragma unroll
                for (int fi = 0; fi < 4; fi++)
                    #pragma unroll
                    for (int fj = 0; fj < 2; fj++)
                        acc[qm][qn][fi][fj] = __builtin_amdgcn_mfma_f32_16x16x32_bf16(
                            af[fi][kk], bfv[fj][kk], acc[qm][qn][fi][fj], 0, 0, 0);
            __builtin_amdgcn_s_setprio(0);
            if (p == 3) {
                if (kt == NT - 2)     { asm volatile("s_waitcnt vmcnt(0)" ::: "memory"); }
                else if (kt < NT - 2) { asm volatile("s_waitcnt vmcnt(4)" ::: "memory"); }
            }
            __builtin_amdgcn_s_barrier();
        }
    }

    #pragma unroll
    for (int qm = 0; qm < 2; qm++)
        #pragma unroll
        for (int qn = 0; qn < 2; qn++)
            #pragma unroll
            for (int fi = 0; fi < 4; fi++)
                #pragma unroll
                for (int fj = 0; fj < 2; fj++)
                    #pragma unroll
                    for (int r = 0; r < 4; r++) {
                        int row = bm*256 + qm*128 + rm*64 + fi*16 + quad*4 + r;
                        int col = bn*256 + qn*128 + cn*32 + fj*16 + l16;
                        Cp[(long)row * 4096 + col] = __float2bfloat16(acc[qm][qn][fi][fj][r]);
                    }
}

// ---------------------------------------------------------------------------
// GEMM fallback (small-ws path): 128x128 tile, BK=64, XOR-swizzled LDS
// ---------------------------------------------------------------------------
__global__ __launch_bounds__(256) void gemm_dual(
    const void* __restrict__ A, int lda,
    const void* __restrict__ Bm, int ldb,
    void* __restrict__ Cp, int ldc, int K,
    const int* __restrict__ flagp, int amode, int bmode, int cmode)
{
    const int isbf = *flagp;
    const int a_bf = amode ? isbf : 1;
    const int b_bf = bmode ? isbf : 1;
    const int c_bf = cmode ? isbf : 1;

    __shared__ bf16 As[128*64];
    __shared__ bf16 Bs[128*64];
    const int t    = threadIdx.x;
    const int lane = t & 63;
    const int w    = t >> 6;
    const int wm   = w >> 1, wn = w & 1;
    const int bm   = blockIdx.y, bn = blockIdx.x;
    const int quad = lane >> 4, l16 = lane & 15;

    f32x4 acc[4][4];
    #pragma unroll
    for (int i = 0; i < 4; i++)
        #pragma unroll
        for (int j = 0; j < 4; j++)
            acc[i][j] = f32x4{0.f, 0.f, 0.f, 0.f};

    for (int k0 = 0; k0 < K; k0 += 64) {
        __syncthreads();
        if (a_bf) {
            #pragma unroll
            for (int seg = 0; seg < 4; seg++) {
                int s = seg*256 + t, row = s >> 3, sg = s & 7;
                int col = (sg ^ (row & 7)) * 8;
                const bf16* ga = (const bf16*)A + ((long)bm*128 + row)*(long)lda + k0 + col;
                G_LDS16(ga, &As[row*64 + sg*8]);
            }
        } else {
            #pragma unroll
            for (int seg = 0; seg < 4; seg++) {
                int s = seg*256 + t, row = s >> 3, sg = s & 7;
                int col = (sg ^ (row & 7)) * 8;
                const float* ap = (const float*)A + ((long)bm*128 + row)*(long)lda + k0 + col;
                f32x4 u = *(const f32x4*)ap, v = *(const f32x4*)(ap + 4);
                short8 va;
                va[0]=bfbits(u[0]); va[1]=bfbits(u[1]); va[2]=bfbits(u[2]); va[3]=bfbits(u[3]);
                va[4]=bfbits(v[0]); va[5]=bfbits(v[1]); va[6]=bfbits(v[2]); va[7]=bfbits(v[3]);
                *(short8*)&As[row*64 + sg*8] = va;
            }
        }
        if (b_bf) {
            #pragma unroll
            for (int seg = 0; seg < 4; seg++) {
                int s = seg*256 + t, row = s >> 3, sg = s & 7;
                int col = (sg ^ (row & 7)) * 8;
                const bf16* gb = (const bf16*)Bm + ((long)bn*128 + row)*(long)ldb + k0 + col;
                G_LDS16(gb, &Bs[row*64 + sg*8]);
            }
        } else {
            #pragma unroll
            for (int seg = 0; seg < 4; seg++) {
                int s = seg*256 + t, row = s >> 3, sg = s & 7;
                int col = (sg ^ (row & 7)) * 8;
                const float* bp = (const float*)Bm + ((long)bn*128 + row)*(long)ldb + k0 + col;
                f32x4 u = *(const f32x4*)bp, v = *(const f32x4*)(bp + 4);
                short8 vb;
                vb[0]=bfbits(u[0]); vb[1]=bfbits(u[1]); vb[2]=bfbits(u[2]); vb[3]=bfbits(u[3]);
                vb[4]=bfbits(v[0]); vb[5]=bfbits(v[1]); vb[6]=bfbits(v[2]); vb[7]=bfbits(v[3]);
                *(short8*)&Bs[row*64 + sg*8] = vb;
            }
        }
        __syncthreads();

        #pragma unroll
        for (int kk = 0; kk < 64; kk += 32) {
            const int cbase = kk >> 3;
            short8 af[4], bfr[4];
            #pragma unroll
            for (int mi = 0; mi < 4; mi++) {
                int row = wm*64 + mi*16 + l16;
                int c = cbase + quad;
                af[mi] = *(const short8*)&As[row*64 + ((c ^ (row & 7))*8)];
            }
            #pragma unroll
            for (int ni = 0; ni < 4; ni++) {
                int row = wn*64 + ni*16 + l16;
                int c = cbase + quad;
                bfr[ni] = *(const short8*)&Bs[row*64 + ((c ^ (row & 7))*8)];
            }
            #pragma unroll
            for (int mi = 0; mi < 4; mi++)
                #pragma unroll
                for (int ni = 0; ni < 4; ni++)
                    acc[mi][ni] = __builtin_amdgcn_mfma_f32_16x16x32_bf16(
                        af[mi], bfr[ni], acc[mi][ni], 0, 0, 0);
        }
    }

    #pragma unroll
    for (int mi = 0; mi < 4; mi++)
        #pragma unroll
        for (int ni = 0; ni < 4; ni++)
            #pragma unroll
            for (int r = 0; r < 4; r++) {
                int row = bm*128 + wm*64 + mi*16 + quad*4 + r;
                int col = bn*128 + wn*64 + ni*16 + l16;
                float val = acc[mi][ni][r];
                if (c_bf) ((bf16*)Cp)[(long)row * ldc + col] = __float2bfloat16(val);
                else      ((float*)Cp)[(long)row * ldc + col] = val;
            }
}

// ---------------------------------------------------------------------------
// GEMM2 (r6-verified): 128x64 tile, BK=64, XOR swizzle. Grid (16,32).
// ---------------------------------------------------------------------------
__global__ __launch_bounds__(256) void gemm_n64(
    const bf16* __restrict__ A, int lda,
    const void* __restrict__ Bm, int ldb,
    void* __restrict__ Cp, int ldc, int K,
    const int* __restrict__ flagp, int bmode, int cmode)
{
    const int isbf = *flagp;
    const int b_bf = bmode ? isbf : 1;
    const int c_bf = cmode ? isbf : 1;

    __shared__ bf16 As[128*64];
    __shared__ bf16 Bs[64*64];
    const int t    = threadIdx.x;
    const int lane = t & 63;
    const int w    = t >> 6;
    const int wm   = w >> 1, wn = w & 1;
    const int bm   = blockIdx.y, bn = blockIdx.x;
    const int quad = lane >> 4, l16 = lane & 15;

    f32x4 acc[4][2];
    #pragma unroll
    for (int i = 0; i < 4; i++)
        #pragma unroll
        for (int j = 0; j < 2; j++)
            acc[i][j] = f32x4{0.f, 0.f, 0.f, 0.f};

    for (int k0 = 0; k0 < K; k0 += 64) {
        __syncthreads();
        #pragma unroll
        for (int seg = 0; seg < 4; seg++) {
            int s = seg*256 + t, row = s >> 3, sg = s & 7;
            int col = (sg ^ (row & 7)) * 8;
            const bf16* ga = A + ((long)bm*128 + row)*(long)lda + k0 + col;
            G_LDS16(ga, &As[row*64 + sg*8]);
        }
        if (b_bf) {
            #pragma unroll
            for (int seg = 0; seg < 2; seg++) {
                int s = seg*256 + t, row = s >> 3, sg = s & 7;
                int col = (sg ^ (row & 7)) * 8;
                const bf16* gb = (const bf16*)Bm + ((long)bn*64 + row)*(long)ldb + k0 + col;
                G_LDS16(gb, &Bs[row*64 + sg*8]);
            }
        } else {
            #pragma unroll
            for (int seg = 0; seg < 2; seg++) {
                int s = seg*256 + t, row = s >> 3, sg = s & 7;
                int col = (sg ^ (row & 7)) * 8;
                const float* bp = (const float*)Bm + ((long)bn*64 + row)*(long)ldb + k0 + col;
                f32x4 u = *(const f32x4*)bp, v = *(const f32x4*)(bp + 4);
                short8 vb;
                vb[0]=bfbits(u[0]); vb[1]=bfbits(u[1]); vb[2]=bfbits(u[2]); vb[3]=bfbits(u[3]);
                vb[4]=bfbits(v[0]); vb[5]=bfbits(v[1]); vb[6]=bfbits(v[2]); vb[7]=bfbits(v[3]);
                *(short8*)&Bs[row*64 + sg*8] = vb;
            }
        }
        __syncthreads();

        #pragma unroll
        for (int kk = 0; kk < 64; kk += 32) {
            const int cbase = kk >> 3;
            short8 af[4], bfr[2];
            #pragma unroll
            for (int mi = 0; mi < 4; mi++) {
                int row = wm*64 + mi*16 + l16;
                int c = cbase + quad;
                af[mi] = *(const short8*)&As[row*64 + ((c ^ (row & 7))*8)];
            }
            #pragma unroll
            for (int ni = 0; ni < 2; ni++) {
                int row = wn*32 + ni*16 + l16;
                int c = cbase + quad;
                bfr[ni] = *(const short8*)&Bs[row*64 + ((c ^ (row & 7))*8)];
            }
            #pragma unroll
            for (int mi = 0; mi < 4; mi++)
                #pragma unroll
                for (int ni = 0; ni < 2; ni++)
                    acc[mi][ni] = __builtin_amdgcn_mfma_f32_16x16x32_bf16(
                        af[mi], bfr[ni], acc[mi][ni], 0, 0, 0);
        }
    }

    #pragma unroll
    for (int mi = 0; mi < 4; mi++)
        #pragma unroll
        for (int ni = 0; ni < 2; ni++)
            #pragma unroll
            for (int r = 0; r < 4; r++) {
                int row = bm*128 + wm*64 + mi*16 + quad*4 + r;
                int col = bn*64 + wn*32 + ni*16 + l16;
                float val = acc[mi][ni][r];
                if (c_bf) ((bf16*)Cp)[(long)row * ldc + col] = __float2bfloat16(val);
                else      ((float*)Cp)[(long)row * ldc + col] = val;
            }
}

// ---------------------------------------------------------------------------
// xproj fused, split-K. r14: when ssmp != null, each split writes its own
// slab ssmp[split][4096][36] with PLAIN stores (disjoint regions) instead of
// 2.36M cross-XCD atomicAdds to shared ssm (r13 counters: 42.6us with
// MfmaUtil 1.3%/VALU 14%/Occ 15% — all idle => contended-atomic tail).
// ssm_reduce then sums the 16 slabs. Fallback (ssmp==null): atomic path.
// ---------------------------------------------------------------------------
__global__ __launch_bounds__(256) void xproj_fused(
    const bf16* __restrict__ xz, const bf16* __restrict__ wxpb,
    const float* __restrict__ smallf, float* __restrict__ ssm,
    bf16* __restrict__ xcb, float* __restrict__ ssmp)
{
    const float* cwf = smallf + OFF_CW;
    const float* cbf = smallf + OFF_CB;
    __shared__ bf16 As[128*32];
    __shared__ bf16 Bs[128*32];
    const int t    = threadIdx.x;
    const int lane = t & 63;
    const int w    = t >> 6;
    const int wm   = w >> 1, wn = w & 1;
    const int bm   = blockIdx.y;
    const int ks   = blockIdx.x * (D_INNER / XSPLIT);
    const int quad = lane >> 4, l16 = lane & 15;

    f32x4 acc[4][4];
    #pragma unroll
    for (int i = 0; i < 4; i++)
        #pragma unroll
        for (int j = 0; j < 4; j++)
            acc[i][j] = f32x4{0.f, 0.f, 0.f, 0.f};

    for (int k0 = ks; k0 < ks + D_INNER/XSPLIT; k0 += 32) {
        __syncthreads();
        #pragma unroll
        for (int seg = 0; seg < 2; seg++) {
            int s = seg*256 + t, row = s >> 2, dcol = (s & 3) * 8;
            int blg = bm*128 + row;
            int b = blg >> 11, l = blg & (LL - 1);
            int d0 = k0 + dcol;
            float a[8];
            {
                f32x4 c0 = *(const f32x4*)&cbf[d0], c1 = *(const f32x4*)&cbf[d0+4];
                a[0]=c0[0]; a[1]=c0[1]; a[2]=c0[2]; a[3]=c0[3];
                a[4]=c1[0]; a[5]=c1[1]; a[6]=c1[2]; a[7]=c1[3];
            }
            f32x4 cw4[8];
            #pragma unroll
            for (int j = 0; j < 8; j++) cw4[j] = *(const f32x4*)&cwf[(d0+j)*4];
            #pragma unroll
            for (int kk = 0; kk < D_CONV; kk++) {
                int ls = l - 3 + kk;
                if (ls >= 0) {
                    short8 xv = *(const short8*)&xz[((long)(b*LL + ls))*4096 + d0];
                    #pragma unroll
                    for (int j = 0; j < 8; j++) a[j] += bits2f(xv[j]) * cw4[j][kk];
                }
            }
            short8 va;
            #pragma unroll
            for (int j = 0; j < 8; j++) va[j] = bfbits(siluf(a[j]));
            *(short8*)&As[row*32 + dcol] = va;
            if (xcb) *(short8*)&xcb[(long)blg*D_INNER + d0] = va;
        }
        #pragma unroll
        for (int seg = 0; seg < 2; seg++) {
            int s = seg*256 + t, row = s >> 2, col = (s & 3) * 8;
            const bf16* gb = wxpb + (long)row*D_INNER + k0 + col;
            G_LDS16(gb, &Bs[row*32 + col]);
        }
        __syncthreads();

        short8 af[4], bfr[4];
        #pragma unroll
        for (int mi = 0; mi < 4; mi++)
            af[mi] = *(const short8*)&As[(wm*64 + mi*16 + l16)*32 + quad*8];
        #pragma unroll
        for (int ni = 0; ni < 4; ni++)
            bfr[ni] = *(const short8*)&Bs[(wn*64 + ni*16 + l16)*32 + quad*8];
        #pragma unroll
        for (int mi = 0; mi < 4; mi++)
            #pragma unroll
            for (int ni = 0; ni < 4; ni++)
                acc[mi][ni] = __builtin_amdgcn_mfma_f32_16x16x32_bf16(
                    af[mi], bfr[ni], acc[mi][ni], 0, 0, 0);
    }

    if (ssmp) {
        float* dst = ssmp + (long)blockIdx.x * BLROWS * SSML;
        #pragma unroll
        for (int mi = 0; mi < 4; mi++)
            #pragma unroll
            for (int ni = 0; ni < 4; ni++) {
                int col = wn*64 + ni*16 + l16;
                if (col < 33) {
                    int newcol = (col == 0) ? 32 : (col - 1);
                    #pragma unroll
                    for (int r = 0; r < 4; r++) {
                        int row = bm*128 + wm*64 + mi*16 + quad*4 + r;
                        dst[(long)row * SSML + newcol] = acc[mi][ni][r];
                    }
                }
            }
    } else {
        #pragma unroll
        for (int mi = 0; mi < 4; mi++)
            #pragma unroll
            for (int ni = 0; ni < 4; ni++) {
                int col = wn*64 + ni*16 + l16;
                if (col < 33) {
                    int newcol = (col == 0) ? 32 : (col - 1);
                    #pragma unroll
                    for (int r = 0; r < 4; r++) {
                        int row = bm*128 + wm*64 + mi*16 + quad*4 + r;
                        atomicAdd(&ssm[(long)row * SSML + newcol], acc[mi][ni][r]);
                    }
                }
            }
    }
}

// ---------------------------------------------------------------------------
// ssm_reduce (r14): ssm[idx] = sum over XSPLIT slabs of ssmp. Pad cols
// (>=33, never written by xproj) are zeroed. Fully coalesced per slab.
// ---------------------------------------------------------------------------
__global__ __launch_bounds__(256) void ssm_reduce(
    const float* __restrict__ ssmp, float* __restrict__ ssm)
{
    int idx = blockIdx.x * 256 + threadIdx.x;     // 0 .. BLROWS*SSML-1
    if (idx >= BLROWS * SSML) return;
    int col = idx % SSML;
    float s = 0.f;
    if (col < 33) {
        #pragma unroll
        for (int p = 0; p < XSPLIT; p++)
            s += ssmp[(long)p * BLROWS * SSML + idx];
    }
    ssm[idx] = s;
}

// ---------------------------------------------------------------------------
// Scan phase A (fallback): packed-f32 h, LDS x-prefetch + conv.
// ---------------------------------------------------------------------------
template<int CHUNK_T>
__global__ __launch_bounds__(256) void scan_partA(
    const float* __restrict__ ssm, const bf16* __restrict__ xz,
    const float* __restrict__ smallf,
    float* __restrict__ sumdq, float* __restrict__ Q,
    const int* __restrict__ flag)
{
    __shared__ float sL[CHUNK_T*SSML];
    __shared__ bf16  sX[CHUNK_T*256];
    const int fastA = flag[1];
    int d = blockIdx.x * 256 + threadIdx.x;
    int c = blockIdx.y, b = blockIdx.z;
    const int NC = gridDim.y;
    int l0 = c * CHUNK_T;
    {
        const float* src = ssm + (long)(b*LL + l0) * SSML;
        for (int idx = threadIdx.x; idx < CHUNK_T*SSML; idx += 256) sL[idx] = src[idx];
        const bf16* xsrc = xz + (long)(b*LL + l0)*4096 + blockIdx.x*256;
        for (int j = threadIdx.x; j < CHUNK_T*32; j += 256) {
            int li = j >> 5, ln = j & 31;
            *(short8*)&sX[li*256 + ln*8] = *(const short8*)&xsrc[(long)li*4096 + ln*8];
        }
    }
    f32x4 h4[4];
    #pragma unroll
    for (int g = 0; g < 4; g++) h4[g] = f32x4{0.f, 0.f, 0.f, 0.f};
    float Aa[D_STATE];
    if (!fastA) {
        #pragma unroll
        for (int s = 0; s < D_STATE; s++) Aa[s] = smallf[OFF_AA + d*D_STATE + s];
    }
    f32x4 cw4 = *(const f32x4*)&smallf[OFF_CW + d*4];
    float cbv  = smallf[OFF_CB + d];
    float wdt  = smallf[OFF_WDT + d];
    float bdtv = smallf[OFF_BDT + d];
    float win[3];
    #pragma unroll
    for (int k = 0; k < 3; k++) {
        int ls = l0 - 3 + k;
        win[k] = (ls >= 0) ? bf2f(xz[((long)(b*LL + ls))*4096 + d]) : 0.f;
    }
    __syncthreads();
    float sumd = 0.f;
    #pragma unroll 4
    for (int li = 0; li < CHUNK_T; li++) {
        float xnew = bf2f(sX[li*256 + threadIdx.x]);
        float convv = cbv + win[0]*cw4[0] + win[1]*cw4[1] + win[2]*cw4[2] + xnew*cw4[3];
        win[0] = win[1]; win[1] = win[2]; win[2] = xnew;
        float xc = siluf(convv);
        const float* row = &sL[li*SSML];
        f32x4 Bv[4];
        #pragma unroll
        for (int g = 0; g < 4; g++) Bv[g] = *(const f32x4*)(row + g*4);
        float delta, r;
        softplus_r(row[32]*wdt + bdtv, delta, r);
        sumd += delta;
        float du = delta * xc;
        if (fastA) {
            float r2 = r*r, r3 = r2*r, r4 = r2*r2;
            f32x4 p0; p0[0]=r; p0[1]=r2; p0[2]=r3; p0[3]=r4;
            float s8 = r4*r4, s12 = s8*r4;
            h4[0] = p0*h4[0]       + du*Bv[0];
            h4[1] = (p0*r4)*h4[1]  + du*Bv[1];
            h4[2] = (p0*s8)*h4[2]  + du*Bv[2];
            h4[3] = (p0*s12)*h4[3] + du*Bv[3];
        } else {
            #pragma unroll
            for (int g = 0; g < 4; g++)
                #pragma unroll
                for (int j = 0; j < 4; j++) {
                    int s = g*4 + j;
                    h4[g][j] = __expf(delta*Aa[s])*h4[g][j] + du*Bv[g][j];
                }
        }
    }
    sumdq[(long)(b*NC + c)*D_INNER + d] = sumd;
    long o = ((long)(b*NC + c)*D_STATE)*D_INNER + d;
    #pragma unroll
    for (int s = 0; s < D_STATE; s++)
        Q[o + (long)s*D_INNER] = h4[s >> 2][s & 3];
}

// ---------------------------------------------------------------------------
// Scan phase A, xc path (r10-verified): xc pre-computed by xproj (xcb).
// ---------------------------------------------------------------------------
template<int CHUNK_T>
__global__ __launch_bounds__(256) void scan_partA_xc(
    const float* __restrict__ ssm, const bf16* __restrict__ xcb,
    const float* __restrict__ smallf,
    float* __restrict__ sumdq, float* __restrict__ Q,
    const int* __restrict__ flag)
{
    __shared__ float sL[CHUNK_T*SSML];
    __shared__ bf16  sX[CHUNK_T*256];
    const int fastA = flag[1];
    int d = blockIdx.x * 256 + threadIdx.x;
    int c = blockIdx.y, b = blockIdx.z;
    const int NC = gridDim.y;
    int l0 = c * CHUNK_T;
    {
        const float* src = ssm + (long)(b*LL + l0) * SSML;
        for (int idx = threadIdx.x; idx < CHUNK_T*SSML; idx += 256) sL[idx] = src[idx];
        const bf16* xsrc = xcb + (long)(b*LL + l0)*D_INNER + blockIdx.x*256;
        for (int j = threadIdx.x; j < CHUNK_T*32; j += 256) {
            int li = j >> 5, ln = j & 31;
            *(short8*)&sX[li*256 + ln*8] = *(const short8*)&xsrc[(long)li*D_INNER + ln*8];
        }
    }
    f32x4 h4[4];
    #pragma unroll
    for (int g = 0; g < 4; g++) h4[g] = f32x4{0.f, 0.f, 0.f, 0.f};
    float Aa[D_STATE];
    if (!fastA) {
        #pragma unroll
        for (int s = 0; s < D_STATE; s++) Aa[s] = smallf[OFF_AA + d*D_STATE + s];
    }
    float wdt  = smallf[OFF_WDT + d];
    float bdtv = smallf[OFF_BDT + d];
    __syncthreads();
    float sumd = 0.f;
    #pragma unroll 4
    for (int li = 0; li < CHUNK_T; li++) {
        float xc = bf2f(sX[li*256 + threadIdx.x]);
        const float* row = &sL[li*SSML];
        f32x4 Bv[4];
        #pragma unroll
        for (int g = 0; g < 4; g++) Bv[g] = *(const f32x4*)(row + g*4);
        float delta, r;
        softplus_r(row[32]*wdt + bdtv, delta, r);
        sumd += delta;
        float du = delta * xc;
        if (fastA) {
            float r2 = r*r, r3 = r2*r, r4 = r2*r2;
            f32x4 p0; p0[0]=r; p0[1]=r2; p0[2]=r3; p0[3]=r4;
            float s8 = r4*r4, s12 = s8*r4;
            h4[0] = p0*h4[0]       + du*Bv[0];
            h4[1] = (p0*r4)*h4[1]  + du*Bv[1];
            h4[2] = (p0*s8)*h4[2]  + du*Bv[2];
            h4[3] = (p0*s12)*h4[3] + du*Bv[3];
        } else {
            #pragma unroll
            for (int g = 0; g < 4; g++)
                #pragma unroll
                for (int j = 0; j < 4; j++) {
                    int s = g*4 + j;
                    h4[g][j] = __expf(delta*Aa[s])*h4[g][j] + du*Bv[g][j];
                }
        }
    }
    sumdq[(long)(b*NC + c)*D_INNER + d] = sumd;
    long o = ((long)(b*NC + c)*D_STATE)*D_INNER + d;
    #pragma unroll
    for (int s = 0; s < D_STATE; s++)
        Q[o + (long)s*D_INNER] = h4[s >> 2][s & 3];
}

// ---------------------------------------------------------------------------
// Scan phase B: combine chunks per (b,d,s); P recomputed from sumd.
// ---------------------------------------------------------------------------
__global__ __launch_bounds__(256) void scan_combine(
    const float* __restrict__ sumdq, float* __restrict__ Q_hst,
    const float* __restrict__ smallf, int NC)
{
    int t = blockIdx.x * 256 + threadIdx.x;   // (b,s,d): d fastest
    int d = t & (D_INNER - 1);
    int s = (t >> 11) & (D_STATE - 1);
    int b = t >> 15;
    float Aa = smallf[OFF_AA + d*D_STATE + s];
    float h = 0.f;
    #pragma unroll 4
    for (int c = 0; c < NC; c++) {
        float sd = sumdq[(long)(b*NC + c)*D_INNER + d];
        long idx = ((long)(b*NC + c)*D_STATE + s)*D_INNER + d;
        float q = Q_hst[idx];
        Q_hst[idx] = h;
        h = __expf(Aa*sd)*h + q;
    }
}

// ---------------------------------------------------------------------------
// Scan phase C (fallback): packed-f32; x AND z prefetched.
// ---------------------------------------------------------------------------
template<int CHUNK_T>
__global__ __launch_bounds__(256) void scan_partC(
    const float* __restrict__ ssm, bf16* __restrict__ xz,
    const float* __restrict__ smallf, const float* __restrict__ hst,
    const int* __restrict__ flag)
{
    __shared__ float sL[CHUNK_T*SSML];
    __shared__ bf16  sX[CHUNK_T*256];
    __shared__ bf16  sZ[CHUNK_T*256];
    const int fastA = flag[1];
    int d = blockIdx.x * 256 + threadIdx.x;
    int c = blockIdx.y, b = blockIdx.z;
    const int NC = gridDim.y;
    int l0 = c * CHUNK_T;
    {
        const float* src = ssm + (long)(b*LL + l0) * SSML;
        for (int idx = threadIdx.x; idx < CHUNK_T*SSML; idx += 256) sL[idx] = src[idx];
        const bf16* xsrc = xz + (long)(b*LL + l0)*4096 + blockIdx.x*256;
        for (int j = threadIdx.x; j < CHUNK_T*32; j += 256) {
            int li = j >> 5, ln = j & 31;
            *(short8*)&sX[li*256 + ln*8] = *(const short8*)&xsrc[(long)li*4096 + ln*8];
            *(short8*)&sZ[li*256 + ln*8] = *(const short8*)&xsrc[(long)li*4096 + D_INNER + ln*8];
        }
    }
    f32x4 h4[4];
    long o = ((long)(b*NC + c)*D_STATE)*D_INNER + d;
    #pragma unroll
    for (int s = 0; s < D_STATE; s++) h4[s >> 2][s & 3] = hst[o + (long)s*D_INNER];
    float Aa[D_STATE];
    if (!fastA) {
        #pragma unroll
        for (int s = 0; s < D_STATE; s++) Aa[s] = smallf[OFF_AA + d*D_STATE + s];
    }
    f32x4 cw4 = *(const f32x4*)&smallf[OFF_CW + d*4];
    float cbv  = smallf[OFF_CB + d];
    float wdt  = smallf[OFF_WDT + d];
    float bdtv = smallf[OFF_BDT + d];
    float Dv   = smallf[OFF_D + d];
    float win[3];
    #pragma unroll
    for (int k = 0; k < 3; k++) {
        int ls = l0 - 3 + k;
        win[k] = (ls >= 0) ? bf2f(xz[((long)(b*LL + ls))*4096 + d]) : 0.f;
    }
    __syncthreads();
    #pragma unroll 2
    for (int li = 0; li < CHUNK_T; li++) {
        long bl = (long)(b*LL + l0 + li);
        float xnew = bf2f(sX[li*256 + threadIdx.x]);
        float convv = cbv + win[0]*cw4[0] + win[1]*cw4[1] + win[2]*cw4[2] + xnew*cw4[3];
        win[0] = win[1]; win[1] = win[2]; win[2] = xnew;
        float xc = siluf(convv);
        const float* row = &sL[li*SSML];
        f32x4 Bv[4], Cv[4];
        #pragma unroll
        for (int g = 0; g < 4; g++) {
            Bv[g] = *(const f32x4*)(row + g*4);
            Cv[g] = *(const f32x4*)(row + 16 + g*4);
        }
        float delta, r;
        softplus_r(row[32]*wdt + bdtv, delta, r);
        float du = delta * xc;
        f32x4 yacc = f32x4{0.f, 0.f, 0.f, 0.f};
        if (fastA) {
            float r2 = r*r, r3 = r2*r, r4 = r2*r2;
            f32x4 p0; p0[0]=r; p0[1]=r2; p0[2]=r3; p0[3]=r4;
            float s8 = r4*r4, s12 = s8*r4;
            h4[0] = p0*h4[0]       + du*Bv[0];
            h4[1] = (p0*r4)*h4[1]  + du*Bv[1];
            h4[2] = (p0*s8)*h4[2]  + du*Bv[2];
            h4[3] = (p0*s12)*h4[3] + du*Bv[3];
            yacc = yacc + h4[0]*Cv[0];
            yacc = yacc + h4[1]*Cv[1];
            yacc = yacc + h4[2]*Cv[2];
            yacc = yacc + h4[3]*Cv[3];
        } else {
            #pragma unroll
            for (int g = 0; g < 4; g++)
                #pragma unroll
                for (int j = 0; j < 4; j++) {
                    int s = g*4 + j;
                    h4[g][j] = __expf(delta*Aa[s])*h4[g][j] + du*Bv[g][j];
                    yacc[j] += h4[g][j]*Cv[g][j];
                }
        }
        float yv = (yacc[0] + yacc[1]) + (yacc[2] + yacc[3]);
        yv += xc * Dv;
        float z = bf2f(sZ[li*256 + threadIdx.x]);
        yv *= siluf(z);
        xz[bl*4096 + D_INNER + d] = __float2bfloat16(yv);
    }
}

// ---------------------------------------------------------------------------
// Scan phase C, xc path (r10-verified): xc from xcb — no conv window.
// ---------------------------------------------------------------------------
template<int CHUNK_T>
__global__ __launch_bounds__(256) void scan_partC_xc(
    const float* __restrict__ ssm, bf16* __restrict__ xz,
    const bf16* __restrict__ xcb,
    const float* __restrict__ smallf, const float* __restrict__ hst,
    const int* __restrict__ flag)
{
    __shared__ float sL[CHUNK_T*SSML];
    __shared__ bf16  sX[CHUNK_T*256];
    __shared__ bf16  sZ[CHUNK_T*256];
    const int fastA = flag[1];
    int d = blockIdx.x * 256 + threadIdx.x;
    int c = blockIdx.y, b = blockIdx.z;
    const int NC = gridDim.y;
    int l0 = c * CHUNK_T;
    {
        const float* src = ssm + (long)(b*LL + l0) * SSML;
        for (int idx = threadIdx.x; idx < CHUNK_T*SSML; idx += 256) sL[idx] = src[idx];
        const bf16* xcs = xcb + (long)(b*LL + l0)*D_INNER + blockIdx.x*256;
        const bf16* zs  = xz  + (long)(b*LL + l0)*4096 + D_INNER + blockIdx.x*256;
        for (int j = threadIdx.x; j < CHUNK_T*32; j += 256) {
            int li = j >> 5, ln = j & 31;
            *(short8*)&sX[li*256 + ln*8] = *(const short8*)&xcs[(long)li*D_INNER + ln*8];
            *(short8*)&sZ[li*256 + ln*8] = *(const short8*)&zs[(long)li*4096 + ln*8];
        }
    }
    f32x4 h4[4];
    long o = ((long)(b*NC + c)*D_STATE)*D_INNER + d;
    #pragma unroll
    for (int s = 0; s < D_STATE; s++) h4[s >> 2][s & 3] = hst[o + (long)s*D_INNER];
    float Aa[D_STATE];
    if (!fastA) {
        #pragma unroll
        for (int s = 0; s < D_STATE; s++) Aa[s] = smallf[OFF_AA + d*D_STATE + s];
    }
    float wdt  = smallf[OFF_WDT + d];
    float bdtv = smallf[OFF_BDT + d];
    float Dv   = smallf[OFF_D + d];
    __syncthreads();
    #pragma unroll 2
    for (int li = 0; li < CHUNK_T; li++) {
        long bl = (long)(b*LL + l0 + li);
        float xc = bf2f(sX[li*256 + threadIdx.x]);
        const float* row = &sL[li*SSML];
        f32x4 Bv[4], Cv[4];
        #pragma unroll
        for (int g = 0; g < 4; g++) {
            Bv[g] = *(const f32x4*)(row + g*4);
            Cv[g] = *(const f32x4*)(row + 16 + g*4);
        }
        float delta, r;
        softplus_r(row[32]*wdt + bdtv, delta, r);
        float du = delta * xc;
        f32x4 yacc = f32x4{0.f, 0.f, 0.f, 0.f};
        if (fastA) {
            float r2 = r*r, r3 = r2*r, r4 = r2*r2;
            f32x4 p0; p0[0]=r; p0[1]=r2; p0[2]=r3; p0[3]=r4;
            float s8 = r4*r4, s12 = s8*r4;
            h4[0] = p0*h4[0]       + du*Bv[0];
            h4[1] = (p0*r4)*h4[1]  + du*Bv[1];
            h4[2] = (p0*s8)*h4[2]  + du*Bv[2];
            h4[3] = (p0*s12)*h4[3] + du*Bv[3];
            yacc = yacc + h4[0]*Cv[0];
            yacc = yacc + h4[1]*Cv[1];
            yacc = yacc + h4[2]*Cv[2];
            yacc = yacc + h4[3]*Cv[3];
        } else {
            #pragma unroll
            for (int g = 0; g < 4; g++)
                #pragma unroll
                for (int j = 0; j < 4; j++) {
                    int s = g*4 + j;
                    h4[g][j] = __expf(delta*Aa[s])*h4[g][j] + du*Bv[g][j];
                    yacc[j] += h4[g][j]*Cv[g][j];
                }
        }
        float yv = (yacc[0] + yacc[1]) + (yacc[2] + yacc[3]);
        yv += xc * Dv;
        float z = bf2f(sZ[li*256 + threadIdx.x]);
        yv *= siluf(z);
        xz[bl*4096 + D_INNER + d] = __float2bfloat16(yv);
    }
}

// ---------------------------------------------------------------------------
extern "C" void kernel_launch(void* const* d_in, const int* in_sizes, int n_in,
                              void* d_out, int out_size, void* d_ws, size_t ws_size,
                              hipStream_t stream)
{
    char* ws = (char*)d_ws;
    bf16*  xz     = (bf16*) (ws);               // 33,554,432
    bf16*  wxpb   = (bf16*) (ws + 33554432);    //    524,288
    float* ssm    = (float*)(ws + 34078720);    //    589,824
    float* sumdq  = (float*)(ws + 34668544);    //  1,048,576
    float* Q      = (float*)(ws + 35717120);    // 16,777,216
    float* smallf = (float*)(ws + 52494336);    //    196,608
    int*   flag   = (int*)  (ws + 52690944);    //         64
    bf16*  woutb  = (bf16*) (ws + 52691008);    //  4,194,304  end: 56,885,312
    bf16*  xcb    = (bf16*) (ws + 56885312);    // 16,777,216  end: 73,662,528
    float* ssmp   = (float*)(ws + 73662528);    //  9,437,184  end: 83,099,712
    // xb and winb ALIAS Q (dead before scan writes Q)
    bf16*  xb     = (bf16*) (ws + 35717120);
    bf16*  winb   = (bf16*) (ws + 35717120 + 8388608);
    const bool big  = ws_size >= 56885312;
    const bool big2 = ws_size >= 73662528;   // xc-fusion path (r10)
    const bool big3 = ws_size >= 83099712;   // atomic-free split-K (r14)

    // 0) dtype probe + flag init
    dtype_probe<<<1, 64, 0, stream>>>((const unsigned short*)d_in[7], flag);

    // 1) weight prep (+ zero ssm, + A-structure check -> flag[1])
    cvt_prep<<<(N_WXPB + N_SMALL + N_SSMZ)/256, 256, 0, stream>>>(
        d_in[4], d_in[2], d_in[3], d_in[5], d_in[6], d_in[7], d_in[8],
        wxpb, smallf, ssm, flag);

    // 2) xz = x @ W_in.T  (M=4096, N=4096, K=1024) — relaxed 8-phase (r13)
    if (big) {
        cvt_all<<<1310720/256, 256, 0, stream>>>(
            d_in[0], d_in[1], d_in[9], xb, winb, woutb, flag);
        gemm8r<<<dim3(16, 16), 512, 0, stream>>>(xb, winb, xz);
    } else {
        gemm_dual<<<dim3(32, 32), 256, 0, stream>>>(
            d_in[0], D_MODEL, d_in[1], D_MODEL, xz, 2*D_INNER, D_MODEL, flag, 1, 1, 0);
    }

    // 3) ssm += conv+silu(x_in) @ Wxp.T  (+ xcb spill; big3: atomic-free)
    xproj_fused<<<dim3(XSPLIT, 32), 256, 0, stream>>>(
        xz, wxpb, smallf, ssm,
        big2 ? xcb : (bf16*)nullptr,
        big3 ? ssmp : (float*)nullptr);
    if (big3) {
        ssm_reduce<<<(BLROWS*SSML + 255)/256, 256, 0, stream>>>(ssmp, ssm);
    }

    // 4) chunked selective scan (xc path when big2)
    {
        dim3 g(D_INNER/256, NCHUNK, BB);
        if (big2) {
            scan_partA_xc<CHUNK><<<g, 256, 0, stream>>>(ssm, xcb, smallf, sumdq, Q, flag);
            scan_combine<<<(BB*D_STATE*D_INNER)/256, 256, 0, stream>>>(sumdq, Q, smallf, NCHUNK);
            scan_partC_xc<CHUNK><<<g, 256, 0, stream>>>(ssm, xz, xcb, smallf, Q, flag);
        } else {
            scan_partA<CHUNK><<<g, 256, 0, stream>>>(ssm, xz, smallf, sumdq, Q, flag);
            scan_combine<<<(BB*D_STATE*D_INNER)/256, 256, 0, stream>>>(sumdq, Q, smallf, NCHUNK);
            scan_partC<CHUNK><<<g, 256, 0, stream>>>(ssm, xz, smallf, Q, flag);
        }
    }

    // 5) out = y @ W_out.T  (M=4096, N=1024, K=2048) — r6-verified gemm_n64
    if (big) {
        gemm_n64<<<dim3(D_MODEL/64, 32), 256, 0, stream>>>(
            xz + D_INNER, 2*D_INNER, woutb, D_INNER, d_out, D_MODEL, D_INNER, flag, 0, 1);
    } else {
        gemm_n64<<<dim3(D_MODEL/64, 32), 256, 0, stream>>>(
            xz + D_INNER, 2*D_INNER, d_in[9], D_INNER, d_out, D_MODEL, D_INNER, flag, 1, 1);
    }
}

// Round 15
// 267.044 us; speedup vs baseline: 1.0906x; 1.0036x over previous
//
#include <hip/hip_runtime.h>
#include <hip/hip_bf16.h>
#include <math.h>

// SelectiveSSM: D_MODEL=1024, D_STATE=16, D_CONV=4, EXPAND=2, B=2, L=2048
#define D_MODEL 1024
#define D_STATE 16
#define D_CONV  4
#define D_INNER 2048
#define BB      2
#define LL      2048
#define BLROWS  (BB*LL)       // 4096
#define NCHUNK  64
#define CHUNK   (LL/NCHUNK)   // 32
#define SSML    36            // padded ssm row stride (floats)
#define XSPLIT  16            // split-K factor for xproj

typedef __hip_bfloat16 bf16;
typedef __attribute__((ext_vector_type(8))) short short8;
typedef __attribute__((ext_vector_type(4))) float f32x4;

__device__ __forceinline__ float ldf(const void* p, long i, int isbf) {
    return isbf ? __bfloat162float(((const bf16*)p)[i]) : ((const float*)p)[i];
}
__device__ __forceinline__ short bfbits(float f) {
    bf16 h = __float2bfloat16(f);
    return *(short*)&h;
}
__device__ __forceinline__ float bits2f(short s) {
    bf16 h; *(short*)&h = s; return __bfloat162float(h);
}
__device__ __forceinline__ float bf2f(bf16 h) { return __bfloat162float(h); }
__device__ __forceinline__ float siluf(float x) {
    return __fdividef(x, 1.f + __expf(-x));
}
// fused stable softplus + exp-negation: delta = log(1+exp(x)), r = exp(-delta)
__device__ __forceinline__ void softplus_r(float x, float& delta, float& r) {
    float e = __expf(-fabsf(x));
    float t = 1.f + e;
    delta = fmaxf(x, 0.f) + __logf(t);
    r = __fdividef((x >= 0.f) ? e : 1.f, t);
}

// smallf float offsets
#define OFF_CW   0
#define OFF_CB   8192
#define OFF_WDT  10240
#define OFF_BDT  12288
#define OFF_AA   14336
#define OFF_D    47104
#define N_SMALL  49152
#define N_WXPB   (128*2048)
#define N_SSMZ   (BLROWS*SSML)

#define G_LDS16(gptr, lptr) __builtin_amdgcn_global_load_lds( \
    (const __attribute__((address_space(1))) void*)(gptr),    \
    (__attribute__((address_space(3))) void*)(lptr), 16, 0, 0)

// ---------------------------------------------------------------------------
// dtype probe + flag init. flag[0]=isbf, flag[1]=fastA.
// ---------------------------------------------------------------------------
__global__ void dtype_probe(const unsigned short* __restrict__ alog, int* __restrict__ flag) {
    if (threadIdx.x == 0) { flag[0] = (alog[1] != 0) ? 1 : 0; flag[1] = 1; }
}

// ---------------------------------------------------------------------------
// prep: padded bf16 W_xproj + fp32 smalls + zero ssm + A-structure check
// ---------------------------------------------------------------------------
__global__ __launch_bounds__(256) void cvt_prep(
    const void* __restrict__ Wxp, const void* __restrict__ cw,
    const void* __restrict__ cb, const void* __restrict__ wdt,
    const void* __restrict__ bdt, const void* __restrict__ alog,
    const void* __restrict__ Dp,
    bf16* __restrict__ wxpb, float* __restrict__ smallf,
    float* __restrict__ ssm, int* __restrict__ flag)
{
    const int isbf = flag[0];
    int idx = blockIdx.x * 256 + threadIdx.x;
    if (idx < N_WXPB) {
        int row = idx >> 11, col = idx & 2047;
        float v = (row < 33) ? ldf(Wxp, (long)row*2048 + col, isbf) : 0.f;
        wxpb[idx] = __float2bfloat16(v);
        return;
    }
    int j = idx - N_WXPB;
    if      (j < 8192)  smallf[OFF_CW  + j]         = ldf(cw,  j, isbf);
    else if (j < 10240) smallf[OFF_CB  + j - 8192]  = ldf(cb,  j - 8192, isbf);
    else if (j < 12288) smallf[OFF_WDT + j - 10240] = ldf(wdt, j - 10240, isbf);
    else if (j < 14336) smallf[OFF_BDT + j - 12288] = ldf(bdt, j - 12288, isbf);
    else if (j < 47104) {
        int jj = j - 14336;                 // = d*16 + s
        float aa = -__expf(ldf(alog, jj, isbf));
        smallf[OFF_AA + jj] = aa;
        int s = jj & 15;
        if (fabsf(aa + (float)(s+1)) > 1e-3f) flag[1] = 0;
    }
    else if (j < 49152) smallf[OFF_D   + j - 47104] = ldf(Dp,  j - 47104, isbf);
    else {
        int z = j - N_SMALL;
        if (z < N_SSMZ) ssm[z] = 0.f;
    }
}

// ---------------------------------------------------------------------------
// merged x/W_in/W_out -> bf16 conversion (8 elems/thread, one launch)
// ---------------------------------------------------------------------------
__global__ __launch_bounds__(256) void cvt_all(
    const void* __restrict__ x, const void* __restrict__ win,
    const void* __restrict__ wout,
    bf16* __restrict__ xb, bf16* __restrict__ winb, bf16* __restrict__ woutb,
    const int* __restrict__ flagp)
{
    const int isbf = *flagp;
    int i = blockIdx.x * 256 + threadIdx.x;
    const void* src; bf16* dst; long o;
    if (i < 524288)       { src = x;    dst = xb;    o = (long)i * 8; }
    else if (i < 1048576) { src = win;  dst = winb;  o = (long)(i - 524288) * 8; }
    else if (i < 1310720) { src = wout; dst = woutb; o = (long)(i - 1048576) * 8; }
    else return;
    short8 v;
    if (isbf) {
        v = *(const short8*)((const bf16*)src + o);
    } else {
        const float* s = (const float*)src + o;
        f32x4 u = *(const f32x4*)s, w = *(const f32x4*)(s + 4);
        v[0]=bfbits(u[0]); v[1]=bfbits(u[1]); v[2]=bfbits(u[2]); v[3]=bfbits(u[3]);
        v[4]=bfbits(w[0]); v[5]=bfbits(w[1]); v[6]=bfbits(w[2]); v[7]=bfbits(w[3]);
    }
    *(short8*)(dst + o) = v;
}

// ---------------------------------------------------------------------------
// gemm8r (r13-verified): snake 8-phase GEMM with relaxed scheduling.
// ---------------------------------------------------------------------------
__global__ __launch_bounds__(512) void gemm8r(
    const bf16* __restrict__ A,    // [4096][1024] row-major
    const bf16* __restrict__ Bm,   // [4096][1024] row-major
    bf16* __restrict__ Cp)         // [4096][4096]
{
    __shared__ bf16 As[2][2][128*64];
    __shared__ bf16 Bs[2][2][128*64];
    const int t    = threadIdx.x;          // 0..511
    const int lane = t & 63;
    const int w    = t >> 6;               // 0..7
    const int rm   = w >> 2;               // 0..1 row-sub within quadrant
    const int cn   = w & 3;                // 0..3 col-sub within quadrant
    const int bm   = blockIdx.y, bn = blockIdx.x;
    const int quad = lane >> 4, l16 = lane & 15;
    const int NT   = 16;                   // K=1024 / BK=64

    f32x4 acc[2][2][4][2];
    #pragma unroll
    for (int a = 0; a < 2; a++)
        #pragma unroll
        for (int b = 0; b < 2; b++)
            #pragma unroll
            for (int i = 0; i < 4; i++)
                #pragma unroll
                for (int j = 0; j < 2; j++)
                    acc[a][b][i][j] = f32x4{0.f, 0.f, 0.f, 0.f};

    auto stageA = [&](int bufi, int half, int kt) {
        #pragma unroll
        for (int seg = 0; seg < 2; seg++) {
            int s = seg*512 + t, row = s >> 3, sg = s & 7;
            int col = (sg ^ (row & 7)) * 8;
            G_LDS16(A + ((long)bm*256 + half*128 + row)*1024 + kt*64 + col,
                    &As[bufi][half][s*8]);
        }
    };
    auto stageB = [&](int bufi, int half, int kt) {
        #pragma unroll
        for (int seg = 0; seg < 2; seg++) {
            int s = seg*512 + t, row = s >> 3, sg = s & 7;
            int col = (sg ^ (row & 7)) * 8;
            G_LDS16(Bm + ((long)bn*256 + half*128 + row)*1024 + kt*64 + col,
                    &Bs[bufi][half][s*8]);
        }
    };

    stageA(0, 0, 0); stageB(0, 0, 0); stageA(0, 1, 0); stageB(0, 1, 0);
    stageA(1, 0, 1); stageB(1, 0, 1);
    asm volatile("s_waitcnt vmcnt(4)" ::: "memory");
    __builtin_amdgcn_s_barrier();

    short8 af[4][2], bfv[2][2];
    for (int kt = 0; kt < NT; ++kt) {
        const int buf = kt & 1;
        #pragma unroll
        for (int p = 0; p < 4; ++p) {
            // snake: (qm,qn) = (0,1),(0,0),(1,0),(1,1)
            const int qm = p >> 1;
            const int qn = (p == 0 || p == 3) ? 1 : 0;
            if (p == 0 || p == 2) {
                #pragma unroll
                for (int fi = 0; fi < 4; fi++)
                    #pragma unroll
                    for (int kk = 0; kk < 2; kk++) {
                        int ar = rm*64 + fi*16 + l16;
                        int c = kk*4 + quad;
                        af[fi][kk] = *(const short8*)&As[buf][qm][ar*64 + ((c ^ (ar & 7))*8)];
                    }
            }
            if (p != 2) {
                #pragma unroll
                for (int fj = 0; fj < 2; fj++)
                    #pragma unroll
                    for (int kk = 0; kk < 2; kk++) {
                        int br = cn*32 + fj*16 + l16;
                        int c = kk*4 + quad;
                        bfv[fj][kk] = *(const short8*)&Bs[buf][qn][br*64 + ((c ^ (br & 7))*8)];
                    }
            }
            if      (p == 0) { if (kt + 1 < NT) stageA(buf ^ 1, 1, kt + 1); }
            else if (p == 1) { if (kt + 1 < NT) stageB(buf ^ 1, 1, kt + 1); }
            else if (p == 2) { if (kt + 2 < NT) stageA(buf, 0, kt + 2); }
            else             { if (kt + 2 < NT) stageB(buf, 0, kt + 2); }
            __builtin_amdgcn_s_setprio(1);
            #pragma unroll
            for (int kk = 0; kk < 2; kk++)
                #pragma unroll
                for (int fi = 0; fi < 4; fi++)
                    #pragma unroll
                    for (int fj = 0; fj < 2; fj++)
                        acc[qm][qn][fi][fj] = __builtin_amdgcn_mfma_f32_16x16x32_bf16(
                            af[fi][kk], bfv[fj][kk], acc[qm][qn][fi][fj], 0, 0, 0);
            __builtin_amdgcn_s_setprio(0);
            if (p == 3) {
                if (kt == NT - 2)     { asm volatile("s_waitcnt vmcnt(0)" ::: "memory"); }
                else if (kt < NT - 2) { asm volatile("s_waitcnt vmcnt(4)" ::: "memory"); }
            }
            __builtin_amdgcn_s_barrier();
        }
    }

    #pragma unroll
    for (int qm = 0; qm < 2; qm++)
        #pragma unroll
        for (int qn = 0; qn < 2; qn++)
            #pragma unroll
            for (int fi = 0; fi < 4; fi++)
                #pragma unroll
                for (int fj = 0; fj < 2; fj++)
                    #pragma unroll
                    for (int r = 0; r < 4; r++) {
                        int row = bm*256 + qm*128 + rm*64 + fi*16 + quad*4 + r;
                        int col = bn*256 + qn*128 + cn*32 + fj*16 + l16;
                        Cp[(long)row * 4096 + col] = __float2bfloat16(acc[qm][qn][fi][fj][r]);
                    }
}

// ---------------------------------------------------------------------------
// GEMM fallback (small-ws path): 128x128 tile, BK=64, XOR-swizzled LDS
// ---------------------------------------------------------------------------
__global__ __launch_bounds__(256) void gemm_dual(
    const void* __restrict__ A, int lda,
    const void* __restrict__ Bm, int ldb,
    void* __restrict__ Cp, int ldc, int K,
    const int* __restrict__ flagp, int amode, int bmode, int cmode)
{
    const int isbf = *flagp;
    const int a_bf = amode ? isbf : 1;
    const int b_bf = bmode ? isbf : 1;
    const int c_bf = cmode ? isbf : 1;

    __shared__ bf16 As[128*64];
    __shared__ bf16 Bs[128*64];
    const int t    = threadIdx.x;
    const int lane = t & 63;
    const int w    = t >> 6;
    const int wm   = w >> 1, wn = w & 1;
    const int bm   = blockIdx.y, bn = blockIdx.x;
    const int quad = lane >> 4, l16 = lane & 15;

    f32x4 acc[4][4];
    #pragma unroll
    for (int i = 0; i < 4; i++)
        #pragma unroll
        for (int j = 0; j < 4; j++)
            acc[i][j] = f32x4{0.f, 0.f, 0.f, 0.f};

    for (int k0 = 0; k0 < K; k0 += 64) {
        __syncthreads();
        if (a_bf) {
            #pragma unroll
            for (int seg = 0; seg < 4; seg++) {
                int s = seg*256 + t, row = s >> 3, sg = s & 7;
                int col = (sg ^ (row & 7)) * 8;
                const bf16* ga = (const bf16*)A + ((long)bm*128 + row)*(long)lda + k0 + col;
                G_LDS16(ga, &As[row*64 + sg*8]);
            }
        } else {
            #pragma unroll
            for (int seg = 0; seg < 4; seg++) {
                int s = seg*256 + t, row = s >> 3, sg = s & 7;
                int col = (sg ^ (row & 7)) * 8;
                const float* ap = (const float*)A + ((long)bm*128 + row)*(long)lda + k0 + col;
                f32x4 u = *(const f32x4*)ap, v = *(const f32x4*)(ap + 4);
                short8 va;
                va[0]=bfbits(u[0]); va[1]=bfbits(u[1]); va[2]=bfbits(u[2]); va[3]=bfbits(u[3]);
                va[4]=bfbits(v[0]); va[5]=bfbits(v[1]); va[6]=bfbits(v[2]); va[7]=bfbits(v[3]);
                *(short8*)&As[row*64 + sg*8] = va;
            }
        }
        if (b_bf) {
            #pragma unroll
            for (int seg = 0; seg < 4; seg++) {
                int s = seg*256 + t, row = s >> 3, sg = s & 7;
                int col = (sg ^ (row & 7)) * 8;
                const bf16* gb = (const bf16*)Bm + ((long)bn*128 + row)*(long)ldb + k0 + col;
                G_LDS16(gb, &Bs[row*64 + sg*8]);
            }
        } else {
            #pragma unroll
            for (int seg = 0; seg < 4; seg++) {
                int s = seg*256 + t, row = s >> 3, sg = s & 7;
                int col = (sg ^ (row & 7)) * 8;
                const float* bp = (const float*)Bm + ((long)bn*128 + row)*(long)ldb + k0 + col;
                f32x4 u = *(const f32x4*)bp, v = *(const f32x4*)(bp + 4);
                short8 vb;
                vb[0]=bfbits(u[0]); vb[1]=bfbits(u[1]); vb[2]=bfbits(u[2]); vb[3]=bfbits(u[3]);
                vb[4]=bfbits(v[0]); vb[5]=bfbits(v[1]); vb[6]=bfbits(v[2]); vb[7]=bfbits(v[3]);
                *(short8*)&Bs[row*64 + sg*8] = vb;
            }
        }
        __syncthreads();

        #pragma unroll
        for (int kk = 0; kk < 64; kk += 32) {
            const int cbase = kk >> 3;
            short8 af[4], bfr[4];
            #pragma unroll
            for (int mi = 0; mi < 4; mi++) {
                int row = wm*64 + mi*16 + l16;
                int c = cbase + quad;
                af[mi] = *(const short8*)&As[row*64 + ((c ^ (row & 7))*8)];
            }
            #pragma unroll
            for (int ni = 0; ni < 4; ni++) {
                int row = wn*64 + ni*16 + l16;
                int c = cbase + quad;
                bfr[ni] = *(const short8*)&Bs[row*64 + ((c ^ (row & 7))*8)];
            }
            #pragma unroll
            for (int mi = 0; mi < 4; mi++)
                #pragma unroll
                for (int ni = 0; ni < 4; ni++)
                    acc[mi][ni] = __builtin_amdgcn_mfma_f32_16x16x32_bf16(
                        af[mi], bfr[ni], acc[mi][ni], 0, 0, 0);
        }
    }

    #pragma unroll
    for (int mi = 0; mi < 4; mi++)
        #pragma unroll
        for (int ni = 0; ni < 4; ni++)
            #pragma unroll
            for (int r = 0; r < 4; r++) {
                int row = bm*128 + wm*64 + mi*16 + quad*4 + r;
                int col = bn*128 + wn*64 + ni*16 + l16;
                float val = acc[mi][ni][r];
                if (c_bf) ((bf16*)Cp)[(long)row * ldc + col] = __float2bfloat16(val);
                else      ((float*)Cp)[(long)row * ldc + col] = val;
            }
}

// ---------------------------------------------------------------------------
// gemm_n64r (r15): dbuf counted-vmcnt version of gemm_n64 (big path only).
// 128x64 tile, BK=64, 256 thr, LDS 48KB -> 3 blocks/CU, grid (16,32)=512.
// Per K-step: reads -> MFMA (compiler auto-lgkm = read-completion proof)
// -> barrier -> stage(buf, t+2) -> vmcnt(6) -> barrier. Replaces the old
// full-drain __syncthreads 2-phase (catalog min-2-phase recipe; no lgkm
// pins per r13's m141 lesson). vmcnt trace: prologue 12 -> vmcnt(6)
// retires tile0; steady state retires t+1's 6, t+2's 6 stay in flight;
// kt=NT-2 drains with vmcnt(0).
// ---------------------------------------------------------------------------
__global__ __launch_bounds__(256) void gemm_n64r(
    const bf16* __restrict__ A, int lda,
    const bf16* __restrict__ Bm, int ldb,
    void* __restrict__ Cp, int ldc, int K,
    const int* __restrict__ flagp, int cmode)
{
    const int c_bf = cmode ? *flagp : 1;
    __shared__ bf16 As[2][128*64];
    __shared__ bf16 Bs[2][64*64];
    const int t    = threadIdx.x;
    const int lane = t & 63;
    const int w    = t >> 6;
    const int wm   = w >> 1, wn = w & 1;
    const int bm   = blockIdx.y, bn = blockIdx.x;
    const int quad = lane >> 4, l16 = lane & 15;
    const int NT   = K >> 6;   // 32

    f32x4 acc[4][2];
    #pragma unroll
    for (int i = 0; i < 4; i++)
        #pragma unroll
        for (int j = 0; j < 2; j++)
            acc[i][j] = f32x4{0.f, 0.f, 0.f, 0.f};

    auto stage = [&](int bufi, int kt) {
        #pragma unroll
        for (int seg = 0; seg < 4; seg++) {
            int s = seg*256 + t, row = s >> 3, sg = s & 7;
            int col = (sg ^ (row & 7)) * 8;
            G_LDS16(A + ((long)bm*128 + row)*(long)lda + kt*64 + col,
                    &As[bufi][row*64 + sg*8]);
        }
        #pragma unroll
        for (int seg = 0; seg < 2; seg++) {
            int s = seg*256 + t, row = s >> 3, sg = s & 7;
            int col = (sg ^ (row & 7)) * 8;
            G_LDS16(Bm + ((long)bn*64 + row)*(long)ldb + kt*64 + col,
                    &Bs[bufi][row*64 + sg*8]);
        }
    };

    stage(0, 0);
    stage(1, 1);
    asm volatile("s_waitcnt vmcnt(6)" ::: "memory");
    __builtin_amdgcn_s_barrier();

    for (int t0 = 0; t0 < NT; ++t0) {
        const int buf = t0 & 1;
        short8 af[2][4], bfr[2][2];
        #pragma unroll
        for (int kk = 0; kk < 2; kk++) {
            #pragma unroll
            for (int mi = 0; mi < 4; mi++) {
                int row = wm*64 + mi*16 + l16;
                int c = kk*4 + quad;
                af[kk][mi] = *(const short8*)&As[buf][row*64 + ((c ^ (row & 7))*8)];
            }
            #pragma unroll
            for (int ni = 0; ni < 2; ni++) {
                int row = wn*32 + ni*16 + l16;
                int c = kk*4 + quad;
                bfr[kk][ni] = *(const short8*)&Bs[buf][row*64 + ((c ^ (row & 7))*8)];
            }
        }
        __builtin_amdgcn_s_setprio(1);
        #pragma unroll
        for (int kk = 0; kk < 2; kk++)
            #pragma unroll
            for (int mi = 0; mi < 4; mi++)
                #pragma unroll
                for (int ni = 0; ni < 2; ni++)
                    acc[mi][ni] = __builtin_amdgcn_mfma_f32_16x16x32_bf16(
                        af[kk][mi], bfr[kk][ni], acc[mi][ni], 0, 0, 0);
        __builtin_amdgcn_s_setprio(0);
        __builtin_amdgcn_s_barrier();          // all waves consumed reads of buf
        if (t0 + 2 < NT) {
            stage(buf, t0 + 2);
            asm volatile("s_waitcnt vmcnt(6)" ::: "memory");   // retire t0+1's 6
        } else if (t0 + 1 < NT) {
            asm volatile("s_waitcnt vmcnt(0)" ::: "memory");   // drain t0+1
        }
        __builtin_amdgcn_s_barrier();          // buf^1 (t0+1) landed for all
    }

    #pragma unroll
    for (int mi = 0; mi < 4; mi++)
        #pragma unroll
        for (int ni = 0; ni < 2; ni++)
            #pragma unroll
            for (int r = 0; r < 4; r++) {
                int row = bm*128 + wm*64 + mi*16 + quad*4 + r;
                int col = bn*64 + wn*32 + ni*16 + l16;
                float val = acc[mi][ni][r];
                if (c_bf) ((bf16*)Cp)[(long)row * ldc + col] = __float2bfloat16(val);
                else      ((float*)Cp)[(long)row * ldc + col] = val;
            }
}

// ---------------------------------------------------------------------------
// GEMM2 fallback (small-ws path): 128x64 tile, BK=64, XOR swizzle.
// ---------------------------------------------------------------------------
__global__ __launch_bounds__(256) void gemm_n64(
    const bf16* __restrict__ A, int lda,
    const void* __restrict__ Bm, int ldb,
    void* __restrict__ Cp, int ldc, int K,
    const int* __restrict__ flagp, int bmode, int cmode)
{
    const int isbf = *flagp;
    const int b_bf = bmode ? isbf : 1;
    const int c_bf = cmode ? isbf : 1;

    __shared__ bf16 As[128*64];
    __shared__ bf16 Bs[64*64];
    const int t    = threadIdx.x;
    const int lane = t & 63;
    const int w    = t >> 6;
    const int wm   = w >> 1, wn = w & 1;
    const int bm   = blockIdx.y, bn = blockIdx.x;
    const int quad = lane >> 4, l16 = lane & 15;

    f32x4 acc[4][2];
    #pragma unroll
    for (int i = 0; i < 4; i++)
        #pragma unroll
        for (int j = 0; j < 2; j++)
            acc[i][j] = f32x4{0.f, 0.f, 0.f, 0.f};

    for (int k0 = 0; k0 < K; k0 += 64) {
        __syncthreads();
        #pragma unroll
        for (int seg = 0; seg < 4; seg++) {
            int s = seg*256 + t, row = s >> 3, sg = s & 7;
            int col = (sg ^ (row & 7)) * 8;
            const bf16* ga = A + ((long)bm*128 + row)*(long)lda + k0 + col;
            G_LDS16(ga, &As[row*64 + sg*8]);
        }
        if (b_bf) {
            #pragma unroll
            for (int seg = 0; seg < 2; seg++) {
                int s = seg*256 + t, row = s >> 3, sg = s & 7;
                int col = (sg ^ (row & 7)) * 8;
                const bf16* gb = (const bf16*)Bm + ((long)bn*64 + row)*(long)ldb + k0 + col;
                G_LDS16(gb, &Bs[row*64 + sg*8]);
            }
        } else {
            #pragma unroll
            for (int seg = 0; seg < 2; seg++) {
                int s = seg*256 + t, row = s >> 3, sg = s & 7;
                int col = (sg ^ (row & 7)) * 8;
                const float* bp = (const float*)Bm + ((long)bn*64 + row)*(long)ldb + k0 + col;
                f32x4 u = *(const f32x4*)bp, v = *(const f32x4*)(bp + 4);
                short8 vb;
                vb[0]=bfbits(u[0]); vb[1]=bfbits(u[1]); vb[2]=bfbits(u[2]); vb[3]=bfbits(u[3]);
                vb[4]=bfbits(v[0]); vb[5]=bfbits(v[1]); vb[6]=bfbits(v[2]); vb[7]=bfbits(v[3]);
                *(short8*)&Bs[row*64 + sg*8] = vb;
            }
        }
        __syncthreads();

        #pragma unroll
        for (int kk = 0; kk < 64; kk += 32) {
            const int cbase = kk >> 3;
            short8 af[4], bfr[2];
            #pragma unroll
            for (int mi = 0; mi < 4; mi++) {
                int row = wm*64 + mi*16 + l16;
                int c = cbase + quad;
                af[mi] = *(const short8*)&As[row*64 + ((c ^ (row & 7))*8)];
            }
            #pragma unroll
            for (int ni = 0; ni < 2; ni++) {
                int row = wn*32 + ni*16 + l16;
                int c = cbase + quad;
                bfr[ni] = *(const short8*)&Bs[row*64 + ((c ^ (row & 7))*8)];
            }
            #pragma unroll
            for (int mi = 0; mi < 4; mi++)
                #pragma unroll
                for (int ni = 0; ni < 2; ni++)
                    acc[mi][ni] = __builtin_amdgcn_mfma_f32_16x16x32_bf16(
                        af[mi], bfr[ni], acc[mi][ni], 0, 0, 0);
        }
    }

    #pragma unroll
    for (int mi = 0; mi < 4; mi++)
        #pragma unroll
        for (int ni = 0; ni < 2; ni++)
            #pragma unroll
            for (int r = 0; r < 4; r++) {
                int row = bm*128 + wm*64 + mi*16 + quad*4 + r;
                int col = bn*64 + wn*32 + ni*16 + l16;
                float val = acc[mi][ni][r];
                if (c_bf) ((bf16*)Cp)[(long)row * ldc + col] = __float2bfloat16(val);
                else      ((float*)Cp)[(long)row * ldc + col] = val;
            }
}

// ---------------------------------------------------------------------------
// xproj fused, split-K (r14-verified): slab stores + ssm_reduce when ssmp.
// ---------------------------------------------------------------------------
__global__ __launch_bounds__(256) void xproj_fused(
    const bf16* __restrict__ xz, const bf16* __restrict__ wxpb,
    const float* __restrict__ smallf, float* __restrict__ ssm,
    bf16* __restrict__ xcb, float* __restrict__ ssmp)
{
    const float* cwf = smallf + OFF_CW;
    const float* cbf = smallf + OFF_CB;
    __shared__ bf16 As[128*32];
    __shared__ bf16 Bs[128*32];
    const int t    = threadIdx.x;
    const int lane = t & 63;
    const int w    = t >> 6;
    const int wm   = w >> 1, wn = w & 1;
    const int bm   = blockIdx.y;
    const int ks   = blockIdx.x * (D_INNER / XSPLIT);
    const int quad = lane >> 4, l16 = lane & 15;

    f32x4 acc[4][4];
    #pragma unroll
    for (int i = 0; i < 4; i++)
        #pragma unroll
        for (int j = 0; j < 4; j++)
            acc[i][j] = f32x4{0.f, 0.f, 0.f, 0.f};

    for (int k0 = ks; k0 < ks + D_INNER/XSPLIT; k0 += 32) {
        __syncthreads();
        #pragma unroll
        for (int seg = 0; seg < 2; seg++) {
            int s = seg*256 + t, row = s >> 2, dcol = (s & 3) * 8;
            int blg = bm*128 + row;
            int b = blg >> 11, l = blg & (LL - 1);
            int d0 = k0 + dcol;
            float a[8];
            {
                f32x4 c0 = *(const f32x4*)&cbf[d0], c1 = *(const f32x4*)&cbf[d0+4];
                a[0]=c0[0]; a[1]=c0[1]; a[2]=c0[2]; a[3]=c0[3];
                a[4]=c1[0]; a[5]=c1[1]; a[6]=c1[2]; a[7]=c1[3];
            }
            f32x4 cw4[8];
            #pragma unroll
            for (int j = 0; j < 8; j++) cw4[j] = *(const f32x4*)&cwf[(d0+j)*4];
            #pragma unroll
            for (int kk = 0; kk < D_CONV; kk++) {
                int ls = l - 3 + kk;
                if (ls >= 0) {
                    short8 xv = *(const short8*)&xz[((long)(b*LL + ls))*4096 + d0];
                    #pragma unroll
                    for (int j = 0; j < 8; j++) a[j] += bits2f(xv[j]) * cw4[j][kk];
                }
            }
            short8 va;
            #pragma unroll
            for (int j = 0; j < 8; j++) va[j] = bfbits(siluf(a[j]));
            *(short8*)&As[row*32 + dcol] = va;
            if (xcb) *(short8*)&xcb[(long)blg*D_INNER + d0] = va;
        }
        #pragma unroll
        for (int seg = 0; seg < 2; seg++) {
            int s = seg*256 + t, row = s >> 2, col = (s & 3) * 8;
            const bf16* gb = wxpb + (long)row*D_INNER + k0 + col;
            G_LDS16(gb, &Bs[row*32 + col]);
        }
        __syncthreads();

        short8 af[4], bfr[4];
        #pragma unroll
        for (int mi = 0; mi < 4; mi++)
            af[mi] = *(const short8*)&As[(wm*64 + mi*16 + l16)*32 + quad*8];
        #pragma unroll
        for (int ni = 0; ni < 4; ni++)
            bfr[ni] = *(const short8*)&Bs[(wn*64 + ni*16 + l16)*32 + quad*8];
        #pragma unroll
        for (int mi = 0; mi < 4; mi++)
            #pragma unroll
            for (int ni = 0; ni < 4; ni++)
                acc[mi][ni] = __builtin_amdgcn_mfma_f32_16x16x32_bf16(
                    af[mi], bfr[ni], acc[mi][ni], 0, 0, 0);
    }

    if (ssmp) {
        float* dst = ssmp + (long)blockIdx.x * BLROWS * SSML;
        #pragma unroll
        for (int mi = 0; mi < 4; mi++)
            #pragma unroll
            for (int ni = 0; ni < 4; ni++) {
                int col = wn*64 + ni*16 + l16;
                if (col < 33) {
                    int newcol = (col == 0) ? 32 : (col - 1);
                    #pragma unroll
                    for (int r = 0; r < 4; r++) {
                        int row = bm*128 + wm*64 + mi*16 + quad*4 + r;
                        dst[(long)row * SSML + newcol] = acc[mi][ni][r];
                    }
                }
            }
    } else {
        #pragma unroll
        for (int mi = 0; mi < 4; mi++)
            #pragma unroll
            for (int ni = 0; ni < 4; ni++) {
                int col = wn*64 + ni*16 + l16;
                if (col < 33) {
                    int newcol = (col == 0) ? 32 : (col - 1);
                    #pragma unroll
                    for (int r = 0; r < 4; r++) {
                        int row = bm*128 + wm*64 + mi*16 + quad*4 + r;
                        atomicAdd(&ssm[(long)row * SSML + newcol], acc[mi][ni][r]);
                    }
                }
            }
    }
}

// ---------------------------------------------------------------------------
// ssm_reduce (r14-verified): ssm[idx] = sum over XSPLIT slabs of ssmp.
// ---------------------------------------------------------------------------
__global__ __launch_bounds__(256) void ssm_reduce(
    const float* __restrict__ ssmp, float* __restrict__ ssm)
{
    int idx = blockIdx.x * 256 + threadIdx.x;     // 0 .. BLROWS*SSML-1
    if (idx >= BLROWS * SSML) return;
    int col = idx % SSML;
    float s = 0.f;
    if (col < 33) {
        #pragma unroll
        for (int p = 0; p < XSPLIT; p++)
            s += ssmp[(long)p * BLROWS * SSML + idx];
    }
    ssm[idx] = s;
}

// ---------------------------------------------------------------------------
// Scan phase A (fallback): packed-f32 h, LDS x-prefetch + conv.
// ---------------------------------------------------------------------------
template<int CHUNK_T>
__global__ __launch_bounds__(256) void scan_partA(
    const float* __restrict__ ssm, const bf16* __restrict__ xz,
    const float* __restrict__ smallf,
    float* __restrict__ sumdq, float* __restrict__ Q,
    const int* __restrict__ flag)
{
    __shared__ float sL[CHUNK_T*SSML];
    __shared__ bf16  sX[CHUNK_T*256];
    const int fastA = flag[1];
    int d = blockIdx.x * 256 + threadIdx.x;
    int c = blockIdx.y, b = blockIdx.z;
    const int NC = gridDim.y;
    int l0 = c * CHUNK_T;
    {
        const float* src = ssm + (long)(b*LL + l0) * SSML;
        for (int idx = threadIdx.x; idx < CHUNK_T*SSML; idx += 256) sL[idx] = src[idx];
        const bf16* xsrc = xz + (long)(b*LL + l0)*4096 + blockIdx.x*256;
        for (int j = threadIdx.x; j < CHUNK_T*32; j += 256) {
            int li = j >> 5, ln = j & 31;
            *(short8*)&sX[li*256 + ln*8] = *(const short8*)&xsrc[(long)li*4096 + ln*8];
        }
    }
    f32x4 h4[4];
    #pragma unroll
    for (int g = 0; g < 4; g++) h4[g] = f32x4{0.f, 0.f, 0.f, 0.f};
    float Aa[D_STATE];
    if (!fastA) {
        #pragma unroll
        for (int s = 0; s < D_STATE; s++) Aa[s] = smallf[OFF_AA + d*D_STATE + s];
    }
    f32x4 cw4 = *(const f32x4*)&smallf[OFF_CW + d*4];
    float cbv  = smallf[OFF_CB + d];
    float wdt  = smallf[OFF_WDT + d];
    float bdtv = smallf[OFF_BDT + d];
    float win[3];
    #pragma unroll
    for (int k = 0; k < 3; k++) {
        int ls = l0 - 3 + k;
        win[k] = (ls >= 0) ? bf2f(xz[((long)(b*LL + ls))*4096 + d]) : 0.f;
    }
    __syncthreads();
    float sumd = 0.f;
    #pragma unroll 4
    for (int li = 0; li < CHUNK_T; li++) {
        float xnew = bf2f(sX[li*256 + threadIdx.x]);
        float convv = cbv + win[0]*cw4[0] + win[1]*cw4[1] + win[2]*cw4[2] + xnew*cw4[3];
        win[0] = win[1]; win[1] = win[2]; win[2] = xnew;
        float xc = siluf(convv);
        const float* row = &sL[li*SSML];
        f32x4 Bv[4];
        #pragma unroll
        for (int g = 0; g < 4; g++) Bv[g] = *(const f32x4*)(row + g*4);
        float delta, r;
        softplus_r(row[32]*wdt + bdtv, delta, r);
        sumd += delta;
        float du = delta * xc;
        if (fastA) {
            float r2 = r*r, r3 = r2*r, r4 = r2*r2;
            f32x4 p0; p0[0]=r; p0[1]=r2; p0[2]=r3; p0[3]=r4;
            float s8 = r4*r4, s12 = s8*r4;
            h4[0] = p0*h4[0]       + du*Bv[0];
            h4[1] = (p0*r4)*h4[1]  + du*Bv[1];
            h4[2] = (p0*s8)*h4[2]  + du*Bv[2];
            h4[3] = (p0*s12)*h4[3] + du*Bv[3];
        } else {
            #pragma unroll
            for (int g = 0; g < 4; g++)
                #pragma unroll
                for (int j = 0; j < 4; j++) {
                    int s = g*4 + j;
                    h4[g][j] = __expf(delta*Aa[s])*h4[g][j] + du*Bv[g][j];
                }
        }
    }
    sumdq[(long)(b*NC + c)*D_INNER + d] = sumd;
    long o = ((long)(b*NC + c)*D_STATE)*D_INNER + d;
    #pragma unroll
    for (int s = 0; s < D_STATE; s++)
        Q[o + (long)s*D_INNER] = h4[s >> 2][s & 3];
}

// ---------------------------------------------------------------------------
// Scan phase A, xc path (r10-verified): xc pre-computed by xproj (xcb).
// ---------------------------------------------------------------------------
template<int CHUNK_T>
__global__ __launch_bounds__(256) void scan_partA_xc(
    const float* __restrict__ ssm, const bf16* __restrict__ xcb,
    const float* __restrict__ smallf,
    float* __restrict__ sumdq, float* __restrict__ Q,
    const int* __restrict__ flag)
{
    __shared__ float sL[CHUNK_T*SSML];
    __shared__ bf16  sX[CHUNK_T*256];
    const int fastA = flag[1];
    int d = blockIdx.x * 256 + threadIdx.x;
    int c = blockIdx.y, b = blockIdx.z;
    const int NC = gridDim.y;
    int l0 = c * CHUNK_T;
    {
        const float* src = ssm + (long)(b*LL + l0) * SSML;
        for (int idx = threadIdx.x; idx < CHUNK_T*SSML; idx += 256) sL[idx] = src[idx];
        const bf16* xsrc = xcb + (long)(b*LL + l0)*D_INNER + blockIdx.x*256;
        for (int j = threadIdx.x; j < CHUNK_T*32; j += 256) {
            int li = j >> 5, ln = j & 31;
            *(short8*)&sX[li*256 + ln*8] = *(const short8*)&xsrc[(long)li*D_INNER + ln*8];
        }
    }
    f32x4 h4[4];
    #pragma unroll
    for (int g = 0; g < 4; g++) h4[g] = f32x4{0.f, 0.f, 0.f, 0.f};
    float Aa[D_STATE];
    if (!fastA) {
        #pragma unroll
        for (int s = 0; s < D_STATE; s++) Aa[s] = smallf[OFF_AA + d*D_STATE + s];
    }
    float wdt  = smallf[OFF_WDT + d];
    float bdtv = smallf[OFF_BDT + d];
    __syncthreads();
    float sumd = 0.f;
    #pragma unroll 4
    for (int li = 0; li < CHUNK_T; li++) {
        float xc = bf2f(sX[li*256 + threadIdx.x]);
        const float* row = &sL[li*SSML];
        f32x4 Bv[4];
        #pragma unroll
        for (int g = 0; g < 4; g++) Bv[g] = *(const f32x4*)(row + g*4);
        float delta, r;
        softplus_r(row[32]*wdt + bdtv, delta, r);
        sumd += delta;
        float du = delta * xc;
        if (fastA) {
            float r2 = r*r, r3 = r2*r, r4 = r2*r2;
            f32x4 p0; p0[0]=r; p0[1]=r2; p0[2]=r3; p0[3]=r4;
            float s8 = r4*r4, s12 = s8*r4;
            h4[0] = p0*h4[0]       + du*Bv[0];
            h4[1] = (p0*r4)*h4[1]  + du*Bv[1];
            h4[2] = (p0*s8)*h4[2]  + du*Bv[2];
            h4[3] = (p0*s12)*h4[3] + du*Bv[3];
        } else {
            #pragma unroll
            for (int g = 0; g < 4; g++)
                #pragma unroll
                for (int j = 0; j < 4; j++) {
                    int s = g*4 + j;
                    h4[g][j] = __expf(delta*Aa[s])*h4[g][j] + du*Bv[g][j];
                }
        }
    }
    sumdq[(long)(b*NC + c)*D_INNER + d] = sumd;
    long o = ((long)(b*NC + c)*D_STATE)*D_INNER + d;
    #pragma unroll
    for (int s = 0; s < D_STATE; s++)
        Q[o + (long)s*D_INNER] = h4[s >> 2][s & 3];
}

// ---------------------------------------------------------------------------
// Scan phase B: combine chunks per (b,d,s); P recomputed from sumd.
// ---------------------------------------------------------------------------
__global__ __launch_bounds__(256) void scan_combine(
    const float* __restrict__ sumdq, float* __restrict__ Q_hst,
    const float* __restrict__ smallf, int NC)
{
    int t = blockIdx.x * 256 + threadIdx.x;   // (b,s,d): d fastest
    int d = t & (D_INNER - 1);
    int s = (t >> 11) & (D_STATE - 1);
    int b = t >> 15;
    float Aa = smallf[OFF_AA + d*D_STATE + s];
    float h = 0.f;
    #pragma unroll 4
    for (int c = 0; c < NC; c++) {
        float sd = sumdq[(long)(b*NC + c)*D_INNER + d];
        long idx = ((long)(b*NC + c)*D_STATE + s)*D_INNER + d;
        float q = Q_hst[idx];
        Q_hst[idx] = h;
        h = __expf(Aa*sd)*h + q;
    }
}

// ---------------------------------------------------------------------------
// Scan phase C (fallback): packed-f32; x AND z prefetched.
// ---------------------------------------------------------------------------
template<int CHUNK_T>
__global__ __launch_bounds__(256) void scan_partC(
    const float* __restrict__ ssm, bf16* __restrict__ xz,
    const float* __restrict__ smallf, const float* __restrict__ hst,
    const int* __restrict__ flag)
{
    __shared__ float sL[CHUNK_T*SSML];
    __shared__ bf16  sX[CHUNK_T*256];
    __shared__ bf16  sZ[CHUNK_T*256];
    const int fastA = flag[1];
    int d = blockIdx.x * 256 + threadIdx.x;
    int c = blockIdx.y, b = blockIdx.z;
    const int NC = gridDim.y;
    int l0 = c * CHUNK_T;
    {
        const float* src = ssm + (long)(b*LL + l0) * SSML;
        for (int idx = threadIdx.x; idx < CHUNK_T*SSML; idx += 256) sL[idx] = src[idx];
        const bf16* xsrc = xz + (long)(b*LL + l0)*4096 + blockIdx.x*256;
        for (int j = threadIdx.x; j < CHUNK_T*32; j += 256) {
            int li = j >> 5, ln = j & 31;
            *(short8*)&sX[li*256 + ln*8] = *(const short8*)&xsrc[(long)li*4096 + ln*8];
            *(short8*)&sZ[li*256 + ln*8] = *(const short8*)&xsrc[(long)li*4096 + D_INNER + ln*8];
        }
    }
    f32x4 h4[4];
    long o = ((long)(b*NC + c)*D_STATE)*D_INNER + d;
    #pragma unroll
    for (int s = 0; s < D_STATE; s++) h4[s >> 2][s & 3] = hst[o + (long)s*D_INNER];
    float Aa[D_STATE];
    if (!fastA) {
        #pragma unroll
        for (int s = 0; s < D_STATE; s++) Aa[s] = smallf[OFF_AA + d*D_STATE + s];
    }
    f32x4 cw4 = *(const f32x4*)&smallf[OFF_CW + d*4];
    float cbv  = smallf[OFF_CB + d];
    float wdt  = smallf[OFF_WDT + d];
    float bdtv = smallf[OFF_BDT + d];
    float Dv   = smallf[OFF_D + d];
    float win[3];
    #pragma unroll
    for (int k = 0; k < 3; k++) {
        int ls = l0 - 3 + k;
        win[k] = (ls >= 0) ? bf2f(xz[((long)(b*LL + ls))*4096 + d]) : 0.f;
    }
    __syncthreads();
    #pragma unroll 2
    for (int li = 0; li < CHUNK_T; li++) {
        long bl = (long)(b*LL + l0 + li);
        float xnew = bf2f(sX[li*256 + threadIdx.x]);
        float convv = cbv + win[0]*cw4[0] + win[1]*cw4[1] + win[2]*cw4[2] + xnew*cw4[3];
        win[0] = win[1]; win[1] = win[2]; win[2] = xnew;
        float xc = siluf(convv);
        const float* row = &sL[li*SSML];
        f32x4 Bv[4], Cv[4];
        #pragma unroll
        for (int g = 0; g < 4; g++) {
            Bv[g] = *(const f32x4*)(row + g*4);
            Cv[g] = *(const f32x4*)(row + 16 + g*4);
        }
        float delta, r;
        softplus_r(row[32]*wdt + bdtv, delta, r);
        float du = delta * xc;
        f32x4 yacc = f32x4{0.f, 0.f, 0.f, 0.f};
        if (fastA) {
            float r2 = r*r, r3 = r2*r, r4 = r2*r2;
            f32x4 p0; p0[0]=r; p0[1]=r2; p0[2]=r3; p0[3]=r4;
            float s8 = r4*r4, s12 = s8*r4;
            h4[0] = p0*h4[0]       + du*Bv[0];
            h4[1] = (p0*r4)*h4[1]  + du*Bv[1];
            h4[2] = (p0*s8)*h4[2]  + du*Bv[2];
            h4[3] = (p0*s12)*h4[3] + du*Bv[3];
            yacc = yacc + h4[0]*Cv[0];
            yacc = yacc + h4[1]*Cv[1];
            yacc = yacc + h4[2]*Cv[2];
            yacc = yacc + h4[3]*Cv[3];
        } else {
            #pragma unroll
            for (int g = 0; g < 4; g++)
                #pragma unroll
                for (int j = 0; j < 4; j++) {
                    int s = g*4 + j;
                    h4[g][j] = __expf(delta*Aa[s])*h4[g][j] + du*Bv[g][j];
                    yacc[j] += h4[g][j]*Cv[g][j];
                }
        }
        float yv = (yacc[0] + yacc[1]) + (yacc[2] + yacc[3]);
        yv += xc * Dv;
        float z = bf2f(sZ[li*256 + threadIdx.x]);
        yv *= siluf(z);
        xz[bl*4096 + D_INNER + d] = __float2bfloat16(yv);
    }
}

// ---------------------------------------------------------------------------
// Scan phase C, xc path (r10-verified): xc from xcb — no conv window.
// ---------------------------------------------------------------------------
template<int CHUNK_T>
__global__ __launch_bounds__(256) void scan_partC_xc(
    const float* __restrict__ ssm, bf16* __restrict__ xz,
    const bf16* __restrict__ xcb,
    const float* __restrict__ smallf, const float* __restrict__ hst,
    const int* __restrict__ flag)
{
    __shared__ float sL[CHUNK_T*SSML];
    __shared__ bf16  sX[CHUNK_T*256];
    __shared__ bf16  sZ[CHUNK_T*256];
    const int fastA = flag[1];
    int d = blockIdx.x * 256 + threadIdx.x;
    int c = blockIdx.y, b = blockIdx.z;
    const int NC = gridDim.y;
    int l0 = c * CHUNK_T;
    {
        const float* src = ssm + (long)(b*LL + l0) * SSML;
        for (int idx = threadIdx.x; idx < CHUNK_T*SSML; idx += 256) sL[idx] = src[idx];
        const bf16* xcs = xcb + (long)(b*LL + l0)*D_INNER + blockIdx.x*256;
        const bf16* zs  = xz  + (long)(b*LL + l0)*4096 + D_INNER + blockIdx.x*256;
        for (int j = threadIdx.x; j < CHUNK_T*32; j += 256) {
            int li = j >> 5, ln = j & 31;
            *(short8*)&sX[li*256 + ln*8] = *(const short8*)&xcs[(long)li*D_INNER + ln*8];
            *(short8*)&sZ[li*256 + ln*8] = *(const short8*)&zs[(long)li*4096 + ln*8];
        }
    }
    f32x4 h4[4];
    long o = ((long)(b*NC + c)*D_STATE)*D_INNER + d;
    #pragma unroll
    for (int s = 0; s < D_STATE; s++) h4[s >> 2][s & 3] = hst[o + (long)s*D_INNER];
    float Aa[D_STATE];
    if (!fastA) {
        #pragma unroll
        for (int s = 0; s < D_STATE; s++) Aa[s] = smallf[OFF_AA + d*D_STATE + s];
    }
    float wdt  = smallf[OFF_WDT + d];
    float bdtv = smallf[OFF_BDT + d];
    float Dv   = smallf[OFF_D + d];
    __syncthreads();
    #pragma unroll 2
    for (int li = 0; li < CHUNK_T; li++) {
        long bl = (long)(b*LL + l0 + li);
        float xc = bf2f(sX[li*256 + threadIdx.x]);
        const float* row = &sL[li*SSML];
        f32x4 Bv[4], Cv[4];
        #pragma unroll
        for (int g = 0; g < 4; g++) {
            Bv[g] = *(const f32x4*)(row + g*4);
            Cv[g] = *(const f32x4*)(row + 16 + g*4);
        }
        float delta, r;
        softplus_r(row[32]*wdt + bdtv, delta, r);
        float du = delta * xc;
        f32x4 yacc = f32x4{0.f, 0.f, 0.f, 0.f};
        if (fastA) {
            float r2 = r*r, r3 = r2*r, r4 = r2*r2;
            f32x4 p0; p0[0]=r; p0[1]=r2; p0[2]=r3; p0[3]=r4;
            float s8 = r4*r4, s12 = s8*r4;
            h4[0] = p0*h4[0]       + du*Bv[0];
            h4[1] = (p0*r4)*h4[1]  + du*Bv[1];
            h4[2] = (p0*s8)*h4[2]  + du*Bv[2];
            h4[3] = (p0*s12)*h4[3] + du*Bv[3];
            yacc = yacc + h4[0]*Cv[0];
            yacc = yacc + h4[1]*Cv[1];
            yacc = yacc + h4[2]*Cv[2];
            yacc = yacc + h4[3]*Cv[3];
        } else {
            #pragma unroll
            for (int g = 0; g < 4; g++)
                #pragma unroll
                for (int j = 0; j < 4; j++) {
                    int s = g*4 + j;
                    h4[g][j] = __expf(delta*Aa[s])*h4[g][j] + du*Bv[g][j];
                    yacc[j] += h4[g][j]*Cv[g][j];
                }
        }
        float yv = (yacc[0] + yacc[1]) + (yacc[2] + yacc[3]);
        yv += xc * Dv;
        float z = bf2f(sZ[li*256 + threadIdx.x]);
        yv *= siluf(z);
        xz[bl*4096 + D_INNER + d] = __float2bfloat16(yv);
    }
}

// ---------------------------------------------------------------------------
extern "C" void kernel_launch(void* const* d_in, const int* in_sizes, int n_in,
                              void* d_out, int out_size, void* d_ws, size_t ws_size,
                              hipStream_t stream)
{
    char* ws = (char*)d_ws;
    bf16*  xz     = (bf16*) (ws);               // 33,554,432
    bf16*  wxpb   = (bf16*) (ws + 33554432);    //    524,288
    float* ssm    = (float*)(ws + 34078720);    //    589,824
    float* sumdq  = (float*)(ws + 34668544);    //  1,048,576
    float* Q      = (float*)(ws + 35717120);    // 16,777,216
    float* smallf = (float*)(ws + 52494336);    //    196,608
    int*   flag   = (int*)  (ws + 52690944);    //         64
    bf16*  woutb  = (bf16*) (ws + 52691008);    //  4,194,304  end: 56,885,312
    bf16*  xcb    = (bf16*) (ws + 56885312);    // 16,777,216  end: 73,662,528
    float* ssmp   = (float*)(ws + 73662528);    //  9,437,184  end: 83,099,712
    // xb and winb ALIAS Q (dead before scan writes Q)
    bf16*  xb     = (bf16*) (ws + 35717120);
    bf16*  winb   = (bf16*) (ws + 35717120 + 8388608);
    const bool big  = ws_size >= 56885312;
    const bool big2 = ws_size >= 73662528;   // xc-fusion path (r10)
    const bool big3 = ws_size >= 83099712;   // atomic-free split-K (r14)

    // 0) dtype probe + flag init
    dtype_probe<<<1, 64, 0, stream>>>((const unsigned short*)d_in[7], flag);

    // 1) weight prep (+ zero ssm, + A-structure check -> flag[1])
    cvt_prep<<<(N_WXPB + N_SMALL + N_SSMZ)/256, 256, 0, stream>>>(
        d_in[4], d_in[2], d_in[3], d_in[5], d_in[6], d_in[7], d_in[8],
        wxpb, smallf, ssm, flag);

    // 2) xz = x @ W_in.T  (M=4096, N=4096, K=1024) — relaxed 8-phase (r13)
    if (big) {
        cvt_all<<<1310720/256, 256, 0, stream>>>(
            d_in[0], d_in[1], d_in[9], xb, winb, woutb, flag);
        gemm8r<<<dim3(16, 16), 512, 0, stream>>>(xb, winb, xz);
    } else {
        gemm_dual<<<dim3(32, 32), 256, 0, stream>>>(
            d_in[0], D_MODEL, d_in[1], D_MODEL, xz, 2*D_INNER, D_MODEL, flag, 1, 1, 0);
    }

    // 3) ssm += conv+silu(x_in) @ Wxp.T  (+ xcb spill; big3: atomic-free)
    xproj_fused<<<dim3(XSPLIT, 32), 256, 0, stream>>>(
        xz, wxpb, smallf, ssm,
        big2 ? xcb : (bf16*)nullptr,
        big3 ? ssmp : (float*)nullptr);
    if (big3) {
        ssm_reduce<<<(BLROWS*SSML + 255)/256, 256, 0, stream>>>(ssmp, ssm);
    }

    // 4) chunked selective scan (xc path when big2)
    {
        dim3 g(D_INNER/256, NCHUNK, BB);
        if (big2) {
            scan_partA_xc<CHUNK><<<g, 256, 0, stream>>>(ssm, xcb, smallf, sumdq, Q, flag);
            scan_combine<<<(BB*D_STATE*D_INNER)/256, 256, 0, stream>>>(sumdq, Q, smallf, NCHUNK);
            scan_partC_xc<CHUNK><<<g, 256, 0, stream>>>(ssm, xz, xcb, smallf, Q, flag);
        } else {
            scan_partA<CHUNK><<<g, 256, 0, stream>>>(ssm, xz, smallf, sumdq, Q, flag);
            scan_combine<<<(BB*D_STATE*D_INNER)/256, 256, 0, stream>>>(sumdq, Q, smallf, NCHUNK);
            scan_partC<CHUNK><<<g, 256, 0, stream>>>(ssm, xz, smallf, Q, flag);
        }
    }

    // 5) out = y @ W_out.T  (M=4096, N=1024, K=2048) — dbuf counted (r15)
    if (big) {
        gemm_n64r<<<dim3(D_MODEL/64, 32), 256, 0, stream>>>(
            xz + D_INNER, 2*D_INNER, woutb, D_INNER, d_out, D_MODEL, D_INNER, flag, 1);
    } else {
        gemm_n64<<<dim3(D_MODEL/64, 32), 256, 0, stream>>>(
            xz + D_INNER, 2*D_INNER, d_in[9], D_INNER, d_out, D_MODEL, D_INNER, flag, 1, 1);
    }
}